// Round 1
// baseline (5977.247 us; speedup 1.0000x reference)
//
#include <hip/hip_runtime.h>
#include <cstdint>
#include <cstddef>

typedef unsigned short u16;
typedef __attribute__((ext_vector_type(8))) short  short8;
typedef __attribute__((ext_vector_type(4))) float  f32x4;
typedef __attribute__((ext_vector_type(2))) unsigned int uint2v;

#define HW4   1792      // 28*64
#define FCH   631       // final feat channels
#define OUTOFF ((size_t)57344)   // feat region element offset in d_out

__device__ __forceinline__ float b2f(u16 u){
  union { unsigned int i; float f; } v; v.i = ((unsigned int)u) << 16; return v.f;
}
__device__ __forceinline__ u16 f2b(float f){
  unsigned int x = __float_as_uint(f);
  return (u16)((x + 0x7fffu + ((x >> 16) & 1u)) >> 16);
}
__device__ __forceinline__ float lrelu(float v){ return v >= 0.f ? v : 0.1f * v; }
// dtype probe: cam_intri[0]=500.0. bf16 pair read as float -> 2.4e-41 ; fp32 -> 500.0
__device__ __forceinline__ bool is_f32(const void* probe){ return ((const float*)probe)[0] > 1.0f; }
__device__ __forceinline__ float ldg_(const void* p, size_t i, bool f){
  return f ? ((const float*)p)[i] : b2f(((const u16*)p)[i]);
}
__device__ __forceinline__ void stg_(void* p, size_t i, float v, bool f){
  if (f) ((float*)p)[i] = v; else ((u16*)p)[i] = f2b(v);
}
__device__ __forceinline__ short8 zero8(){
  union { long long l[2]; short8 s; } z; z.l[0] = 0; z.l[1] = 0; return z.s;
}
__device__ __forceinline__ f32x4 zero4(){
  union { long long l[2]; f32x4 s; } z; z.l[0] = 0; z.l[1] = 0; return z.s;
}
__device__ __forceinline__ short8 pack8(uint2v a, uint2v b){
  union { unsigned int u[4]; short8 s; } t;
  t.u[0] = a.x; t.u[1] = a.y; t.u[2] = b.x; t.u[3] = b.y; return t.s;
}

// async global->LDS, 16B per lane; LDS dest = wave-uniform base + lane*16
#define GLL16(SRC, LOFF) \
  __builtin_amdgcn_global_load_lds((const __attribute__((address_space(1))) void*)(SRC), \
      (__attribute__((address_space(3))) void*)(uintptr_t)(LOFF), 16, 0, 0)

// hardware transpose read: 4 bf16 at element offsets addr/2 + {0,16,32,48}
#define TRR(D, A) asm volatile("ds_read_b64_tr_b16 %0, %1" : "=v"(D) : "v"(A))

// ---------------------------------------------------------------- M = K R(q) Kinv
__global__ void k_M(const void* __restrict__ quat, const void* __restrict__ K,
                    const void* __restrict__ Kinv, float* __restrict__ Mout){
  bool f = is_f32(K);
  int b = threadIdx.x;
  if (b >= 16) return;
  float q0 = ldg_(quat,b*4+0,f), q1 = ldg_(quat,b*4+1,f);
  float q2 = ldg_(quat,b*4+2,f), q3 = ldg_(quat,b*4+3,f);
  float n = sqrtf(q0*q0 + q1*q1 + q2*q2 + q3*q3);
  float w = q0/n, x = q1/n, y = q2/n, z = q3/n;
  float R[9];
  R[0] = 1.f - 2.f*(y*y + z*z); R[1] = 2.f*(x*y - w*z); R[2] = 2.f*(x*z + w*y);
  R[3] = 2.f*(x*y + w*z); R[4] = 1.f - 2.f*(x*x + z*z); R[5] = 2.f*(y*z - w*x);
  R[6] = 2.f*(x*z - w*y); R[7] = 2.f*(y*z + w*x); R[8] = 1.f - 2.f*(x*x + y*y);
  float Kf[9], Ki[9];
  for (int i = 0; i < 9; i++){ Kf[i] = ldg_(K,i,f); Ki[i] = ldg_(Kinv,i,f); }
  float T[9];
  for (int r = 0; r < 3; r++)
    for (int c = 0; c < 3; c++)
      T[r*3+c] = R[r*3+0]*Ki[0*3+c] + R[r*3+1]*Ki[1*3+c] + R[r*3+2]*Ki[2*3+c];
  for (int r = 0; r < 3; r++)
    for (int c = 0; c < 3; c++)
      Mout[b*9 + r*3 + c] = Kf[r*3+0]*T[0*3+c] + Kf[r*3+1]*T[1*3+c] + Kf[r*3+2]*T[2*3+c];
}

// ---------------------------------------- rotation-flow, column (W 1024->64) pass
__global__ void k_rflow_col(const float* __restrict__ Mws, float* __restrict__ tmpA){
  int t = blockIdx.x * 256 + threadIdx.x;      // 16*448*64 = 458752 exactly
  int xo = t & 63;
  int yf = (t >> 6) % 448;
  int b  = t / (448*64);
  const float* M = Mws + b*9;
  float m0=M[0],m1=M[1],m2=M[2],m3=M[3],m4=M[4],m5=M[5],m6=M[6],m7=M[7],m8=M[8];
  float cx = 16.f*xo + 7.5f;
  float yff = (float)yf;
  float su = 0.f, sv = 0.f, wsum = 0.f;
  for (int i = 0; i < 32; i++){
    int xi = 16*xo - 8 + i;
    if (xi < 0 || xi > 1023) continue;
    float xf = (float)xi;
    float wgt = 1.f - fabsf(xf - cx) * (1.f/16.f);
    float den = m6*xf + m7*yff + m8;
    float inv = 1.f / den;
    float u = (m0*xf + m1*yff + m2)*inv - xf;
    float v = (m3*xf + m4*yff + m5)*inv - yff;
    su += wgt*u; sv += wgt*v; wsum += wgt;
  }
  float rn = 1.f / wsum;
  tmpA[((size_t)(b*2+0)*64 + xo)*448 + yf] = su*rn;
  tmpA[((size_t)(b*2+1)*64 + xo)*448 + yf] = sv*rn;
}

// ---------------------------------------- rotation-flow, row (448->28) + /SCALE
__global__ void k_rflow_row(const float* __restrict__ tmpA, float* __restrict__ rfr,
                            void* __restrict__ outb, const void* probe){
  bool f = is_f32(probe);
  int t = blockIdx.x * 256 + threadIdx.x;      // 28672 exactly
  int xo = t & 63;
  int yo = (t >> 6) % 28;
  int b  = t / HW4;
  float cy = 16.f*yo + 7.5f;
  for (int c = 0; c < 2; c++){
    const float* col = tmpA + ((size_t)(b*2+c)*64 + xo)*448;
    float s = 0.f, wsum = 0.f;
    for (int i = 0; i < 32; i++){
      int yi = 16*yo - 8 + i;
      if (yi < 0 || yi > 447) continue;
      float wgt = 1.f - fabsf((float)yi - cy) * (1.f/16.f);
      s += wgt * col[yi]; wsum += wgt;
    }
    float val = s / (wsum * 16.0f);   // includes /SCALE
    rfr[(size_t)(b*2+c)*HW4 + yo*64 + xo] = val;
    stg_(outb, OUTOFF + ((size_t)b*FCH + 529 + c)*HW4 + yo*64 + xo, val, f);
  }
}

// ---------------------------------------------------- deconv4s2 of prev_flow (2ch)
__global__ void k_dflow(const void* __restrict__ pf, const void* __restrict__ w,
                        const void* __restrict__ bias, float* __restrict__ tflow,
                        void* __restrict__ outb, const void* probe){
  bool f = is_f32(probe);
  int t = blockIdx.x * 256 + threadIdx.x;      // 57344 exactly
  int x = t & 63;
  int y = (t >> 6) % 28;
  int co = (t / HW4) & 1;
  int b  = t / (2*HW4);
  float acc = ldg_(bias, co, f);
  for (int ky = 0; ky < 4; ky++){
    int dy = y + ky - 2;
    if (dy < 0 || dy > 26 || (dy & 1)) continue;
    int iy = dy >> 1;
    for (int kx = 0; kx < 4; kx++){
      int dx = x + kx - 2;
      if (dx < 0 || dx > 62 || (dx & 1)) continue;
      int ix = dx >> 1;
      for (int ci = 0; ci < 2; ci++){
        acc += ldg_(pf, ((size_t)(b*2+ci)*14 + iy)*32 + ix, f) *
               ldg_(w,  (size_t)ci*32 + co*16 + (3-ky)*4 + (3-kx), f);
      }
    }
  }
  tflow[(size_t)(b*2+co)*HW4 + y*64 + x] = acc;
  stg_(outb, OUTOFF + ((size_t)b*FCH + 627 + co)*HW4 + y*64 + x, acc, f);
}

// ---------------------------------------------------- deconv4s2 of prev_feat (663->2)
__global__ void k_dfeat(const void* __restrict__ pfeat, const void* __restrict__ w,
                        const void* __restrict__ bias, void* __restrict__ outb,
                        const void* probe){
  bool f = is_f32(probe);
  int t = blockIdx.x * 256 + threadIdx.x;      // 57344 exactly
  int x = t & 63;
  int y = (t >> 6) % 28;
  int co = (t / HW4) & 1;
  int b  = t / (2*HW4);
  float acc = ldg_(bias, co, f);
  if (f){
    const float* pin = (const float*)pfeat + (size_t)b*663*448;
    const float* wf  = (const float*)w;
    for (int ky = 0; ky < 4; ky++){
      int dy = y + ky - 2;
      if (dy < 0 || dy > 26 || (dy & 1)) continue;
      int iy = dy >> 1;
      for (int kx = 0; kx < 4; kx++){
        int dx = x + kx - 2;
        if (dx < 0 || dx > 62 || (dx & 1)) continue;
        int ix = dx >> 1;
        const float* ip = pin + iy*32 + ix;
        const float* wp = wf + co*16 + (3-ky)*4 + (3-kx);
        #pragma unroll 4
        for (int ci = 0; ci < 663; ci++) acc += ip[ci*448] * wp[ci*32];
      }
    }
  } else {
    const u16* pin = (const u16*)pfeat + (size_t)b*663*448;
    const u16* wf  = (const u16*)w;
    for (int ky = 0; ky < 4; ky++){
      int dy = y + ky - 2;
      if (dy < 0 || dy > 26 || (dy & 1)) continue;
      int iy = dy >> 1;
      for (int kx = 0; kx < 4; kx++){
        int dx = x + kx - 2;
        if (dx < 0 || dx > 62 || (dx & 1)) continue;
        int ix = dx >> 1;
        const u16* ip = pin + iy*32 + ix;
        const u16* wp = wf + co*16 + (3-ky)*4 + (3-kx);
        #pragma unroll 4
        for (int ci = 0; ci < 663; ci++) acc += b2f(ip[ci*448]) * b2f(wp[ci*32]);
      }
    }
  }
  stg_(outb, OUTOFF + ((size_t)b*FCH + 629 + co)*HW4 + y*64 + x, acc, f);
}

// ---------------------------------------------------------------- copy tenOne into feat
__global__ void k_copy_one(const void* __restrict__ one, void* __restrict__ outb,
                           const void* probe){
  bool f = is_f32(probe);
  int t = blockIdx.x * 256 + threadIdx.x;      // 2752512 exactly
  int p = t % HW4;
  int c = (t / HW4) % 96;
  int b = t / (96*HW4);
  stg_(outb, OUTOFF + ((size_t)b*FCH + 531 + c)*HW4 + p,
       ldg_(one, (size_t)(b*96+c)*HW4 + p, f), f);
}

// ------------------------------------------- fused double-warp of tenTwo (16-pt gather)
__global__ void k_warp2(const void* __restrict__ two, const float* __restrict__ rfr,
                        const float* __restrict__ tflow, float* __restrict__ wrp2,
                        const void* probe){
  bool f = is_f32(probe);
  int t = blockIdx.x * 256 + threadIdx.x;      // 2752512 exactly
  int x = t & 63;
  int y = (t >> 6) % 28;
  int c = (t / HW4) % 96;
  int b = t / (96*HW4);
  float qu = tflow[(size_t)(b*2+0)*HW4 + y*64 + x] * 1.25f;
  float qv = tflow[(size_t)(b*2+1)*HW4 + y*64 + x] * 1.25f;
  float qx = (float)x + qu, qy = (float)y + qv;
  float qx0 = floorf(qx), qy0 = floorf(qy);
  float wx = qx - qx0, wy = qy - qy0;
  const size_t cb = (size_t)(b*96+c)*HW4;
  float acc = 0.f;
  #pragma unroll
  for (int a = 0; a < 2; a++){
    #pragma unroll
    for (int bb = 0; bb < 2; bb++){
      float ry = qy0 + (float)a, rx = qx0 + (float)bb;
      if (ry < 0.f || ry > 27.f || rx < 0.f || rx > 63.f) continue;
      float W = (a ? wy : 1.f-wy) * (bb ? wx : 1.f-wx);
      int iry = (int)ry, irx = (int)rx;
      float su = rfr[(size_t)(b*2+0)*HW4 + iry*64 + irx];
      float sv = rfr[(size_t)(b*2+1)*HW4 + iry*64 + irx];
      float sx = rx + su, sy = ry + sv;
      float sx0 = floorf(sx), sy0 = floorf(sy);
      float swx = sx - sx0, swy = sy - sy0;
      float inner = 0.f;
      #pragma unroll
      for (int aa = 0; aa < 2; aa++){
        #pragma unroll
        for (int cc2 = 0; cc2 < 2; cc2++){
          float gy2 = sy0 + (float)aa, gx2 = sx0 + (float)cc2;
          if (gy2 < 0.f || gy2 > 27.f || gx2 < 0.f || gx2 > 63.f) continue;
          float wv = (aa ? swy : 1.f-swy) * (cc2 ? swx : 1.f-swx);
          inner += wv * ldg_(two, cb + (size_t)((int)gy2*64 + (int)gx2), f);
        }
      }
      acc += W * inner;
    }
  }
  wrp2[t] = acc;
}

// ---------------------------------------------------------------- correlation (81 ch)
__global__ void k_corr(const void* __restrict__ one, const float* __restrict__ two,
                       void* __restrict__ outb, const void* probe){
  bool f = is_f32(probe);
  int t = blockIdx.x * 256 + threadIdx.x;      // 16*9*1792 = 258048 exactly
  int x  = t & 63;
  int y  = (t >> 6) % 28;
  int dy = (t / HW4) % 9;
  int b  = t / (9*HW4);
  float acc[9];
  #pragma unroll
  for (int i = 0; i < 9; i++) acc[i] = 0.f;
  int row = y + dy - 4;
  if (row >= 0 && row < 28){
    for (int c = 0; c < 96; c++){
      float f1 = ldg_(one, (size_t)(b*96+c)*HW4 + y*64 + x, f);
      const float* rp = two + (size_t)(b*96+c)*HW4 + row*64;
      #pragma unroll
      for (int dx = 0; dx < 9; dx++){
        int xx = x + dx - 4;
        if (xx >= 0 && xx < 64) acc[dx] += f1 * rp[xx];
      }
    }
  }
  #pragma unroll
  for (int dx = 0; dx < 9; dx++){
    float v = lrelu(acc[dx] * (1.f/96.f));
    stg_(outb, OUTOFF + ((size_t)b*FCH + 448 + dy*9 + dx)*HW4 + y*64 + x, v, f);
  }
}

// ---------------------------------------------------------------- 3x3 conv + lrelu (f32 fallback path)
__global__ __launch_bounds__(256) void k_conv(
    void* __restrict__ base, size_t in_off,
    const void* __restrict__ w, const void* __restrict__ bias,
    int Cin, int Cout, size_t out_off, size_t out_bstr, const void* probe, int gate){
  __shared__ float s_in[32*3*66];    // 25344 B
  __shared__ float s_w[32*9*32];     // 36864 B
  bool f = is_f32(probe);
  if (gate && !f) return;            // gate=1: run only when data is f32
  int tid = threadIdx.x;
  int x = tid & 63;
  int g = tid >> 6;
  int by = blockIdx.x;
  int b = by / 28, y = by % 28;
  int co_base = blockIdx.y * 32;
  const size_t FB = (size_t)FCH * HW4;
  float acc[8];
  #pragma unroll
  for (int j = 0; j < 8; j++) acc[j] = 0.f;

  for (int ci0 = 0; ci0 < Cin; ci0 += 32){
    int cc = min(32, Cin - ci0);
    if (f){
      const float* inb = (const float*)base + in_off + (size_t)b*FB;
      for (int e = tid; e < cc*198; e += 256){
        int ci = e / 198; int rem = e - ci*198;
        int r = rem / 66; int xx = rem - r*66;
        int iy = y + r - 1; int ix = xx - 1;
        float v = 0.f;
        if (iy >= 0 && iy < 28 && ix >= 0 && ix < 64)
          v = inb[(size_t)(ci0+ci)*HW4 + iy*64 + ix];
        s_in[(ci*3 + r)*66 + xx] = v;
      }
      const float* wf = (const float*)w;
      for (int e = tid; e < cc*288; e += 256){
        int co_i = e & 31; int k = (e >> 5) % 9; int ci = e / 288;
        int co = co_base + co_i;
        float v = 0.f;
        if (co < Cout) v = wf[((size_t)co*Cin + ci0 + ci)*9 + k];
        s_w[(ci*9 + k)*32 + co_i] = v;
      }
    } else {
      const u16* inb = (const u16*)base + in_off + (size_t)b*FB;
      for (int e = tid; e < cc*198; e += 256){
        int ci = e / 198; int rem = e - ci*198;
        int r = rem / 66; int xx = rem - r*66;
        int iy = y + r - 1; int ix = xx - 1;
        float v = 0.f;
        if (iy >= 0 && iy < 28 && ix >= 0 && ix < 64)
          v = b2f(inb[(size_t)(ci0+ci)*HW4 + iy*64 + ix]);
        s_in[(ci*3 + r)*66 + xx] = v;
      }
      const u16* wf = (const u16*)w;
      for (int e = tid; e < cc*288; e += 256){
        int co_i = e & 31; int k = (e >> 5) % 9; int ci = e / 288;
        int co = co_base + co_i;
        float v = 0.f;
        if (co < Cout) v = b2f(wf[((size_t)co*Cin + ci0 + ci)*9 + k]);
        s_w[(ci*9 + k)*32 + co_i] = v;
      }
    }
    __syncthreads();
    for (int ci = 0; ci < cc; ci++){
      const float* si = &s_in[ci*198 + x];
      const float* sw = &s_w[ci*288 + 8*g];
      #pragma unroll
      for (int ky = 0; ky < 3; ky++){
        #pragma unroll
        for (int kx = 0; kx < 3; kx++){
          float v = si[ky*66 + kx];
          const float* wp = sw + (ky*3 + kx)*32;
          float4 wa = *(const float4*)(wp);
          float4 wb = *(const float4*)(wp + 4);
          acc[0] += wa.x*v; acc[1] += wa.y*v; acc[2] += wa.z*v; acc[3] += wa.w*v;
          acc[4] += wb.x*v; acc[5] += wb.y*v; acc[6] += wb.z*v; acc[7] += wb.w*v;
        }
      }
    }
    __syncthreads();
  }
  #pragma unroll
  for (int j = 0; j < 8; j++){
    int co = co_base + 8*g + j;
    if (co < Cout){
      float v = lrelu(acc[j] + ldg_(bias, co, f));
      stg_(base, out_off + (size_t)b*out_bstr + (size_t)co*HW4 + y*64 + x, v, f);
    }
  }
}

// --------------------------------------------------------- weight transpose for MFMA path
// wT layout: [(k*coP + co)*CinP + ci], zero-padded in both co (>=Cout) and ci (>=Cin).
__global__ void k_wprep(const void* __restrict__ w, u16* __restrict__ wT,
                        int Cin, int Cout, int coP, int CinP, int total,
                        u16* __restrict__ zbuf, int gate, const void* probe){
  if (gate && is_f32(probe)) return;
  int t = blockIdx.x * 256 + threadIdx.x;
  if (zbuf && t < 32) zbuf[t] = 0;   // 64 B zero page for staging redirects
  if (t >= total) return;
  int ci = t % CinP;
  int s  = t / CinP;
  int co = s % coP;
  int k  = s / coP;
  u16 v = 0;
  if (ci < Cin && co < Cout) v = ((const u16*)w)[((size_t)co*Cin + ci)*9 + k];
  wT[t] = v;
}

// --------------------------------------------------------- 3x3 conv via bf16 MFMA
// Block: 256 thr = 4 waves. Wave wv: row = y0+(wv&1), co quad = (wv>>1)*32.
// Block tile: 64 co x 64 x x 2 rows. Grid: (224 = 16*14 y-pairs, coP/64).
// LDS: input  [r:4][ciq:8][xc:4][cir:4][xr:16] bf16 = 16384 B  (tr-read subtiled)
//      weight [k:9][co:64][ci:32]              bf16 = 36864 B  (b128 fragment order)
// K decomposed per tap: acc += W[k][co][ci] * In[ci][y+ky-1][x+kx-1], 9 taps.
__global__ __launch_bounds__(256, 3) void k_conv_mfma(
    void* __restrict__ base, size_t in_off, const u16* __restrict__ wT,
    const void* __restrict__ bias, int Cin, int CinP, int Cout,
    size_t out_off, size_t out_bstr, const u16* __restrict__ zbuf,
    int gate, const void* __restrict__ probe){
  if (gate && is_f32(probe)) return;
  __shared__ __align__(16) u16 lds[26624];   // 53248 B total
  const int tid  = threadIdx.x;
  const int lane = tid & 63, wv = tid >> 6;
  const int wrow = wv & 1, wcoc = wv >> 1;
  const int lx = lane & 15, lg = lane >> 4;
  const int b  = blockIdx.x / 14;
  const int y0 = (blockIdx.x % 14) * 2;
  const int coB = blockIdx.y * 64;
  const int coP = (int)gridDim.y * 64;
  const u16* inb = (const u16*)base + in_off + (size_t)b * ((size_t)FCH * HW4);
  const uint32_t lbase = (uint32_t)(uintptr_t)&lds[0];

  // per-lane tr-read bases for the 3 kx shifts (x = lx + kx - 1, clamped; OOB lanes masked)
  uint32_t a_in[3];
  #pragma unroll
  for (int kx = 0; kx < 3; kx++){
    int x = lx + kx - 1; if (x < 0) x = 0;
    a_in[kx] = lbase + (uint32_t)((wrow*8 + 2*lg)*512 + (x >> 4)*128 + (x & 15)*2);
  }

  f32x4 acc[2][4];
  #pragma unroll
  for (int f2 = 0; f2 < 2; f2++)
    #pragma unroll
    for (int xg = 0; xg < 4; xg++) acc[f2][xg] = zero4();

  const int nCB = CinP >> 5;
  for (int cb = 0; cb < nCB; cb++){
    const int ci0 = cb << 5;
    // ---- stage input tile: 16 KB, 16 wave-issues of global_load_lds x16B
    #pragma unroll
    for (int i = 0; i < 4; i++){
      int c   = (wv*4 + i)*64 + lane;          // chunk id 0..1023
      int row = y0 - 1 + (c >> 8);
      int ci  = ci0 + ((c >> 5) & 7)*4 + ((c >> 1) & 3);
      int xo  = ((c >> 3) & 3)*16 + (c & 1)*8;
      const u16* src = (row >= 0 && row < 28 && ci < Cin)
                     ? (inb + (size_t)ci*HW4 + row*64 + xo) : zbuf;
      GLL16(src, lbase + (uint32_t)((wv*4 + i)*1024));
    }
    // ---- stage weight tile: 36 KB, 36 wave-issues (wT pre-padded, all chunks valid)
    #pragma unroll
    for (int i = 0; i < 9; i++){
      int c = (wv*9 + i)*64 + lane;            // chunk id 0..2303
      int cq = c & 3, co_l = (c >> 2) & 63, k = c >> 8;
      const u16* src = wT + (size_t)(k*coP + coB + co_l)*CinP + (ci0 + cq*8);
      GLL16(src, lbase + 16384u + (uint32_t)((wv*9 + i)*1024));
    }
    __syncthreads();
    #pragma unroll
    for (int ky = 0; ky < 3; ky++){
      #pragma unroll
      for (int kx = 0; kx < 3; kx++){
        const int k = ky*3 + kx;
        // A frags: contiguous b128 (lane: co = base+lx, 8 ci); conflict-free permutation
        short8 aA0, aA1;
        {
          int eA = 8192 + (k*64 + wcoc*32 + lx)*32 + lg*8;
          aA0 = *(const short8*)&lds[eA];
          aA1 = *(const short8*)&lds[eA + 512];        // f=1: +16 co
        }
        // B frags: hw transpose reads (lane: x col, elems: 4 consecutive ci)
        uint32_t ab = a_in[kx] + (uint32_t)(ky*4096);
        uint2v t0,t1,t2,t3,t4,t5,t6,t7;
        TRR(t0, ab);        TRR(t1, ab + 512u);
        TRR(t2, ab + 128u); TRR(t3, ab + 640u);
        TRR(t4, ab + 256u); TRR(t5, ab + 768u);
        TRR(t6, ab + 384u); TRR(t7, ab + 896u);
        asm volatile("s_waitcnt lgkmcnt(0)" ::: "memory");
        __builtin_amdgcn_sched_barrier(0);             // rule 18: fence reg use of asm ds_reads
        short8 b0 = pack8(t0,t1), b1 = pack8(t2,t3);
        short8 b2v = pack8(t4,t5), b3 = pack8(t6,t7);
        if (kx == 0 && lx == 0)  b0 = zero8();         // x = -1 column
        if (kx == 2 && lx == 15) b3 = zero8();         // x = 64 column
        acc[0][0] = __builtin_amdgcn_mfma_f32_16x16x32_bf16(aA0, b0,  acc[0][0], 0,0,0);
        acc[0][1] = __builtin_amdgcn_mfma_f32_16x16x32_bf16(aA0, b1,  acc[0][1], 0,0,0);
        acc[0][2] = __builtin_amdgcn_mfma_f32_16x16x32_bf16(aA0, b2v, acc[0][2], 0,0,0);
        acc[0][3] = __builtin_amdgcn_mfma_f32_16x16x32_bf16(aA0, b3,  acc[0][3], 0,0,0);
        acc[1][0] = __builtin_amdgcn_mfma_f32_16x16x32_bf16(aA1, b0,  acc[1][0], 0,0,0);
        acc[1][1] = __builtin_amdgcn_mfma_f32_16x16x32_bf16(aA1, b1,  acc[1][1], 0,0,0);
        acc[1][2] = __builtin_amdgcn_mfma_f32_16x16x32_bf16(aA1, b2v, acc[1][2], 0,0,0);
        acc[1][3] = __builtin_amdgcn_mfma_f32_16x16x32_bf16(aA1, b3,  acc[1][3], 0,0,0);
      }
    }
    __syncthreads();
  }
  // epilogue: bias + lrelu + bf16 store (D: row m = 4*lg+reg -> co, col n = lx -> x)
  u16* ob = (u16*)base;
  const u16* bb = (const u16*)bias;
  const int y = y0 + wrow;
  #pragma unroll
  for (int f2 = 0; f2 < 2; f2++){
    #pragma unroll
    for (int xg = 0; xg < 4; xg++){
      const int x = xg*16 + lx;
      #pragma unroll
      for (int r = 0; r < 4; r++){
        int co = coB + wcoc*32 + f2*16 + lg*4 + r;
        if (co < Cout){
          float v = lrelu(acc[f2][xg][r] + b2f(bb[co]));
          ob[out_off + (size_t)b*out_bstr + (size_t)co*HW4 + (size_t)(y*64 + x)] = f2b(v);
        }
      }
    }
  }
}

// ----------------------------------------------------------------------------------
extern "C" void kernel_launch(void* const* d_in, const int* in_sizes, int n_in,
                              void* d_out, int out_size, void* d_ws, size_t ws_size,
                              hipStream_t stream){
  const void* tenOne    = d_in[0];
  const void* tenTwo    = d_in[1];
  const void* prev_flow = d_in[2];
  const void* prev_feat = d_in[3];
  const void* quat      = d_in[4];
  const void* K         = d_in[5];
  const void* Kinv      = d_in[6];
  const void* upflow_w  = d_in[7];
  const void* upflow_b  = d_in[8];
  const void* upfeat_w  = d_in[9];
  const void* upfeat_b  = d_in[10];
  const void* w1 = d_in[11];  const void* b1 = d_in[12];
  const void* w2 = d_in[13];  const void* b2 = d_in[14];
  const void* w3 = d_in[15];  const void* b3 = d_in[16];
  const void* w4 = d_in[17];  const void* b4 = d_in[18];
  const void* w5 = d_in[19];  const void* b5 = d_in[20];
  const void* w6 = d_in[21];  const void* b6 = d_in[22];
  const void* probe = K;    // cam_intri[0]==500.0 discriminates dtype

  float* ws    = (float*)d_ws;
  float* Mws   = ws;                         // 160
  float* tmpA  = ws + 160;                   // 917504
  float* rfr   = ws + 917664;                // 57344
  float* tflow = ws + 975008;                // 57344
  float* wrp2  = ws + 1032352;               // 2752512 (end 3784864 floats ~15.1MB)
  u16*   zbuf  = (u16*)(ws + 3784864);       // 64 B zero page (written by k_wprep L1)
  u16*   wTb   = (u16*)(ws + 3784880);       // 2138112 u16 (~4.3 MB) transposed weights

  // host-side dtype resolution from input byte size (2752512 elements in tenOne)
  const int n_one = 16*96*28*64;
  bool known_bf16 = (n_in > 0) && (in_sizes[0] == n_one*2);
  bool known_f32  = (n_in > 0) && (in_sizes[0] == n_one*4);
  bool launch_new = !known_f32;              // MFMA chain (bf16)
  bool launch_old = !known_bf16;             // VALU chain (f32)
  int gate_new = known_bf16 ? 0 : 1;
  int gate_old = known_f32  ? 0 : 1;

  k_M<<<1, 64, 0, stream>>>(quat, K, Kinv, Mws);
  k_rflow_col<<<1792, 256, 0, stream>>>(Mws, tmpA);
  k_rflow_row<<<112, 256, 0, stream>>>(tmpA, rfr, d_out, probe);
  k_dflow<<<224, 256, 0, stream>>>(prev_flow, upflow_w, upflow_b, tflow, d_out, probe);
  k_dfeat<<<224, 256, 0, stream>>>(prev_feat, upfeat_w, upfeat_b, d_out, probe);
  k_copy_one<<<10752, 256, 0, stream>>>(tenOne, d_out, probe);
  k_warp2<<<10752, 256, 0, stream>>>(tenTwo, rfr, tflow, wrp2, probe);
  k_corr<<<1008, 256, 0, stream>>>(tenOne, wrp2, d_out, probe);

  const size_t FB = (size_t)FCH * HW4;
  const size_t f0 = OUTOFF;

  struct LD { const void *w, *bi; int Cin, Cout, coP, CinP; size_t wOff, in_off, out_off, out_bstr; };
  const LD L[6] = {
    { w1, b1, 183, 128, 128, 192, 0,       f0+(size_t)448*HW4, f0+(size_t)320*HW4, FB },
    { w2, b2, 311, 128, 128, 320, 221184,  f0+(size_t)320*HW4, f0+(size_t)192*HW4, FB },
    { w3, b3, 439,  96, 128, 448, 589824,  f0+(size_t)192*HW4, f0+(size_t) 96*HW4, FB },
    { w4, b4, 535,  64,  64, 544, 1105920, f0+(size_t) 96*HW4, f0+(size_t) 32*HW4, FB },
    { w5, b5, 599,  32,  64, 608, 1419264, f0+(size_t) 32*HW4, f0,                 FB },
    { w6, b6, 631,   2,  64, 640, 1769472, f0,                 0,        (size_t)2*HW4 },
  };

  if (launch_new){
    for (int i = 0; i < 6; i++){
      int total = 9 * L[i].coP * L[i].CinP;
      k_wprep<<<(total + 255)/256, 256, 0, stream>>>(
          L[i].w, wTb + L[i].wOff, L[i].Cin, L[i].Cout, L[i].coP, L[i].CinP,
          total, (i == 0) ? zbuf : (u16*)nullptr, gate_new, probe);
    }
    for (int i = 0; i < 6; i++){
      k_conv_mfma<<<dim3(224, L[i].coP/64), 256, 0, stream>>>(
          d_out, L[i].in_off, wTb + L[i].wOff, L[i].bi,
          L[i].Cin, L[i].CinP, L[i].Cout,
          L[i].out_off, L[i].out_bstr, zbuf, gate_new, probe);
    }
  }
  if (launch_old){
    k_conv<<<dim3(448,4), 256, 0, stream>>>(d_out, f0 + (size_t)448*HW4, w1, b1, 183, 128,
                                            f0 + (size_t)320*HW4, FB, probe, gate_old);
    k_conv<<<dim3(448,4), 256, 0, stream>>>(d_out, f0 + (size_t)320*HW4, w2, b2, 311, 128,
                                            f0 + (size_t)192*HW4, FB, probe, gate_old);
    k_conv<<<dim3(448,3), 256, 0, stream>>>(d_out, f0 + (size_t)192*HW4, w3, b3, 439, 96,
                                            f0 + (size_t)96*HW4, FB, probe, gate_old);
    k_conv<<<dim3(448,2), 256, 0, stream>>>(d_out, f0 + (size_t)96*HW4, w4, b4, 535, 64,
                                            f0 + (size_t)32*HW4, FB, probe, gate_old);
    k_conv<<<dim3(448,1), 256, 0, stream>>>(d_out, f0 + (size_t)32*HW4, w5, b5, 599, 32,
                                            f0, FB, probe, gate_old);
    k_conv<<<dim3(448,1), 256, 0, stream>>>(d_out, f0, w6, b6, 631, 2,
                                            0, (size_t)2*HW4, probe, gate_old);
  }
}

// Round 3
// 5919.405 us; speedup vs baseline: 1.0098x; 1.0098x over previous
//
#include <hip/hip_runtime.h>
#include <cstdint>
#include <cstddef>

typedef unsigned short u16;
typedef __attribute__((ext_vector_type(8))) short  short8;
typedef __attribute__((ext_vector_type(4))) float  f32x4;
typedef __attribute__((ext_vector_type(2))) unsigned int uint2v;

#define HW4   1792      // 28*64
#define FCH   631       // final feat channels
#define OUTOFF ((size_t)57344)   // feat region element offset in d_out

__device__ __forceinline__ float b2f(u16 u){
  union { unsigned int i; float f; } v; v.i = ((unsigned int)u) << 16; return v.f;
}
__device__ __forceinline__ u16 f2b(float f){
  unsigned int x = __float_as_uint(f);
  return (u16)((x + 0x7fffu + ((x >> 16) & 1u)) >> 16);
}
__device__ __forceinline__ float lrelu(float v){ return v >= 0.f ? v : 0.1f * v; }
// dtype probe: cam_intri[0]=500.0. bf16 pair read as float -> 2.4e-41 ; fp32 -> 500.0
__device__ __forceinline__ bool is_f32(const void* probe){ return ((const float*)probe)[0] > 1.0f; }
__device__ __forceinline__ float ldg_(const void* p, size_t i, bool f){
  return f ? ((const float*)p)[i] : b2f(((const u16*)p)[i]);
}
__device__ __forceinline__ void stg_(void* p, size_t i, float v, bool f){
  if (f) ((float*)p)[i] = v; else ((u16*)p)[i] = f2b(v);
}
__device__ __forceinline__ short8 zero8(){
  union { long long l[2]; short8 s; } z; z.l[0] = 0; z.l[1] = 0; return z.s;
}
__device__ __forceinline__ f32x4 zero4(){
  union { long long l[2]; f32x4 s; } z; z.l[0] = 0; z.l[1] = 0; return z.s;
}
__device__ __forceinline__ short8 pack8(uint2v a, uint2v b){
  union { unsigned int u[4]; short8 s; } t;
  t.u[0] = a.x; t.u[1] = a.y; t.u[2] = b.x; t.u[3] = b.y; return t.s;
}

// async global->LDS, 16B per lane; LDS dest = wave-uniform base + lane*16
#define GLL16(SRC, LOFF) \
  __builtin_amdgcn_global_load_lds((const __attribute__((address_space(1))) void*)(SRC), \
      (__attribute__((address_space(3))) void*)(uintptr_t)(LOFF), 16, 0, 0)

// hardware transpose read: 4 bf16 at byte offsets addr + {0,32,64,96} (16-bf16 HW stride)
#define TRR(D, A) asm volatile("ds_read_b64_tr_b16 %0, %1" : "=v"(D) : "v"(A))

// ---------------------------------------------------------------- M = K R(q) Kinv
__global__ void k_M(const void* __restrict__ quat, const void* __restrict__ K,
                    const void* __restrict__ Kinv, float* __restrict__ Mout){
  bool f = is_f32(K);
  int b = threadIdx.x;
  if (b >= 16) return;
  float q0 = ldg_(quat,b*4+0,f), q1 = ldg_(quat,b*4+1,f);
  float q2 = ldg_(quat,b*4+2,f), q3 = ldg_(quat,b*4+3,f);
  float n = sqrtf(q0*q0 + q1*q1 + q2*q2 + q3*q3);
  float w = q0/n, x = q1/n, y = q2/n, z = q3/n;
  float R[9];
  R[0] = 1.f - 2.f*(y*y + z*z); R[1] = 2.f*(x*y - w*z); R[2] = 2.f*(x*z + w*y);
  R[3] = 2.f*(x*y + w*z); R[4] = 1.f - 2.f*(x*x + z*z); R[5] = 2.f*(y*z - w*x);
  R[6] = 2.f*(x*z - w*y); R[7] = 2.f*(y*z + w*x); R[8] = 1.f - 2.f*(x*x + y*y);
  float Kf[9], Ki[9];
  for (int i = 0; i < 9; i++){ Kf[i] = ldg_(K,i,f); Ki[i] = ldg_(Kinv,i,f); }
  float T[9];
  for (int r = 0; r < 3; r++)
    for (int c = 0; c < 3; c++)
      T[r*3+c] = R[r*3+0]*Ki[0*3+c] + R[r*3+1]*Ki[1*3+c] + R[r*3+2]*Ki[2*3+c];
  for (int r = 0; r < 3; r++)
    for (int c = 0; c < 3; c++)
      Mout[b*9 + r*3 + c] = Kf[r*3+0]*T[0*3+c] + Kf[r*3+1]*T[1*3+c] + Kf[r*3+2]*T[2*3+c];
}

// ---------------------------------------- rotation-flow, column (W 1024->64) pass
__global__ void k_rflow_col(const float* __restrict__ Mws, float* __restrict__ tmpA){
  int t = blockIdx.x * 256 + threadIdx.x;      // 16*448*64 = 458752 exactly
  int xo = t & 63;
  int yf = (t >> 6) % 448;
  int b  = t / (448*64);
  const float* M = Mws + b*9;
  float m0=M[0],m1=M[1],m2=M[2],m3=M[3],m4=M[4],m5=M[5],m6=M[6],m7=M[7],m8=M[8];
  float cx = 16.f*xo + 7.5f;
  float yff = (float)yf;
  float su = 0.f, sv = 0.f, wsum = 0.f;
  for (int i = 0; i < 32; i++){
    int xi = 16*xo - 8 + i;
    if (xi < 0 || xi > 1023) continue;
    float xf = (float)xi;
    float wgt = 1.f - fabsf(xf - cx) * (1.f/16.f);
    float den = m6*xf + m7*yff + m8;
    float inv = 1.f / den;
    float u = (m0*xf + m1*yff + m2)*inv - xf;
    float v = (m3*xf + m4*yff + m5)*inv - yff;
    su += wgt*u; sv += wgt*v; wsum += wgt;
  }
  float rn = 1.f / wsum;
  tmpA[((size_t)(b*2+0)*64 + xo)*448 + yf] = su*rn;
  tmpA[((size_t)(b*2+1)*64 + xo)*448 + yf] = sv*rn;
}

// ---------------------------------------- rotation-flow, row (448->28) + /SCALE
__global__ void k_rflow_row(const float* __restrict__ tmpA, float* __restrict__ rfr,
                            void* __restrict__ outb, const void* probe){
  bool f = is_f32(probe);
  int t = blockIdx.x * 256 + threadIdx.x;      // 28672 exactly
  int xo = t & 63;
  int yo = (t >> 6) % 28;
  int b  = t / HW4;
  float cy = 16.f*yo + 7.5f;
  for (int c = 0; c < 2; c++){
    const float* col = tmpA + ((size_t)(b*2+c)*64 + xo)*448;
    float s = 0.f, wsum = 0.f;
    for (int i = 0; i < 32; i++){
      int yi = 16*yo - 8 + i;
      if (yi < 0 || yi > 447) continue;
      float wgt = 1.f - fabsf((float)yi - cy) * (1.f/16.f);
      s += wgt * col[yi]; wsum += wgt;
    }
    float val = s / (wsum * 16.0f);   // includes /SCALE
    rfr[(size_t)(b*2+c)*HW4 + yo*64 + xo] = val;
    stg_(outb, OUTOFF + ((size_t)b*FCH + 529 + c)*HW4 + yo*64 + xo, val, f);
  }
}

// ---------------------------------------------------- deconv4s2 of prev_flow (2ch)
__global__ void k_dflow(const void* __restrict__ pf, const void* __restrict__ w,
                        const void* __restrict__ bias, float* __restrict__ tflow,
                        void* __restrict__ outb, const void* probe){
  bool f = is_f32(probe);
  int t = blockIdx.x * 256 + threadIdx.x;      // 57344 exactly
  int x = t & 63;
  int y = (t >> 6) % 28;
  int co = (t / HW4) & 1;
  int b  = t / (2*HW4);
  float acc = ldg_(bias, co, f);
  for (int ky = 0; ky < 4; ky++){
    int dy = y + ky - 2;
    if (dy < 0 || dy > 26 || (dy & 1)) continue;
    int iy = dy >> 1;
    for (int kx = 0; kx < 4; kx++){
      int dx = x + kx - 2;
      if (dx < 0 || dx > 62 || (dx & 1)) continue;
      int ix = dx >> 1;
      for (int ci = 0; ci < 2; ci++){
        acc += ldg_(pf, ((size_t)(b*2+ci)*14 + iy)*32 + ix, f) *
               ldg_(w,  (size_t)ci*32 + co*16 + (3-ky)*4 + (3-kx), f);
      }
    }
  }
  tflow[(size_t)(b*2+co)*HW4 + y*64 + x] = acc;
  stg_(outb, OUTOFF + ((size_t)b*FCH + 627 + co)*HW4 + y*64 + x, acc, f);
}

// ---------------------------------------------------- deconv4s2 of prev_feat (663->2)
__global__ void k_dfeat(const void* __restrict__ pfeat, const void* __restrict__ w,
                        const void* __restrict__ bias, void* __restrict__ outb,
                        const void* probe){
  bool f = is_f32(probe);
  int t = blockIdx.x * 256 + threadIdx.x;      // 57344 exactly
  int x = t & 63;
  int y = (t >> 6) % 28;
  int co = (t / HW4) & 1;
  int b  = t / (2*HW4);
  float acc = ldg_(bias, co, f);
  if (f){
    const float* pin = (const float*)pfeat + (size_t)b*663*448;
    const float* wf  = (const float*)w;
    for (int ky = 0; ky < 4; ky++){
      int dy = y + ky - 2;
      if (dy < 0 || dy > 26 || (dy & 1)) continue;
      int iy = dy >> 1;
      for (int kx = 0; kx < 4; kx++){
        int dx = x + kx - 2;
        if (dx < 0 || dx > 62 || (dx & 1)) continue;
        int ix = dx >> 1;
        const float* ip = pin + iy*32 + ix;
        const float* wp = wf + co*16 + (3-ky)*4 + (3-kx);
        #pragma unroll 4
        for (int ci = 0; ci < 663; ci++) acc += ip[ci*448] * wp[ci*32];
      }
    }
  } else {
    const u16* pin = (const u16*)pfeat + (size_t)b*663*448;
    const u16* wf  = (const u16*)w;
    for (int ky = 0; ky < 4; ky++){
      int dy = y + ky - 2;
      if (dy < 0 || dy > 26 || (dy & 1)) continue;
      int iy = dy >> 1;
      for (int kx = 0; kx < 4; kx++){
        int dx = x + kx - 2;
        if (dx < 0 || dx > 62 || (dx & 1)) continue;
        int ix = dx >> 1;
        const u16* ip = pin + iy*32 + ix;
        const u16* wp = wf + co*16 + (3-ky)*4 + (3-kx);
        #pragma unroll 4
        for (int ci = 0; ci < 663; ci++) acc += b2f(ip[ci*448]) * b2f(wp[ci*32]);
      }
    }
  }
  stg_(outb, OUTOFF + ((size_t)b*FCH + 629 + co)*HW4 + y*64 + x, acc, f);
}

// ---------------------------------------------------------------- copy tenOne into feat
__global__ void k_copy_one(const void* __restrict__ one, void* __restrict__ outb,
                           const void* probe){
  bool f = is_f32(probe);
  int t = blockIdx.x * 256 + threadIdx.x;      // 2752512 exactly
  int p = t % HW4;
  int c = (t / HW4) % 96;
  int b = t / (96*HW4);
  stg_(outb, OUTOFF + ((size_t)b*FCH + 531 + c)*HW4 + p,
       ldg_(one, (size_t)(b*96+c)*HW4 + p, f), f);
}

// ------------------------------------------- fused double-warp of tenTwo (16-pt gather)
__global__ void k_warp2(const void* __restrict__ two, const float* __restrict__ rfr,
                        const float* __restrict__ tflow, float* __restrict__ wrp2,
                        const void* probe){
  bool f = is_f32(probe);
  int t = blockIdx.x * 256 + threadIdx.x;      // 2752512 exactly
  int x = t & 63;
  int y = (t >> 6) % 28;
  int c = (t / HW4) % 96;
  int b = t / (96*HW4);
  float qu = tflow[(size_t)(b*2+0)*HW4 + y*64 + x] * 1.25f;
  float qv = tflow[(size_t)(b*2+1)*HW4 + y*64 + x] * 1.25f;
  float qx = (float)x + qu, qy = (float)y + qv;
  float qx0 = floorf(qx), qy0 = floorf(qy);
  float wx = qx - qx0, wy = qy - qy0;
  const size_t cb = (size_t)(b*96+c)*HW4;
  float acc = 0.f;
  #pragma unroll
  for (int a = 0; a < 2; a++){
    #pragma unroll
    for (int bb = 0; bb < 2; bb++){
      float ry = qy0 + (float)a, rx = qx0 + (float)bb;
      if (ry < 0.f || ry > 27.f || rx < 0.f || rx > 63.f) continue;
      float W = (a ? wy : 1.f-wy) * (bb ? wx : 1.f-wx);
      int iry = (int)ry, irx = (int)rx;
      float su = rfr[(size_t)(b*2+0)*HW4 + iry*64 + irx];
      float sv = rfr[(size_t)(b*2+1)*HW4 + iry*64 + irx];
      float sx = rx + su, sy = ry + sv;
      float sx0 = floorf(sx), sy0 = floorf(sy);
      float swx = sx - sx0, swy = sy - sy0;
      float inner = 0.f;
      #pragma unroll
      for (int aa = 0; aa < 2; aa++){
        #pragma unroll
        for (int cc2 = 0; cc2 < 2; cc2++){
          float gy2 = sy0 + (float)aa, gx2 = sx0 + (float)cc2;
          if (gy2 < 0.f || gy2 > 27.f || gx2 < 0.f || gx2 > 63.f) continue;
          float wv = (aa ? swy : 1.f-swy) * (cc2 ? swx : 1.f-swx);
          inner += wv * ldg_(two, cb + (size_t)((int)gy2*64 + (int)gx2), f);
        }
      }
      acc += W * inner;
    }
  }
  wrp2[t] = acc;
}

// ---------------------------------------------------------------- correlation (81 ch)
__global__ void k_corr(const void* __restrict__ one, const float* __restrict__ two,
                       void* __restrict__ outb, const void* probe){
  bool f = is_f32(probe);
  int t = blockIdx.x * 256 + threadIdx.x;      // 16*9*1792 = 258048 exactly
  int x  = t & 63;
  int y  = (t >> 6) % 28;
  int dy = (t / HW4) % 9;
  int b  = t / (9*HW4);
  float acc[9];
  #pragma unroll
  for (int i = 0; i < 9; i++) acc[i] = 0.f;
  int row = y + dy - 4;
  if (row >= 0 && row < 28){
    for (int c = 0; c < 96; c++){
      float f1 = ldg_(one, (size_t)(b*96+c)*HW4 + y*64 + x, f);
      const float* rp = two + (size_t)(b*96+c)*HW4 + row*64;
      #pragma unroll
      for (int dx = 0; dx < 9; dx++){
        int xx = x + dx - 4;
        if (xx >= 0 && xx < 64) acc[dx] += f1 * rp[xx];
      }
    }
  }
  #pragma unroll
  for (int dx = 0; dx < 9; dx++){
    float v = lrelu(acc[dx] * (1.f/96.f));
    stg_(outb, OUTOFF + ((size_t)b*FCH + 448 + dy*9 + dx)*HW4 + y*64 + x, v, f);
  }
}

// ---------------------------------------------------------------- 3x3 conv + lrelu
// VALU path — runs ONLY when data is f32 (runtime probe); bf16 goes through MFMA path.
__global__ __launch_bounds__(256) void k_conv(
    void* __restrict__ base, size_t in_off,
    const void* __restrict__ w, const void* __restrict__ bias,
    int Cin, int Cout, size_t out_off, size_t out_bstr, const void* probe){
  bool f = is_f32(probe);
  if (!f) return;
  __shared__ float s_in[32*3*66];    // 25344 B
  __shared__ float s_w[32*9*32];     // 36864 B
  int tid = threadIdx.x;
  int x = tid & 63;
  int g = tid >> 6;
  int by = blockIdx.x;
  int b = by / 28, y = by % 28;
  int co_base = blockIdx.y * 32;
  const size_t FB = (size_t)FCH * HW4;
  float acc[8];
  #pragma unroll
  for (int j = 0; j < 8; j++) acc[j] = 0.f;

  for (int ci0 = 0; ci0 < Cin; ci0 += 32){
    int cc = min(32, Cin - ci0);
    const float* inb = (const float*)base + in_off + (size_t)b*FB;
    for (int e = tid; e < cc*198; e += 256){
      int ci = e / 198; int rem = e - ci*198;
      int r = rem / 66; int xx = rem - r*66;
      int iy = y + r - 1; int ix = xx - 1;
      float v = 0.f;
      if (iy >= 0 && iy < 28 && ix >= 0 && ix < 64)
        v = inb[(size_t)(ci0+ci)*HW4 + iy*64 + ix];
      s_in[(ci*3 + r)*66 + xx] = v;
    }
    const float* wf = (const float*)w;
    for (int e = tid; e < cc*288; e += 256){
      int co_i = e & 31; int k = (e >> 5) % 9; int ci = e / 288;
      int co = co_base + co_i;
      float v = 0.f;
      if (co < Cout) v = wf[((size_t)co*Cin + ci0 + ci)*9 + k];
      s_w[(ci*9 + k)*32 + co_i] = v;
    }
    __syncthreads();
    for (int ci = 0; ci < cc; ci++){
      const float* si = &s_in[ci*198 + x];
      const float* sw = &s_w[ci*288 + 8*g];
      #pragma unroll
      for (int ky = 0; ky < 3; ky++){
        #pragma unroll
        for (int kx = 0; kx < 3; kx++){
          float v = si[ky*66 + kx];
          const float* wp = sw + (ky*3 + kx)*32;
          float4 wa = *(const float4*)(wp);
          float4 wb = *(const float4*)(wp + 4);
          acc[0] += wa.x*v; acc[1] += wa.y*v; acc[2] += wa.z*v; acc[3] += wa.w*v;
          acc[4] += wb.x*v; acc[5] += wb.y*v; acc[6] += wb.z*v; acc[7] += wb.w*v;
        }
      }
    }
    __syncthreads();
  }
  #pragma unroll
  for (int j = 0; j < 8; j++){
    int co = co_base + 8*g + j;
    if (co < Cout){
      float v = lrelu(acc[j] + ((const float*)bias)[co]);
      ((float*)base)[out_off + (size_t)b*out_bstr + (size_t)co*HW4 + y*64 + x] = v;
    }
  }
}

// --------------------------------------------------------- weight fragment-linearize (bf16)
// wT idx = ((((gyb*nCB + cb)*9 + tap)*4 + tI)*64 + lane)*8 + j
// ci = cb*32 + (lane>>4)*8 + j ; co = gyb*64 + tI*16 + (lane&15) ; zero-padded.
__global__ void k_wprep(const void* __restrict__ w, u16* __restrict__ wT,
                        int Cin, int Cout, int nCB, int total,
                        u16* __restrict__ zbuf, const void* probe){
  if (is_f32(probe)) return;           // bf16 path only
  int t = blockIdx.x * 256 + threadIdx.x;
  if (zbuf && t < 32) zbuf[t] = 0;     // 64 B zero page for staging redirects
  if (t >= total) return;
  int j     = t & 7;
  int lane  = (t >> 3) & 63;
  int rest  = t >> 9;
  int tI    = rest & 3;
  int rest2 = rest >> 2;
  int tap   = rest2 % 9;
  int gc    = rest2 / 9;
  int cb    = gc % nCB;
  int gyb   = gc / nCB;
  int ci = cb*32 + ((lane >> 4) << 3) + j;
  int co = gyb*64 + tI*16 + (lane & 15);
  u16 v = 0;
  if (co < Cout && ci < Cin) v = ((const u16*)w)[((size_t)co*Cin + ci)*9 + tap];
  wT[t] = v;
}

// --------------------------------------------------------- 3x3 conv via native bf16 MFMA
// Block: 256 thr = 4 waves; wave wv owns output row y0+wv, 64 co, 64 x.
// Grid: (112 = 16b * 7 row-quads, ceil(Cout/64)).
// K decomposed per tap: acc[co][x] += W[tap][co][ci] * In[ci][y+ky-1][x+kx-1].
// LDS 61440 B (linear, GLL16-staged):
//   input  [0,24576): 128B tiles T=(ciq*6+r)*4+xc, inside [cir:4][xr:16] bf16
//                     (exactly the ds_read_b64_tr_b16 [.][4][16] subtiling)
//   weight [24576,61440): fragment-linear, conflict-free ds_read_b128 A-frags.
__global__ __launch_bounds__(256, 2) void k_conv_mf(
    void* __restrict__ base, size_t in_off, const u16* __restrict__ wT,
    const void* __restrict__ bias, int Cin, int nCB, int Cout,
    size_t out_off, size_t out_bstr, const u16* __restrict__ zbuf,
    const void* __restrict__ probe){
  if (is_f32(probe)) return;           // bf16 path only
  __shared__ __align__(16) u16 lds[30720];   // 61440 B
  const int tid  = threadIdx.x;
  const int lane = tid & 63, wv = tid >> 6;
  const int lx = lane & 15, lg = lane >> 4;
  const int b  = blockIdx.x & 15;
  const int y0 = (blockIdx.x >> 4) * 4;
  const int coB = (int)blockIdx.y * 64;
  const u16* inb = (const u16*)base + in_off + (size_t)b * ((size_t)FCH * HW4);
  const u16* wTg = wT + (size_t)blockIdx.y * (size_t)nCB * 18432;
  const uint32_t lbase = (uint32_t)(uintptr_t)&lds[0];

  f32x4 acc[4][4];
  #pragma unroll
  for (int t2 = 0; t2 < 4; t2++)
    #pragma unroll
    for (int xg = 0; xg < 4; xg++) acc[t2][xg] = zero4();

  // per-kx fragment x-offset: xoff = lx + kx - 1 in [-1..16]; clamp -1 -> 0 (value zeroed)
  int offx[3];
  #pragma unroll
  for (int kx = 0; kx < 3; kx++){
    int xo = lx + kx - 1; if (xo < 0) xo = 0;
    offx[kx] = ((xo >> 4) * 128) + ((xo & 15) * 2);
  }

  for (int cb = 0; cb < nCB; cb++){
    // ---- weights: 36864 B = 36 wave-issues of global_load_lds x16B (pre-padded, linear)
    const u16* wsrc = wTg + (size_t)cb * 18432;
    #pragma unroll
    for (int i = 0; i < 9; i++){
      int cc = wv*9 + i;                       // chunk-group 0..35
      GLL16(wsrc + (size_t)(cc*64 + lane)*8, lbase + 24576u + (uint32_t)cc*1024u);
    }
    // ---- input: 24576 B = 24 wave-issues; chunk c -> (ci,row,x-octet), zbuf for halo/tail
    #pragma unroll
    for (int i = 0; i < 6; i++){
      int c   = (wv*6 + i)*64 + lane;          // 0..1535
      int xo1 = c & 1;
      int cir = (c >> 1) & 3;
      int xc  = (c >> 3) & 3;
      int q   = c >> 5;                        // 0..47
      int r   = q % 6;
      int ciq = q / 6;
      int ci  = cb*32 + ciq*4 + cir;
      int row = y0 - 1 + r;
      int x0  = (xc*2 + xo1)*8;
      const u16* src = (row >= 0 && row < 28 && ci < Cin)
                     ? (inb + (size_t)ci*HW4 + row*64 + x0) : zbuf;
      GLL16(src, lbase + (uint32_t)c*16u);
    }
    __syncthreads();
    // ---- 9 taps x (4 co-tiles x 4 x-tiles) MFMA
    #pragma unroll
    for (int ky = 0; ky < 3; ky++){
      #pragma unroll
      for (int kx = 0; kx < 3; kx++){
        const int k = ky*3 + kx;
        // B frags: lane lx -> x col, lg -> ci octet; pair tile at +24 tiles (=+3072B)
        uint32_t ab = lbase + (uint32_t)((12*lg + wv + ky) * 512) + (uint32_t)offx[kx];
        uint2v t0,t1,t2,t3,t4,t5,t6,t7;
        TRR(t0, ab);         TRR(t1, ab + 3072u);
        TRR(t2, ab + 128u);  TRR(t3, ab + 3200u);
        TRR(t4, ab + 256u);  TRR(t5, ab + 3328u);
        TRR(t6, ab + 384u);  TRR(t7, ab + 3456u);
        asm volatile("s_waitcnt lgkmcnt(0)" ::: "memory");
        __builtin_amdgcn_sched_barrier(0);     // rule 18: fence asm ds_read consumers
        short8 B0 = pack8(t0,t1), B1 = pack8(t2,t3);
        short8 B2 = pack8(t4,t5), B3 = pack8(t6,t7);
        if (kx == 0 && lx == 0)  B0 = zero8(); // x_in = -1
        if (kx == 2 && lx == 15) B3 = zero8(); // x_in = 64
        #pragma unroll
        for (int t2i = 0; t2i < 4; t2i++){
          short8 Af = *(const short8*)&lds[12288 + ((k*4 + t2i)*64 + lane)*8];
          acc[t2i][0] = __builtin_amdgcn_mfma_f32_16x16x32_bf16(Af, B0, acc[t2i][0], 0,0,0);
          acc[t2i][1] = __builtin_amdgcn_mfma_f32_16x16x32_bf16(Af, B1, acc[t2i][1], 0,0,0);
          acc[t2i][2] = __builtin_amdgcn_mfma_f32_16x16x32_bf16(Af, B2, acc[t2i][2], 0,0,0);
          acc[t2i][3] = __builtin_amdgcn_mfma_f32_16x16x32_bf16(Af, B3, acc[t2i][3], 0,0,0);
        }
      }
    }
    __syncthreads();
  }
  // epilogue: bias + lrelu + bf16 store. D: col=lane&15 -> x, row=(lane>>4)*4+reg -> co
  u16* ob = (u16*)base;
  const u16* bb = (const u16*)bias;
  const int y = y0 + wv;
  #pragma unroll
  for (int t2 = 0; t2 < 4; t2++){
    #pragma unroll
    for (int xg = 0; xg < 4; xg++){
      const int x = xg*16 + lx;
      #pragma unroll
      for (int r = 0; r < 4; r++){
        int co = coB + t2*16 + lg*4 + r;
        if (co < Cout){
          float v = lrelu(acc[t2][xg][r] + b2f(bb[co]));
          ob[out_off + (size_t)b*out_bstr + (size_t)co*HW4 + (size_t)(y*64 + x)] = f2b(v);
        }
      }
    }
  }
}

// ----------------------------------------------------------------------------------
extern "C" void kernel_launch(void* const* d_in, const int* in_sizes, int n_in,
                              void* d_out, int out_size, void* d_ws, size_t ws_size,
                              hipStream_t stream){
  const void* tenOne    = d_in[0];
  const void* tenTwo    = d_in[1];
  const void* prev_flow = d_in[2];
  const void* prev_feat = d_in[3];
  const void* quat      = d_in[4];
  const void* K         = d_in[5];
  const void* Kinv      = d_in[6];
  const void* upflow_w  = d_in[7];
  const void* upflow_b  = d_in[8];
  const void* upfeat_w  = d_in[9];
  const void* upfeat_b  = d_in[10];
  const void* w1 = d_in[11];  const void* b1 = d_in[12];
  const void* w2 = d_in[13];  const void* b2 = d_in[14];
  const void* w3 = d_in[15];  const void* b3 = d_in[16];
  const void* w4 = d_in[17];  const void* b4 = d_in[18];
  const void* w5 = d_in[19];  const void* b5 = d_in[20];
  const void* w6 = d_in[21];  const void* b6 = d_in[22];
  const void* probe = K;    // cam_intri[0]==500.0 discriminates dtype (runtime-only!)

  float* ws    = (float*)d_ws;
  float* Mws   = ws;                         // 160
  float* tmpA  = ws + 160;                   // 917504
  float* rfr   = ws + 917664;                // 57344
  float* tflow = ws + 975008;                // 57344
  float* wrp2  = ws + 1032352;               // 2752512 (end 3784864 floats ~15.1MB)
  u16*   zbuf  = (u16*)(ws + 3784864);       // 64 B zero page (zeroed by k_wprep L1)
  u16*   wTb   = zbuf + 32;                  // 2138112 u16 (~4.3MB) fragment weights

  k_M<<<1, 64, 0, stream>>>(quat, K, Kinv, Mws);
  k_rflow_col<<<1792, 256, 0, stream>>>(Mws, tmpA);
  k_rflow_row<<<112, 256, 0, stream>>>(tmpA, rfr, d_out, probe);
  k_dflow<<<224, 256, 0, stream>>>(prev_flow, upflow_w, upflow_b, tflow, d_out, probe);
  k_dfeat<<<224, 256, 0, stream>>>(prev_feat, upfeat_w, upfeat_b, d_out, probe);
  k_copy_one<<<10752, 256, 0, stream>>>(tenOne, d_out, probe);
  k_warp2<<<10752, 256, 0, stream>>>(tenTwo, rfr, tflow, wrp2, probe);
  k_corr<<<1008, 256, 0, stream>>>(tenOne, wrp2, d_out, probe);

  const size_t FB = (size_t)FCH * HW4;
  const size_t f0 = OUTOFF;

  struct LD { const void *w, *bi; int Cin, Cout, nCB, gy; size_t wOff, in_off, out_off, out_bstr; };
  const LD L[6] = {
    { w1, b1, 183, 128,  6, 2, 0,       f0+(size_t)448*HW4, f0+(size_t)320*HW4, FB },
    { w2, b2, 311, 128, 10, 2, 221184,  f0+(size_t)320*HW4, f0+(size_t)192*HW4, FB },
    { w3, b3, 439,  96, 14, 2, 589824,  f0+(size_t)192*HW4, f0+(size_t) 96*HW4, FB },
    { w4, b4, 535,  64, 17, 1, 1105920, f0+(size_t) 96*HW4, f0+(size_t) 32*HW4, FB },
    { w5, b5, 599,  32, 19, 1, 1419264, f0+(size_t) 32*HW4, f0,                 FB },
    { w6, b6, 631,   2, 20, 1, 1769472, f0,                 0,        (size_t)2*HW4 },
  };

  // bf16 MFMA path (self-gated: early-out when probe says f32)
  for (int i = 0; i < 6; i++){
    int total = L[i].gy * L[i].nCB * 18432;
    k_wprep<<<(total + 255)/256, 256, 0, stream>>>(
        L[i].w, wTb + L[i].wOff, L[i].Cin, L[i].Cout, L[i].nCB, total,
        (i == 0) ? zbuf : (u16*)nullptr, probe);
  }
  for (int i = 0; i < 6; i++){
    k_conv_mf<<<dim3(112, L[i].gy), 256, 0, stream>>>(
        d_out, L[i].in_off, wTb + L[i].wOff, L[i].bi,
        L[i].Cin, L[i].nCB, L[i].Cout,
        L[i].out_off, L[i].out_bstr, zbuf, probe);
  }

  // f32 VALU fallback path (self-gated: early-out when probe says bf16)
  k_conv<<<dim3(448,4), 256, 0, stream>>>(d_out, f0 + (size_t)448*HW4, w1, b1, 183, 128,
                                          f0 + (size_t)320*HW4, FB, probe);
  k_conv<<<dim3(448,4), 256, 0, stream>>>(d_out, f0 + (size_t)320*HW4, w2, b2, 311, 128,
                                          f0 + (size_t)192*HW4, FB, probe);
  k_conv<<<dim3(448,3), 256, 0, stream>>>(d_out, f0 + (size_t)192*HW4, w3, b3, 439, 96,
                                          f0 + (size_t)96*HW4, FB, probe);
  k_conv<<<dim3(448,2), 256, 0, stream>>>(d_out, f0 + (size_t)96*HW4, w4, b4, 535, 64,
                                          f0 + (size_t)32*HW4, FB, probe);
  k_conv<<<dim3(448,1), 256, 0, stream>>>(d_out, f0 + (size_t)32*HW4, w5, b5, 599, 32,
                                          f0, FB, probe);
  k_conv<<<dim3(448,1), 256, 0, stream>>>(d_out, f0, w6, b6, 631, 2,
                                          0, (size_t)2*HW4, probe);
}

// Round 4
// 1933.397 us; speedup vs baseline: 3.0916x; 3.0617x over previous
//
#include <hip/hip_runtime.h>
#include <cstdint>
#include <cstddef>

typedef unsigned short u16;
typedef __attribute__((ext_vector_type(8))) short  short8;
typedef __attribute__((ext_vector_type(4))) float  f32x4;

#define HW4   1792      // 28*64
#define FCH   631       // final feat channels
#define OUTOFF ((size_t)57344)   // feat region element offset in d_out

__device__ __forceinline__ float b2f(u16 u){
  union { unsigned int i; float f; } v; v.i = ((unsigned int)u) << 16; return v.f;
}
__device__ __forceinline__ u16 f2b(float f){
  unsigned int x = __float_as_uint(f);
  return (u16)((x + 0x7fffu + ((x >> 16) & 1u)) >> 16);
}
__device__ __forceinline__ float lrelu(float v){ return v >= 0.f ? v : 0.1f * v; }
// dtype probe: cam_intri[0]=500.0. bf16 pair read as float -> 2.4e-41 ; fp32 -> 500.0
__device__ __forceinline__ bool is_f32(const void* probe){ return ((const float*)probe)[0] > 1.0f; }
__device__ __forceinline__ float ldg_(const void* p, size_t i, bool f){
  return f ? ((const float*)p)[i] : b2f(((const u16*)p)[i]);
}
__device__ __forceinline__ void stg_(void* p, size_t i, float v, bool f){
  if (f) ((float*)p)[i] = v; else ((u16*)p)[i] = f2b(v);
}
__device__ __forceinline__ short8 zero8(){
  union { long long l[2]; short8 s; } z; z.l[0] = 0; z.l[1] = 0; return z.s;
}
__device__ __forceinline__ f32x4 zero4(){
  union { long long l[2]; f32x4 s; } z; z.l[0] = 0; z.l[1] = 0; return z.s;
}
// swap 16b halves of each dword: K-slot j <-> j^1 (hi/lo plane exchange)
__device__ __forceinline__ short8 swap16(short8 v){
  union { short8 s; unsigned int u[4]; } a, r;
  a.s = v;
  #pragma unroll
  for (int i = 0; i < 4; i++) r.u[i] = (a.u[i] >> 16) | (a.u[i] << 16);
  return r.s;
}

// ---------------------------------------------------------------- M = K R(q) Kinv
__global__ void k_M(const void* __restrict__ quat, const void* __restrict__ K,
                    const void* __restrict__ Kinv, float* __restrict__ Mout){
  bool f = is_f32(K);
  int b = threadIdx.x;
  if (b >= 16) return;
  float q0 = ldg_(quat,b*4+0,f), q1 = ldg_(quat,b*4+1,f);
  float q2 = ldg_(quat,b*4+2,f), q3 = ldg_(quat,b*4+3,f);
  float n = sqrtf(q0*q0 + q1*q1 + q2*q2 + q3*q3);
  float w = q0/n, x = q1/n, y = q2/n, z = q3/n;
  float R[9];
  R[0] = 1.f - 2.f*(y*y + z*z); R[1] = 2.f*(x*y - w*z); R[2] = 2.f*(x*z + w*y);
  R[3] = 2.f*(x*y + w*z); R[4] = 1.f - 2.f*(x*x + z*z); R[5] = 2.f*(y*z - w*x);
  R[6] = 2.f*(x*z - w*y); R[7] = 2.f*(y*z + w*x); R[8] = 1.f - 2.f*(x*x + y*y);
  float Kf[9], Ki[9];
  for (int i = 0; i < 9; i++){ Kf[i] = ldg_(K,i,f); Ki[i] = ldg_(Kinv,i,f); }
  float T[9];
  for (int r = 0; r < 3; r++)
    for (int c = 0; c < 3; c++)
      T[r*3+c] = R[r*3+0]*Ki[0*3+c] + R[r*3+1]*Ki[1*3+c] + R[r*3+2]*Ki[2*3+c];
  for (int r = 0; r < 3; r++)
    for (int c = 0; c < 3; c++)
      Mout[b*9 + r*3 + c] = Kf[r*3+0]*T[0*3+c] + Kf[r*3+1]*T[1*3+c] + Kf[r*3+2]*T[2*3+c];
}

// ---------------------------------------- rotation-flow, column (W 1024->64) pass
__global__ void k_rflow_col(const float* __restrict__ Mws, float* __restrict__ tmpA){
  int t = blockIdx.x * 256 + threadIdx.x;      // 16*448*64 = 458752 exactly
  int xo = t & 63;
  int yf = (t >> 6) % 448;
  int b  = t / (448*64);
  const float* M = Mws + b*9;
  float m0=M[0],m1=M[1],m2=M[2],m3=M[3],m4=M[4],m5=M[5],m6=M[6],m7=M[7],m8=M[8];
  float cx = 16.f*xo + 7.5f;
  float yff = (float)yf;
  float su = 0.f, sv = 0.f, wsum = 0.f;
  for (int i = 0; i < 32; i++){
    int xi = 16*xo - 8 + i;
    if (xi < 0 || xi > 1023) continue;
    float xf = (float)xi;
    float wgt = 1.f - fabsf(xf - cx) * (1.f/16.f);
    float den = m6*xf + m7*yff + m8;
    float inv = 1.f / den;
    float u = (m0*xf + m1*yff + m2)*inv - xf;
    float v = (m3*xf + m4*yff + m5)*inv - yff;
    su += wgt*u; sv += wgt*v; wsum += wgt;
  }
  float rn = 1.f / wsum;
  tmpA[((size_t)(b*2+0)*64 + xo)*448 + yf] = su*rn;
  tmpA[((size_t)(b*2+1)*64 + xo)*448 + yf] = sv*rn;
}

// ---------------------------------------- rotation-flow, row (448->28) + /SCALE
__global__ void k_rflow_row(const float* __restrict__ tmpA, float* __restrict__ rfr,
                            void* __restrict__ outb, const void* probe){
  bool f = is_f32(probe);
  int t = blockIdx.x * 256 + threadIdx.x;      // 28672 exactly
  int xo = t & 63;
  int yo = (t >> 6) % 28;
  int b  = t / HW4;
  float cy = 16.f*yo + 7.5f;
  for (int c = 0; c < 2; c++){
    const float* col = tmpA + ((size_t)(b*2+c)*64 + xo)*448;
    float s = 0.f, wsum = 0.f;
    for (int i = 0; i < 32; i++){
      int yi = 16*yo - 8 + i;
      if (yi < 0 || yi > 447) continue;
      float wgt = 1.f - fabsf((float)yi - cy) * (1.f/16.f);
      s += wgt * col[yi]; wsum += wgt;
    }
    float val = s / (wsum * 16.0f);   // includes /SCALE
    rfr[(size_t)(b*2+c)*HW4 + yo*64 + xo] = val;
    stg_(outb, OUTOFF + ((size_t)b*FCH + 529 + c)*HW4 + yo*64 + xo, val, f);
  }
}

// ---------------------------------------------------- deconv4s2 of prev_flow (2ch)
__global__ void k_dflow(const void* __restrict__ pf, const void* __restrict__ w,
                        const void* __restrict__ bias, float* __restrict__ tflow,
                        void* __restrict__ outb, const void* probe){
  bool f = is_f32(probe);
  int t = blockIdx.x * 256 + threadIdx.x;      // 57344 exactly
  int x = t & 63;
  int y = (t >> 6) % 28;
  int co = (t / HW4) & 1;
  int b  = t / (2*HW4);
  float acc = ldg_(bias, co, f);
  for (int ky = 0; ky < 4; ky++){
    int dy = y + ky - 2;
    if (dy < 0 || dy > 26 || (dy & 1)) continue;
    int iy = dy >> 1;
    for (int kx = 0; kx < 4; kx++){
      int dx = x + kx - 2;
      if (dx < 0 || dx > 62 || (dx & 1)) continue;
      int ix = dx >> 1;
      for (int ci = 0; ci < 2; ci++){
        acc += ldg_(pf, ((size_t)(b*2+ci)*14 + iy)*32 + ix, f) *
               ldg_(w,  (size_t)ci*32 + co*16 + (3-ky)*4 + (3-kx), f);
      }
    }
  }
  tflow[(size_t)(b*2+co)*HW4 + y*64 + x] = acc;
  stg_(outb, OUTOFF + ((size_t)b*FCH + 627 + co)*HW4 + y*64 + x, acc, f);
}

// ---------------------------------------------------- deconv4s2 of prev_feat (663->2)
__global__ void k_dfeat(const void* __restrict__ pfeat, const void* __restrict__ w,
                        const void* __restrict__ bias, void* __restrict__ outb,
                        const void* probe){
  bool f = is_f32(probe);
  int t = blockIdx.x * 256 + threadIdx.x;      // 57344 exactly
  int x = t & 63;
  int y = (t >> 6) % 28;
  int co = (t / HW4) & 1;
  int b  = t / (2*HW4);
  float acc = ldg_(bias, co, f);
  if (f){
    const float* pin = (const float*)pfeat + (size_t)b*663*448;
    const float* wf  = (const float*)w;
    for (int ky = 0; ky < 4; ky++){
      int dy = y + ky - 2;
      if (dy < 0 || dy > 26 || (dy & 1)) continue;
      int iy = dy >> 1;
      for (int kx = 0; kx < 4; kx++){
        int dx = x + kx - 2;
        if (dx < 0 || dx > 62 || (dx & 1)) continue;
        int ix = dx >> 1;
        const float* ip = pin + iy*32 + ix;
        const float* wp = wf + co*16 + (3-ky)*4 + (3-kx);
        #pragma unroll 4
        for (int ci = 0; ci < 663; ci++) acc += ip[ci*448] * wp[ci*32];
      }
    }
  } else {
    const u16* pin = (const u16*)pfeat + (size_t)b*663*448;
    const u16* wf  = (const u16*)w;
    for (int ky = 0; ky < 4; ky++){
      int dy = y + ky - 2;
      if (dy < 0 || dy > 26 || (dy & 1)) continue;
      int iy = dy >> 1;
      for (int kx = 0; kx < 4; kx++){
        int dx = x + kx - 2;
        if (dx < 0 || dx > 62 || (dx & 1)) continue;
        int ix = dx >> 1;
        const u16* ip = pin + iy*32 + ix;
        const u16* wp = wf + co*16 + (3-ky)*4 + (3-kx);
        #pragma unroll 4
        for (int ci = 0; ci < 663; ci++) acc += b2f(ip[ci*448]) * b2f(wp[ci*32]);
      }
    }
  }
  stg_(outb, OUTOFF + ((size_t)b*FCH + 629 + co)*HW4 + y*64 + x, acc, f);
}

// ---------------------------------------------------------------- copy tenOne into feat
__global__ void k_copy_one(const void* __restrict__ one, void* __restrict__ outb,
                           const void* probe){
  bool f = is_f32(probe);
  int t = blockIdx.x * 256 + threadIdx.x;      // 2752512 exactly
  int p = t % HW4;
  int c = (t / HW4) % 96;
  int b = t / (96*HW4);
  stg_(outb, OUTOFF + ((size_t)b*FCH + 531 + c)*HW4 + p,
       ldg_(one, (size_t)(b*96+c)*HW4 + p, f), f);
}

// ------------------------------------------- fused double-warp of tenTwo (16-pt gather)
__global__ void k_warp2(const void* __restrict__ two, const float* __restrict__ rfr,
                        const float* __restrict__ tflow, float* __restrict__ wrp2,
                        const void* probe){
  bool f = is_f32(probe);
  int t = blockIdx.x * 256 + threadIdx.x;      // 2752512 exactly
  int x = t & 63;
  int y = (t >> 6) % 28;
  int c = (t / HW4) % 96;
  int b = t / (96*HW4);
  float qu = tflow[(size_t)(b*2+0)*HW4 + y*64 + x] * 1.25f;
  float qv = tflow[(size_t)(b*2+1)*HW4 + y*64 + x] * 1.25f;
  float qx = (float)x + qu, qy = (float)y + qv;
  float qx0 = floorf(qx), qy0 = floorf(qy);
  float wx = qx - qx0, wy = qy - qy0;
  const size_t cb = (size_t)(b*96+c)*HW4;
  float acc = 0.f;
  #pragma unroll
  for (int a = 0; a < 2; a++){
    #pragma unroll
    for (int bb = 0; bb < 2; bb++){
      float ry = qy0 + (float)a, rx = qx0 + (float)bb;
      if (ry < 0.f || ry > 27.f || rx < 0.f || rx > 63.f) continue;
      float W = (a ? wy : 1.f-wy) * (bb ? wx : 1.f-wx);
      int iry = (int)ry, irx = (int)rx;
      float su = rfr[(size_t)(b*2+0)*HW4 + iry*64 + irx];
      float sv = rfr[(size_t)(b*2+1)*HW4 + iry*64 + irx];
      float sx = rx + su, sy = ry + sv;
      float sx0 = floorf(sx), sy0 = floorf(sy);
      float swx = sx - sx0, swy = sy - sy0;
      float inner = 0.f;
      #pragma unroll
      for (int aa = 0; aa < 2; aa++){
        #pragma unroll
        for (int cc2 = 0; cc2 < 2; cc2++){
          float gy2 = sy0 + (float)aa, gx2 = sx0 + (float)cc2;
          if (gy2 < 0.f || gy2 > 27.f || gx2 < 0.f || gx2 > 63.f) continue;
          float wv = (aa ? swy : 1.f-swy) * (cc2 ? swx : 1.f-swx);
          inner += wv * ldg_(two, cb + (size_t)((int)gy2*64 + (int)gx2), f);
        }
      }
      acc += W * inner;
    }
  }
  wrp2[t] = acc;
}

// ---------------------------------------------------------------- correlation (81 ch)
__global__ void k_corr(const void* __restrict__ one, const float* __restrict__ two,
                       void* __restrict__ outb, const void* probe){
  bool f = is_f32(probe);
  int t = blockIdx.x * 256 + threadIdx.x;      // 16*9*1792 = 258048 exactly
  int x  = t & 63;
  int y  = (t >> 6) % 28;
  int dy = (t / HW4) % 9;
  int b  = t / (9*HW4);
  float acc[9];
  #pragma unroll
  for (int i = 0; i < 9; i++) acc[i] = 0.f;
  int row = y + dy - 4;
  if (row >= 0 && row < 28){
    for (int c = 0; c < 96; c++){
      float f1 = ldg_(one, (size_t)(b*96+c)*HW4 + y*64 + x, f);
      const float* rp = two + (size_t)(b*96+c)*HW4 + row*64;
      #pragma unroll
      for (int dx = 0; dx < 9; dx++){
        int xx = x + dx - 4;
        if (xx >= 0 && xx < 64) acc[dx] += f1 * rp[xx];
      }
    }
  }
  #pragma unroll
  for (int dx = 0; dx < 9; dx++){
    float v = lrelu(acc[dx] * (1.f/96.f));
    stg_(outb, OUTOFF + ((size_t)b*FCH + 448 + dy*9 + dx)*HW4 + y*64 + x, v, f);
  }
}

// ---------------------------------------------------------------- 3x3 conv + lrelu
// Dual-dtype VALU path. bf16_only=1: run only when data is bf16 (f32 -> MFMA path).
__global__ __launch_bounds__(256) void k_conv(
    void* __restrict__ base, size_t in_off,
    const void* __restrict__ w, const void* __restrict__ bias,
    int Cin, int Cout, size_t out_off, size_t out_bstr, const void* probe,
    int bf16_only){
  bool f = is_f32(probe);
  if (bf16_only && f) return;
  __shared__ float s_in[32*3*66];    // 25344 B
  __shared__ float s_w[32*9*32];     // 36864 B
  int tid = threadIdx.x;
  int x = tid & 63;
  int g = tid >> 6;
  int by = blockIdx.x;
  int b = by / 28, y = by % 28;
  int co_base = blockIdx.y * 32;
  const size_t FB = (size_t)FCH * HW4;
  float acc[8];
  #pragma unroll
  for (int j = 0; j < 8; j++) acc[j] = 0.f;

  for (int ci0 = 0; ci0 < Cin; ci0 += 32){
    int cc = min(32, Cin - ci0);
    if (f){
      const float* inb = (const float*)base + in_off + (size_t)b*FB;
      for (int e = tid; e < cc*198; e += 256){
        int ci = e / 198; int rem = e - ci*198;
        int r = rem / 66; int xx = rem - r*66;
        int iy = y + r - 1; int ix = xx - 1;
        float v = 0.f;
        if (iy >= 0 && iy < 28 && ix >= 0 && ix < 64)
          v = inb[(size_t)(ci0+ci)*HW4 + iy*64 + ix];
        s_in[(ci*3 + r)*66 + xx] = v;
      }
      const float* wf = (const float*)w;
      for (int e = tid; e < cc*288; e += 256){
        int co_i = e & 31; int k = (e >> 5) % 9; int ci = e / 288;
        int co = co_base + co_i;
        float v = 0.f;
        if (co < Cout) v = wf[((size_t)co*Cin + ci0 + ci)*9 + k];
        s_w[(ci*9 + k)*32 + co_i] = v;
      }
    } else {
      const u16* inb = (const u16*)base + in_off + (size_t)b*FB;
      for (int e = tid; e < cc*198; e += 256){
        int ci = e / 198; int rem = e - ci*198;
        int r = rem / 66; int xx = rem - r*66;
        int iy = y + r - 1; int ix = xx - 1;
        float v = 0.f;
        if (iy >= 0 && iy < 28 && ix >= 0 && ix < 64)
          v = b2f(inb[(size_t)(ci0+ci)*HW4 + iy*64 + ix]);
        s_in[(ci*3 + r)*66 + xx] = v;
      }
      const u16* wf = (const u16*)w;
      for (int e = tid; e < cc*288; e += 256){
        int co_i = e & 31; int k = (e >> 5) % 9; int ci = e / 288;
        int co = co_base + co_i;
        float v = 0.f;
        if (co < Cout) v = b2f(wf[((size_t)co*Cin + ci0 + ci)*9 + k]);
        s_w[(ci*9 + k)*32 + co_i] = v;
      }
    }
    __syncthreads();
    for (int ci = 0; ci < cc; ci++){
      const float* si = &s_in[ci*198 + x];
      const float* sw = &s_w[ci*288 + 8*g];
      #pragma unroll
      for (int ky = 0; ky < 3; ky++){
        #pragma unroll
        for (int kx = 0; kx < 3; kx++){
          float v = si[ky*66 + kx];
          const float* wp = sw + (ky*3 + kx)*32;
          float4 wa = *(const float4*)(wp);
          float4 wb = *(const float4*)(wp + 4);
          acc[0] += wa.x*v; acc[1] += wa.y*v; acc[2] += wa.z*v; acc[3] += wa.w*v;
          acc[4] += wb.x*v; acc[5] += wb.y*v; acc[6] += wb.z*v; acc[7] += wb.w*v;
        }
      }
    }
    __syncthreads();
  }
  #pragma unroll
  for (int j = 0; j < 8; j++){
    int co = co_base + 8*g + j;
    if (co < Cout){
      float v = lrelu(acc[j] + ldg_(bias, co, f));
      stg_(base, out_off + (size_t)b*out_bstr + (size_t)co*HW4 + y*64 + x, v, f);
    }
  }
}

// --------------------------------------------------------- weight hi/lo split + frag-linearize
// t = ((((gyb*nCB + cb)*9 + tap)*4 + tI)*64 + lane)*8 + j
// kk = (lane>>4)*8 + j ; ci = cb*16 + (kk>>1) ; plane = kk&1 ; co = gyb*64 + tI*16 + (lane&15)
__global__ void k_wprep(const void* __restrict__ w, u16* __restrict__ wT,
                        int Cin, int Cout, int nCB, int total, const void* probe){
  if (!is_f32(probe)) return;          // f32 path only
  int t = blockIdx.x * 256 + threadIdx.x;
  if (t >= total) return;
  int j     = t & 7;
  int lane  = (t >> 3) & 63;
  int rest  = t >> 9;
  int tI    = rest & 3;
  int rest2 = rest >> 2;
  int tap   = rest2 % 9;
  int gc    = rest2 / 9;
  int cb    = gc % nCB;
  int gyb   = gc / nCB;
  int kk = ((lane >> 4) << 3) + j;
  int ci = cb*16 + (kk >> 1);
  int co = gyb*64 + tI*16 + (lane & 15);
  float x = 0.f;
  if (co < Cout && ci < Cin) x = ((const float*)w)[((size_t)co*Cin + ci)*9 + tap];
  u16 hi = f2b(x);
  wT[t] = (kk & 1) ? f2b(x - b2f(hi)) : hi;
}

// --------------------------------------------------------- 3x3 conv via split-bf16 MFMA (f32 I/O)
// w = w_hi + w_lo, in = in_hi + in_lo ; K interleaved kk = 2*ci_local + plane (K=32 = 16 ci).
// acc += MFMA(A,B) + MFMA(A, swap16(B))  == full 4-term product, f32-accumulated.
// Block: 256 thr = 4 waves; wave wv: row = y0+(wv&1), x-half = (wv>>1)*32; 64 co.
// Grid: (224 = 16 b * 14 row-pairs, ceil(Cout/64)).
// LDS 53248 B, ALL operands plain conflict-free ds_read_b128:
//   input  u16 [0,8192):     [r:4][xt:4][n:16][lg:4][j:8]  (B-fragment-linear)
//   weight u16 [8192,26624): [tap:9][tI:4][lane:64][j:8]   (A-fragment-linear)
__global__ __launch_bounds__(256, 2) void k_conv_ms(
    void* __restrict__ base, size_t in_off, const u16* __restrict__ wT,
    const void* __restrict__ bias, int Cin, int nCB, int Cout,
    size_t out_off, size_t out_bstr, const void* __restrict__ probe){
  if (!is_f32(probe)) return;          // f32 path only
  __shared__ __align__(16) u16 lds[26624];   // 53248 B
  const int tid  = threadIdx.x;
  const int lane = tid & 63, wv = tid >> 6;
  const int lx = lane & 15, lg = lane >> 4;
  const int wr  = wv & 1;              // wave row within pair
  const int wxh = wv >> 1;             // wave x-half
  const int b  = blockIdx.x & 15;
  const int y0 = (blockIdx.x >> 4) * 2;
  const int coB = (int)blockIdx.y * 64;
  const float* inb = (const float*)base + in_off + (size_t)b * ((size_t)FCH * HW4);
  const u16* wTg = wT + (size_t)blockIdx.y * (size_t)nCB * 18432;

  f32x4 acc[4][2];
  #pragma unroll
  for (int tI = 0; tI < 4; tI++){ acc[tI][0] = zero4(); acc[tI][1] = zero4(); }

  // per-kx B-frag x offset (u16): xo = lx+kx-1 in [-1,16]; arithmetic >> carries tiles
  int offb[3];
  #pragma unroll
  for (int kx = 0; kx < 3; kx++){
    int xo = lx + kx - 1;
    offb[kx] = (xo >> 4)*512 + (xo & 15)*32;
  }
  const bool maskB0 = (lx == 0  && wxh == 0);   // x = -1
  const bool maskB1 = (lx == 15 && wxh == 1);   // x = 64

  for (int cb = 0; cb < nCB; cb++){
    // ---- stage weights: 36864 B, plain vector copy (global 16B -> LDS 16B, conflict-free)
    const u16* wsrc = wTg + (size_t)cb * 18432;
    #pragma unroll
    for (int i = 0; i < 9; i++){
      int cc = wv*9 + i;                         // 0..35
      short8 v = *(const short8*)(wsrc + (size_t)cc*512 + lane*8);
      *(short8*)&lds[8192 + cc*512 + lane*8] = v;
    }
    // ---- stage input: 16 ci x 4 rows x 64 x f32 -> hi/lo bf16 pairs, B-frag-linear
    #pragma unroll
    for (int i = 0; i < 4; i++){
      int id  = tid + 256*i;                     // 0..1023
      int x4  = id & 15;
      int r   = (id >> 4) & 3;
      int cil = id >> 6;                         // 0..15
      int ci  = cb*16 + cil;
      int row = y0 - 1 + r;
      float4 v = {0.f, 0.f, 0.f, 0.f};
      if (row >= 0 && row < 28 && ci < Cin)
        v = *(const float4*)(inb + (size_t)ci*HW4 + row*64 + x4*4);
      int jo = (cil >> 2)*8 + 2*(cil & 3);       // lg_w*8 + j_hi  (kk = 2*cil, 2*cil+1)
      int rb = r*64;
      #pragma unroll
      for (int u = 0; u < 4; u++){
        int x = x4*4 + u;
        float xv = (&v.x)[u];
        u16 hi = f2b(xv);
        u16 lo = f2b(xv - b2f(hi));
        int idx = (rb + (x >> 4)*16 + (x & 15))*32 + jo;
        *(unsigned int*)&lds[idx] = (unsigned int)hi | ((unsigned int)lo << 16);
      }
    }
    __syncthreads();
    // ---- 9 taps
    #pragma unroll
    for (int ky = 0; ky < 3; ky++){
      const int rb = (wr + ky)*2048 + wxh*1024;  // u16 base: row, wave x-half
      #pragma unroll
      for (int kx = 0; kx < 3; kx++){
        const int k = ky*3 + kx;
        const int bA = rb + offb[kx] + lg*8;
        short8 B0 = *(const short8*)&lds[bA];          // xg=0 frag
        short8 B1 = *(const short8*)&lds[bA + 512];    // xg=1 frag
        if (kx == 0 && maskB0) B0 = zero8();
        if (kx == 2 && maskB1) B1 = zero8();
        short8 S0 = swap16(B0), S1 = swap16(B1);
        #pragma unroll
        for (int tI = 0; tI < 4; tI++){
          short8 Af = *(const short8*)&lds[8192 + ((k*4 + tI)*64 + lane)*8];
          acc[tI][0] = __builtin_amdgcn_mfma_f32_16x16x32_bf16(Af, B0, acc[tI][0], 0,0,0);
          acc[tI][0] = __builtin_amdgcn_mfma_f32_16x16x32_bf16(Af, S0, acc[tI][0], 0,0,0);
          acc[tI][1] = __builtin_amdgcn_mfma_f32_16x16x32_bf16(Af, B1, acc[tI][1], 0,0,0);
          acc[tI][1] = __builtin_amdgcn_mfma_f32_16x16x32_bf16(Af, S1, acc[tI][1], 0,0,0);
        }
      }
    }
    __syncthreads();
  }
  // epilogue: bias + lrelu + f32 store. D: col=lane&15 -> x, row=(lane>>4)*4+reg -> co
  float* ob = (float*)base;
  const float* bf = (const float*)bias;
  const int y = y0 + wr;
  #pragma unroll
  for (int tI = 0; tI < 4; tI++){
    #pragma unroll
    for (int xg = 0; xg < 2; xg++){
      const int x = wxh*32 + xg*16 + lx;
      #pragma unroll
      for (int r4 = 0; r4 < 4; r4++){
        int co = coB + tI*16 + lg*4 + r4;
        if (co < Cout){
          float v = lrelu(acc[tI][xg][r4] + bf[co]);
          ob[out_off + (size_t)b*out_bstr + (size_t)co*HW4 + (size_t)(y*64 + x)] = v;
        }
      }
    }
  }
}

// ----------------------------------------------------------------------------------
extern "C" void kernel_launch(void* const* d_in, const int* in_sizes, int n_in,
                              void* d_out, int out_size, void* d_ws, size_t ws_size,
                              hipStream_t stream){
  const void* tenOne    = d_in[0];
  const void* tenTwo    = d_in[1];
  const void* prev_flow = d_in[2];
  const void* prev_feat = d_in[3];
  const void* quat      = d_in[4];
  const void* K         = d_in[5];
  const void* Kinv      = d_in[6];
  const void* upflow_w  = d_in[7];
  const void* upflow_b  = d_in[8];
  const void* upfeat_w  = d_in[9];
  const void* upfeat_b  = d_in[10];
  const void* w1 = d_in[11];  const void* b1 = d_in[12];
  const void* w2 = d_in[13];  const void* b2 = d_in[14];
  const void* w3 = d_in[15];  const void* b3 = d_in[16];
  const void* w4 = d_in[17];  const void* b4 = d_in[18];
  const void* w5 = d_in[19];  const void* b5 = d_in[20];
  const void* w6 = d_in[21];  const void* b6 = d_in[22];
  const void* probe = K;    // cam_intri[0]==500.0 discriminates dtype (runtime-only!)

  float* ws    = (float*)d_ws;
  float* Mws   = ws;                         // 160
  float* tmpA  = ws + 160;                   // 917504
  float* rfr   = ws + 917664;                // 57344
  float* tflow = ws + 975008;                // 57344
  float* wrp2  = ws + 1032352;               // 2752512 (end 3784864 floats = 15139456 B)
  u16*   wTb   = (u16*)(ws + 3784864);       // 4276224 u16 (8552448 B) split weights

  // host-side capacity check for the MFMA path's weight buffer
  const bool ws_ok = ws_size >= (size_t)23691904;   // 15139456 + 8552448

  k_M<<<1, 64, 0, stream>>>(quat, K, Kinv, Mws);
  k_rflow_col<<<1792, 256, 0, stream>>>(Mws, tmpA);
  k_rflow_row<<<112, 256, 0, stream>>>(tmpA, rfr, d_out, probe);
  k_dflow<<<224, 256, 0, stream>>>(prev_flow, upflow_w, upflow_b, tflow, d_out, probe);
  k_dfeat<<<224, 256, 0, stream>>>(prev_feat, upfeat_w, upfeat_b, d_out, probe);
  k_copy_one<<<10752, 256, 0, stream>>>(tenOne, d_out, probe);
  k_warp2<<<10752, 256, 0, stream>>>(tenTwo, rfr, tflow, wrp2, probe);
  k_corr<<<1008, 256, 0, stream>>>(tenOne, wrp2, d_out, probe);

  const size_t FB = (size_t)FCH * HW4;
  const size_t f0 = OUTOFF;

  struct LD { const void *w, *bi; int Cin, Cout, nCB, gy; size_t wOff, in_off, out_off, out_bstr; };
  const LD L[6] = {
    { w1, b1, 183, 128, 12, 2, 0,       f0+(size_t)448*HW4, f0+(size_t)320*HW4, FB },
    { w2, b2, 311, 128, 20, 2, 442368,  f0+(size_t)320*HW4, f0+(size_t)192*HW4, FB },
    { w3, b3, 439,  96, 28, 2, 1179648, f0+(size_t)192*HW4, f0+(size_t) 96*HW4, FB },
    { w4, b4, 535,  64, 34, 1, 2211840, f0+(size_t) 96*HW4, f0+(size_t) 32*HW4, FB },
    { w5, b5, 599,  32, 38, 1, 2838528, f0+(size_t) 32*HW4, f0,                 FB },
    { w6, b6, 631,   2, 40, 1, 3538944, f0,                 0,        (size_t)2*HW4 },
  };

  if (ws_ok){
    // f32 MFMA path (self-gated: early-out when probe says bf16)
    for (int i = 0; i < 6; i++){
      int total = L[i].gy * L[i].nCB * 18432;
      k_wprep<<<(total + 255)/256, 256, 0, stream>>>(
          L[i].w, wTb + L[i].wOff, L[i].Cin, L[i].Cout, L[i].nCB, total, probe);
    }
    for (int i = 0; i < 6; i++){
      k_conv_ms<<<dim3(224, L[i].gy), 256, 0, stream>>>(
          d_out, L[i].in_off, wTb + L[i].wOff, L[i].bi,
          L[i].Cin, L[i].nCB, L[i].Cout,
          L[i].out_off, L[i].out_bstr, probe);
    }
  }
  // VALU path: bf16 data always; f32 data only if ws too small for the MFMA path
  const int bf16_only = ws_ok ? 1 : 0;
  k_conv<<<dim3(448,4), 256, 0, stream>>>(d_out, f0 + (size_t)448*HW4, w1, b1, 183, 128,
                                          f0 + (size_t)320*HW4, FB, probe, bf16_only);
  k_conv<<<dim3(448,4), 256, 0, stream>>>(d_out, f0 + (size_t)320*HW4, w2, b2, 311, 128,
                                          f0 + (size_t)192*HW4, FB, probe, bf16_only);
  k_conv<<<dim3(448,3), 256, 0, stream>>>(d_out, f0 + (size_t)192*HW4, w3, b3, 439, 96,
                                          f0 + (size_t)96*HW4, FB, probe, bf16_only);
  k_conv<<<dim3(448,2), 256, 0, stream>>>(d_out, f0 + (size_t)96*HW4, w4, b4, 535, 64,
                                          f0 + (size_t)32*HW4, FB, probe, bf16_only);
  k_conv<<<dim3(448,1), 256, 0, stream>>>(d_out, f0 + (size_t)32*HW4, w5, b5, 599, 32,
                                          f0, FB, probe, bf16_only);
  k_conv<<<dim3(448,1), 256, 0, stream>>>(d_out, f0, w6, b6, 631, 2,
                                          0, (size_t)2*HW4, probe, bf16_only);
}

// Round 5
// 1325.629 us; speedup vs baseline: 4.5090x; 1.4585x over previous
//
#include <hip/hip_runtime.h>
#include <cstdint>
#include <cstddef>

typedef unsigned short u16;
typedef __attribute__((ext_vector_type(8))) short  short8;
typedef __attribute__((ext_vector_type(4))) float  f32x4;

#define HW4   1792      // 28*64
#define FCH   631       // final feat channels
#define OUTOFF ((size_t)57344)   // feat region element offset in d_out

__device__ __forceinline__ float b2f(u16 u){
  union { unsigned int i; float f; } v; v.i = ((unsigned int)u) << 16; return v.f;
}
__device__ __forceinline__ u16 f2b(float f){
  unsigned int x = __float_as_uint(f);
  return (u16)((x + 0x7fffu + ((x >> 16) & 1u)) >> 16);
}
__device__ __forceinline__ float lrelu(float v){ return v >= 0.f ? v : 0.1f * v; }
// dtype probe: cam_intri[0]=500.0. bf16 pair read as float -> 2.4e-41 ; fp32 -> 500.0
__device__ __forceinline__ bool is_f32(const void* probe){ return ((const float*)probe)[0] > 1.0f; }
__device__ __forceinline__ float ldg_(const void* p, size_t i, bool f){
  return f ? ((const float*)p)[i] : b2f(((const u16*)p)[i]);
}
__device__ __forceinline__ void stg_(void* p, size_t i, float v, bool f){
  if (f) ((float*)p)[i] = v; else ((u16*)p)[i] = f2b(v);
}
__device__ __forceinline__ short8 zero8(){
  union { long long l[2]; short8 s; } z; z.l[0] = 0; z.l[1] = 0; return z.s;
}
__device__ __forceinline__ f32x4 zero4(){
  union { long long l[2]; f32x4 s; } z; z.l[0] = 0; z.l[1] = 0; return z.s;
}
// swap 16b halves of each dword: K-slot j <-> j^1 (hi/lo plane exchange)
__device__ __forceinline__ short8 swap16(short8 v){
  union { short8 s; unsigned int u[4]; } a, r;
  a.s = v;
  #pragma unroll
  for (int i = 0; i < 4; i++) r.u[i] = (a.u[i] >> 16) | (a.u[i] << 16);
  return r.s;
}

// ---------------------------------------------------------------- M = K R(q) Kinv
__global__ void k_M(const void* __restrict__ quat, const void* __restrict__ K,
                    const void* __restrict__ Kinv, float* __restrict__ Mout){
  bool f = is_f32(K);
  int b = threadIdx.x;
  if (b >= 16) return;
  float q0 = ldg_(quat,b*4+0,f), q1 = ldg_(quat,b*4+1,f);
  float q2 = ldg_(quat,b*4+2,f), q3 = ldg_(quat,b*4+3,f);
  float n = sqrtf(q0*q0 + q1*q1 + q2*q2 + q3*q3);
  float w = q0/n, x = q1/n, y = q2/n, z = q3/n;
  float R[9];
  R[0] = 1.f - 2.f*(y*y + z*z); R[1] = 2.f*(x*y - w*z); R[2] = 2.f*(x*z + w*y);
  R[3] = 2.f*(x*y + w*z); R[4] = 1.f - 2.f*(x*x + z*z); R[5] = 2.f*(y*z - w*x);
  R[6] = 2.f*(x*z - w*y); R[7] = 2.f*(y*z + w*x); R[8] = 1.f - 2.f*(x*x + y*y);
  float Kf[9], Ki[9];
  for (int i = 0; i < 9; i++){ Kf[i] = ldg_(K,i,f); Ki[i] = ldg_(Kinv,i,f); }
  float T[9];
  for (int r = 0; r < 3; r++)
    for (int c = 0; c < 3; c++)
      T[r*3+c] = R[r*3+0]*Ki[0*3+c] + R[r*3+1]*Ki[1*3+c] + R[r*3+2]*Ki[2*3+c];
  for (int r = 0; r < 3; r++)
    for (int c = 0; c < 3; c++)
      Mout[b*9 + r*3 + c] = Kf[r*3+0]*T[0*3+c] + Kf[r*3+1]*T[1*3+c] + Kf[r*3+2]*T[2*3+c];
}

// ---------------------------------------- rotation-flow, column (W 1024->64) pass
__global__ void k_rflow_col(const float* __restrict__ Mws, float* __restrict__ tmpA){
  int t = blockIdx.x * 256 + threadIdx.x;      // 16*448*64 = 458752 exactly
  int xo = t & 63;
  int yf = (t >> 6) % 448;
  int b  = t / (448*64);
  const float* M = Mws + b*9;
  float m0=M[0],m1=M[1],m2=M[2],m3=M[3],m4=M[4],m5=M[5],m6=M[6],m7=M[7],m8=M[8];
  float cx = 16.f*xo + 7.5f;
  float yff = (float)yf;
  float su = 0.f, sv = 0.f, wsum = 0.f;
  for (int i = 0; i < 32; i++){
    int xi = 16*xo - 8 + i;
    if (xi < 0 || xi > 1023) continue;
    float xf = (float)xi;
    float wgt = 1.f - fabsf(xf - cx) * (1.f/16.f);
    float den = m6*xf + m7*yff + m8;
    float inv = 1.f / den;
    float u = (m0*xf + m1*yff + m2)*inv - xf;
    float v = (m3*xf + m4*yff + m5)*inv - yff;
    su += wgt*u; sv += wgt*v; wsum += wgt;
  }
  float rn = 1.f / wsum;
  tmpA[((size_t)(b*2+0)*64 + xo)*448 + yf] = su*rn;
  tmpA[((size_t)(b*2+1)*64 + xo)*448 + yf] = sv*rn;
}

// ---------------------------------------- rotation-flow, row (448->28) + /SCALE
__global__ void k_rflow_row(const float* __restrict__ tmpA, float* __restrict__ rfr,
                            void* __restrict__ outb, const void* probe){
  bool f = is_f32(probe);
  int t = blockIdx.x * 256 + threadIdx.x;      // 28672 exactly
  int xo = t & 63;
  int yo = (t >> 6) % 28;
  int b  = t / HW4;
  float cy = 16.f*yo + 7.5f;
  for (int c = 0; c < 2; c++){
    const float* col = tmpA + ((size_t)(b*2+c)*64 + xo)*448;
    float s = 0.f, wsum = 0.f;
    for (int i = 0; i < 32; i++){
      int yi = 16*yo - 8 + i;
      if (yi < 0 || yi > 447) continue;
      float wgt = 1.f - fabsf((float)yi - cy) * (1.f/16.f);
      s += wgt * col[yi]; wsum += wgt;
    }
    float val = s / (wsum * 16.0f);   // includes /SCALE
    rfr[(size_t)(b*2+c)*HW4 + yo*64 + xo] = val;
    stg_(outb, OUTOFF + ((size_t)b*FCH + 529 + c)*HW4 + yo*64 + xo, val, f);
  }
}

// ---------------------------------------------------- deconv4s2 of prev_flow (2ch)
__global__ void k_dflow(const void* __restrict__ pf, const void* __restrict__ w,
                        const void* __restrict__ bias, float* __restrict__ tflow,
                        void* __restrict__ outb, const void* probe){
  bool f = is_f32(probe);
  int t = blockIdx.x * 256 + threadIdx.x;      // 57344 exactly
  int x = t & 63;
  int y = (t >> 6) % 28;
  int co = (t / HW4) & 1;
  int b  = t / (2*HW4);
  float acc = ldg_(bias, co, f);
  for (int ky = 0; ky < 4; ky++){
    int dy = y + ky - 2;
    if (dy < 0 || dy > 26 || (dy & 1)) continue;
    int iy = dy >> 1;
    for (int kx = 0; kx < 4; kx++){
      int dx = x + kx - 2;
      if (dx < 0 || dx > 62 || (dx & 1)) continue;
      int ix = dx >> 1;
      for (int ci = 0; ci < 2; ci++){
        acc += ldg_(pf, ((size_t)(b*2+ci)*14 + iy)*32 + ix, f) *
               ldg_(w,  (size_t)ci*32 + co*16 + (3-ky)*4 + (3-kx), f);
      }
    }
  }
  tflow[(size_t)(b*2+co)*HW4 + y*64 + x] = acc;
  stg_(outb, OUTOFF + ((size_t)b*FCH + 627 + co)*HW4 + y*64 + x, acc, f);
}

// ---------------------------------------------------- deconv4s2 of prev_feat (663->2)
// ci-parallel: block = 512 thr (8 waves) per (b,y); lane = x; wave = ci-slice of 83.
// LDS tree-reduce the 8 partials per (co,x); bias + store by first 128 threads.
__global__ __launch_bounds__(512) void k_dfeat(
    const void* __restrict__ pfeat, const void* __restrict__ w,
    const void* __restrict__ bias, void* __restrict__ outb, const void* probe){
  bool f = is_f32(probe);
  __shared__ float red[8*128];
  int tid = threadIdx.x;
  int x = tid & 63;
  int s = tid >> 6;                 // ci-slice 0..7
  int b = blockIdx.x / 28;
  int y = blockIdx.x % 28;

  // valid (ky,iy) pairs: ky parity == y parity; dy = y+ky-2 in [0,26] even
  int iy0 = -1, iy1 = -1, wy0 = 0, wy1 = 0;
  {
    int n = 0;
    for (int ky = (y & 1); ky < 4; ky += 2){
      int dy = y + ky - 2;
      if (dy >= 0 && dy <= 26){
        if (n == 0){ iy0 = dy >> 1; wy0 = (3-ky)*4; }
        else       { iy1 = dy >> 1; wy1 = (3-ky)*4; }
        n++;
      }
    }
  }
  int ix0 = -1, ix1 = -1, wx0 = 0, wx1 = 0;
  {
    int n = 0;
    for (int kx = (x & 1); kx < 4; kx += 2){
      int dx = x + kx - 2;
      if (dx >= 0 && dx <= 62){
        if (n == 0){ ix0 = dx >> 1; wx0 = 3-kx; }
        else       { ix1 = dx >> 1; wx1 = 3-kx; }
        n++;
      }
    }
  }
  const bool v00 = (iy0 >= 0) && (ix0 >= 0);
  const bool v01 = (iy0 >= 0) && (ix1 >= 0);
  const bool v10 = (iy1 >= 0) && (ix0 >= 0);
  const bool v11 = (iy1 >= 0) && (ix1 >= 0);
  const int wo00 = wy0 + wx0, wo01 = wy0 + wx1, wo10 = wy1 + wx0, wo11 = wy1 + wx1;

  float acc0 = 0.f, acc1 = 0.f;
  const size_t pbase = (size_t)b * 663 * 448;
  const int ci_end = min(663, (s + 1) * 83);
  #pragma unroll 2
  for (int ci = s * 83; ci < ci_end; ci++){
    const size_t cbase = pbase + (size_t)ci * 448;
    const int wb = ci * 32;
    if (v00){ float iv = ldg_(pfeat, cbase + iy0*32 + ix0, f);
      acc0 += iv * ldg_(w, wb + wo00, f); acc1 += iv * ldg_(w, wb + 16 + wo00, f); }
    if (v01){ float iv = ldg_(pfeat, cbase + iy0*32 + ix1, f);
      acc0 += iv * ldg_(w, wb + wo01, f); acc1 += iv * ldg_(w, wb + 16 + wo01, f); }
    if (v10){ float iv = ldg_(pfeat, cbase + iy1*32 + ix0, f);
      acc0 += iv * ldg_(w, wb + wo10, f); acc1 += iv * ldg_(w, wb + 16 + wo10, f); }
    if (v11){ float iv = ldg_(pfeat, cbase + iy1*32 + ix1, f);
      acc0 += iv * ldg_(w, wb + wo11, f); acc1 += iv * ldg_(w, wb + 16 + wo11, f); }
  }
  red[s*128 + x]      = acc0;
  red[s*128 + 64 + x] = acc1;
  __syncthreads();
  if (tid < 128){
    int co = tid >> 6, xx = tid & 63;
    float t = ldg_(bias, co, f);
    #pragma unroll
    for (int q = 0; q < 8; q++) t += red[q*128 + co*64 + xx];
    stg_(outb, OUTOFF + ((size_t)b*FCH + 629 + co)*HW4 + y*64 + xx, t, f);
  }
}

// ---------------------------------------------------------------- copy tenOne into feat
__global__ void k_copy_one(const void* __restrict__ one, void* __restrict__ outb,
                           const void* probe){
  bool f = is_f32(probe);
  int t = blockIdx.x * 256 + threadIdx.x;      // 2752512 exactly
  int p = t % HW4;
  int c = (t / HW4) % 96;
  int b = t / (96*HW4);
  stg_(outb, OUTOFF + ((size_t)b*FCH + 531 + c)*HW4 + p,
       ldg_(one, (size_t)(b*96+c)*HW4 + p, f), f);
}

// ------------------------------------------- fused double-warp of tenTwo (16-pt gather)
__global__ void k_warp2(const void* __restrict__ two, const float* __restrict__ rfr,
                        const float* __restrict__ tflow, float* __restrict__ wrp2,
                        const void* probe){
  bool f = is_f32(probe);
  int t = blockIdx.x * 256 + threadIdx.x;      // 2752512 exactly
  int x = t & 63;
  int y = (t >> 6) % 28;
  int c = (t / HW4) % 96;
  int b = t / (96*HW4);
  float qu = tflow[(size_t)(b*2+0)*HW4 + y*64 + x] * 1.25f;
  float qv = tflow[(size_t)(b*2+1)*HW4 + y*64 + x] * 1.25f;
  float qx = (float)x + qu, qy = (float)y + qv;
  float qx0 = floorf(qx), qy0 = floorf(qy);
  float wx = qx - qx0, wy = qy - qy0;
  const size_t cb = (size_t)(b*96+c)*HW4;
  float acc = 0.f;
  #pragma unroll
  for (int a = 0; a < 2; a++){
    #pragma unroll
    for (int bb = 0; bb < 2; bb++){
      float ry = qy0 + (float)a, rx = qx0 + (float)bb;
      if (ry < 0.f || ry > 27.f || rx < 0.f || rx > 63.f) continue;
      float W = (a ? wy : 1.f-wy) * (bb ? wx : 1.f-wx);
      int iry = (int)ry, irx = (int)rx;
      float su = rfr[(size_t)(b*2+0)*HW4 + iry*64 + irx];
      float sv = rfr[(size_t)(b*2+1)*HW4 + iry*64 + irx];
      float sx = rx + su, sy = ry + sv;
      float sx0 = floorf(sx), sy0 = floorf(sy);
      float swx = sx - sx0, swy = sy - sy0;
      float inner = 0.f;
      #pragma unroll
      for (int aa = 0; aa < 2; aa++){
        #pragma unroll
        for (int cc2 = 0; cc2 < 2; cc2++){
          float gy2 = sy0 + (float)aa, gx2 = sx0 + (float)cc2;
          if (gy2 < 0.f || gy2 > 27.f || gx2 < 0.f || gx2 > 63.f) continue;
          float wv = (aa ? swy : 1.f-swy) * (cc2 ? swx : 1.f-swx);
          inner += wv * ldg_(two, cb + (size_t)((int)gy2*64 + (int)gx2), f);
        }
      }
      acc += W * inner;
    }
  }
  wrp2[t] = acc;
}

// ---------------------------------------------------------------- correlation (81 ch)
__global__ void k_corr(const void* __restrict__ one, const float* __restrict__ two,
                       void* __restrict__ outb, const void* probe){
  bool f = is_f32(probe);
  int t = blockIdx.x * 256 + threadIdx.x;      // 16*9*1792 = 258048 exactly
  int x  = t & 63;
  int y  = (t >> 6) % 28;
  int dy = (t / HW4) % 9;
  int b  = t / (9*HW4);
  float acc[9];
  #pragma unroll
  for (int i = 0; i < 9; i++) acc[i] = 0.f;
  int row = y + dy - 4;
  if (row >= 0 && row < 28){
    for (int c = 0; c < 96; c++){
      float f1 = ldg_(one, (size_t)(b*96+c)*HW4 + y*64 + x, f);
      const float* rp = two + (size_t)(b*96+c)*HW4 + row*64;
      #pragma unroll
      for (int dx = 0; dx < 9; dx++){
        int xx = x + dx - 4;
        if (xx >= 0 && xx < 64) acc[dx] += f1 * rp[xx];
      }
    }
  }
  #pragma unroll
  for (int dx = 0; dx < 9; dx++){
    float v = lrelu(acc[dx] * (1.f/96.f));
    stg_(outb, OUTOFF + ((size_t)b*FCH + 448 + dy*9 + dx)*HW4 + y*64 + x, v, f);
  }
}

// ---------------------------------------------------------------- 3x3 conv + lrelu
// Dual-dtype VALU path. bf16_only=1: run only when data is bf16 (f32 -> MFMA path).
__global__ __launch_bounds__(256) void k_conv(
    void* __restrict__ base, size_t in_off,
    const void* __restrict__ w, const void* __restrict__ bias,
    int Cin, int Cout, size_t out_off, size_t out_bstr, const void* probe,
    int bf16_only){
  bool f = is_f32(probe);
  if (bf16_only && f) return;
  __shared__ float s_in[32*3*66];    // 25344 B
  __shared__ float s_w[32*9*32];     // 36864 B
  int tid = threadIdx.x;
  int x = tid & 63;
  int g = tid >> 6;
  int by = blockIdx.x;
  int b = by / 28, y = by % 28;
  int co_base = blockIdx.y * 32;
  const size_t FB = (size_t)FCH * HW4;
  float acc[8];
  #pragma unroll
  for (int j = 0; j < 8; j++) acc[j] = 0.f;

  for (int ci0 = 0; ci0 < Cin; ci0 += 32){
    int cc = min(32, Cin - ci0);
    if (f){
      const float* inb = (const float*)base + in_off + (size_t)b*FB;
      for (int e = tid; e < cc*198; e += 256){
        int ci = e / 198; int rem = e - ci*198;
        int r = rem / 66; int xx = rem - r*66;
        int iy = y + r - 1; int ix = xx - 1;
        float v = 0.f;
        if (iy >= 0 && iy < 28 && ix >= 0 && ix < 64)
          v = inb[(size_t)(ci0+ci)*HW4 + iy*64 + ix];
        s_in[(ci*3 + r)*66 + xx] = v;
      }
      const float* wf = (const float*)w;
      for (int e = tid; e < cc*288; e += 256){
        int co_i = e & 31; int k = (e >> 5) % 9; int ci = e / 288;
        int co = co_base + co_i;
        float v = 0.f;
        if (co < Cout) v = wf[((size_t)co*Cin + ci0 + ci)*9 + k];
        s_w[(ci*9 + k)*32 + co_i] = v;
      }
    } else {
      const u16* inb = (const u16*)base + in_off + (size_t)b*FB;
      for (int e = tid; e < cc*198; e += 256){
        int ci = e / 198; int rem = e - ci*198;
        int r = rem / 66; int xx = rem - r*66;
        int iy = y + r - 1; int ix = xx - 1;
        float v = 0.f;
        if (iy >= 0 && iy < 28 && ix >= 0 && ix < 64)
          v = b2f(inb[(size_t)(ci0+ci)*HW4 + iy*64 + ix]);
        s_in[(ci*3 + r)*66 + xx] = v;
      }
      const u16* wf = (const u16*)w;
      for (int e = tid; e < cc*288; e += 256){
        int co_i = e & 31; int k = (e >> 5) % 9; int ci = e / 288;
        int co = co_base + co_i;
        float v = 0.f;
        if (co < Cout) v = b2f(wf[((size_t)co*Cin + ci0 + ci)*9 + k]);
        s_w[(ci*9 + k)*32 + co_i] = v;
      }
    }
    __syncthreads();
    for (int ci = 0; ci < cc; ci++){
      const float* si = &s_in[ci*198 + x];
      const float* sw = &s_w[ci*288 + 8*g];
      #pragma unroll
      for (int ky = 0; ky < 3; ky++){
        #pragma unroll
        for (int kx = 0; kx < 3; kx++){
          float v = si[ky*66 + kx];
          const float* wp = sw + (ky*3 + kx)*32;
          float4 wa = *(const float4*)(wp);
          float4 wb = *(const float4*)(wp + 4);
          acc[0] += wa.x*v; acc[1] += wa.y*v; acc[2] += wa.z*v; acc[3] += wa.w*v;
          acc[4] += wb.x*v; acc[5] += wb.y*v; acc[6] += wb.z*v; acc[7] += wb.w*v;
        }
      }
    }
    __syncthreads();
  }
  #pragma unroll
  for (int j = 0; j < 8; j++){
    int co = co_base + 8*g + j;
    if (co < Cout){
      float v = lrelu(acc[j] + ldg_(bias, co, f));
      stg_(base, out_off + (size_t)b*out_bstr + (size_t)co*HW4 + y*64 + x, v, f);
    }
  }
}

// --------------------------------------------------------- weight hi/lo split + frag-linearize
// t = ((((gyb*nCB + cb)*9 + tap)*4 + tI)*64 + lane)*8 + j
// kk = (lane>>4)*8 + j ; ci = cb*16 + (kk>>1) ; plane = kk&1 ; co = gyb*64 + tI*16 + (lane&15)
__global__ void k_wprep(const void* __restrict__ w, u16* __restrict__ wT,
                        int Cin, int Cout, int nCB, int total, const void* probe){
  if (!is_f32(probe)) return;          // f32 path only
  int t = blockIdx.x * 256 + threadIdx.x;
  if (t >= total) return;
  int j     = t & 7;
  int lane  = (t >> 3) & 63;
  int rest  = t >> 9;
  int tI    = rest & 3;
  int rest2 = rest >> 2;
  int tap   = rest2 % 9;
  int gc    = rest2 / 9;
  int cb    = gc % nCB;
  int gyb   = gc / nCB;
  int kk = ((lane >> 4) << 3) + j;
  int ci = cb*16 + (kk >> 1);
  int co = gyb*64 + tI*16 + (lane & 15);
  float x = 0.f;
  if (co < Cout && ci < Cin) x = ((const float*)w)[((size_t)co*Cin + ci)*9 + tap];
  u16 hi = f2b(x);
  wT[t] = (kk & 1) ? f2b(x - b2f(hi)) : hi;
}

// --------------------------------------------------------- 3x3 conv via split-bf16 MFMA (f32 I/O)
// w = w_hi + w_lo, in = in_hi + in_lo ; K interleaved kk = 2*ci_local + plane (K=32 = 16 ci).
// acc += MFMA(A,B) + MFMA(A, swap16(B))  == full 4-term product, f32-accumulated.
// Block: 256 thr = 4 waves; wave wv: row = y0+(wv&1), x-half = (wv>>1)*32; 64 co.
// Grid: (224 = 16 b * 14 row-pairs, ceil(Cout/64)).
// LDS 53248 B, ALL operands plain conflict-free ds_read_b128:
//   input  u16 [0,8192):     [r:4][xt:4][n:16][lg:4][j:8]  (B-fragment-linear)
//   weight u16 [8192,26624): [tap:9][tI:4][lane:64][j:8]   (A-fragment-linear)
__global__ __launch_bounds__(256, 2) void k_conv_ms(
    void* __restrict__ base, size_t in_off, const u16* __restrict__ wT,
    const void* __restrict__ bias, int Cin, int nCB, int Cout,
    size_t out_off, size_t out_bstr, const void* __restrict__ probe){
  if (!is_f32(probe)) return;          // f32 path only
  __shared__ __align__(16) u16 lds[26624];   // 53248 B
  const int tid  = threadIdx.x;
  const int lane = tid & 63, wv = tid >> 6;
  const int lx = lane & 15, lg = lane >> 4;
  const int wr  = wv & 1;              // wave row within pair
  const int wxh = wv >> 1;             // wave x-half
  const int b  = blockIdx.x & 15;
  const int y0 = (blockIdx.x >> 4) * 2;
  const int coB = (int)blockIdx.y * 64;
  const float* inb = (const float*)base + in_off + (size_t)b * ((size_t)FCH * HW4);
  const u16* wTg = wT + (size_t)blockIdx.y * (size_t)nCB * 18432;

  f32x4 acc[4][2];
  #pragma unroll
  for (int tI = 0; tI < 4; tI++){ acc[tI][0] = zero4(); acc[tI][1] = zero4(); }

  // per-kx B-frag x offset (u16): xo = lx+kx-1 in [-1,16]; arithmetic >> carries tiles
  int offb[3];
  #pragma unroll
  for (int kx = 0; kx < 3; kx++){
    int xo = lx + kx - 1;
    offb[kx] = (xo >> 4)*512 + (xo & 15)*32;
  }
  const bool maskB0 = (lx == 0  && wxh == 0);   // x = -1
  const bool maskB1 = (lx == 15 && wxh == 1);   // x = 64

  for (int cb = 0; cb < nCB; cb++){
    // ---- stage weights: 36864 B, plain vector copy (global 16B -> LDS 16B, conflict-free)
    const u16* wsrc = wTg + (size_t)cb * 18432;
    #pragma unroll
    for (int i = 0; i < 9; i++){
      int cc = wv*9 + i;                         // 0..35
      short8 v = *(const short8*)(wsrc + (size_t)cc*512 + lane*8);
      *(short8*)&lds[8192 + cc*512 + lane*8] = v;
    }
    // ---- stage input: 16 ci x 4 rows x 64 x f32 -> hi/lo bf16 pairs, B-frag-linear
    #pragma unroll
    for (int i = 0; i < 4; i++){
      int id  = tid + 256*i;                     // 0..1023
      int x4  = id & 15;
      int r   = (id >> 4) & 3;
      int cil = id >> 6;                         // 0..15
      int ci  = cb*16 + cil;
      int row = y0 - 1 + r;
      float4 v = {0.f, 0.f, 0.f, 0.f};
      if (row >= 0 && row < 28 && ci < Cin)
        v = *(const float4*)(inb + (size_t)ci*HW4 + row*64 + x4*4);
      int jo = (cil >> 2)*8 + 2*(cil & 3);       // lg_w*8 + j_hi  (kk = 2*cil, 2*cil+1)
      int rb = r*64;
      #pragma unroll
      for (int u = 0; u < 4; u++){
        int x = x4*4 + u;
        float xv = (&v.x)[u];
        u16 hi = f2b(xv);
        u16 lo = f2b(xv - b2f(hi));
        int idx = (rb + (x >> 4)*16 + (x & 15))*32 + jo;
        *(unsigned int*)&lds[idx] = (unsigned int)hi | ((unsigned int)lo << 16);
      }
    }
    __syncthreads();
    // ---- 9 taps
    #pragma unroll
    for (int ky = 0; ky < 3; ky++){
      const int rb = (wr + ky)*2048 + wxh*1024;  // u16 base: row, wave x-half
      #pragma unroll
      for (int kx = 0; kx < 3; kx++){
        const int k = ky*3 + kx;
        const int bA = rb + offb[kx] + lg*8;
        short8 B0 = *(const short8*)&lds[bA];          // xg=0 frag
        short8 B1 = *(const short8*)&lds[bA + 512];    // xg=1 frag
        if (kx == 0 && maskB0) B0 = zero8();
        if (kx == 2 && maskB1) B1 = zero8();
        short8 S0 = swap16(B0), S1 = swap16(B1);
        #pragma unroll
        for (int tI = 0; tI < 4; tI++){
          short8 Af = *(const short8*)&lds[8192 + ((k*4 + tI)*64 + lane)*8];
          acc[tI][0] = __builtin_amdgcn_mfma_f32_16x16x32_bf16(Af, B0, acc[tI][0], 0,0,0);
          acc[tI][0] = __builtin_amdgcn_mfma_f32_16x16x32_bf16(Af, S0, acc[tI][0], 0,0,0);
          acc[tI][1] = __builtin_amdgcn_mfma_f32_16x16x32_bf16(Af, B1, acc[tI][1], 0,0,0);
          acc[tI][1] = __builtin_amdgcn_mfma_f32_16x16x32_bf16(Af, S1, acc[tI][1], 0,0,0);
        }
      }
    }
    __syncthreads();
  }
  // epilogue: bias + lrelu + f32 store. D: col=lane&15 -> x, row=(lane>>4)*4+reg -> co
  float* ob = (float*)base;
  const float* bf = (const float*)bias;
  const int y = y0 + wr;
  #pragma unroll
  for (int tI = 0; tI < 4; tI++){
    #pragma unroll
    for (int xg = 0; xg < 2; xg++){
      const int x = wxh*32 + xg*16 + lx;
      #pragma unroll
      for (int r4 = 0; r4 < 4; r4++){
        int co = coB + tI*16 + lg*4 + r4;
        if (co < Cout){
          float v = lrelu(acc[tI][xg][r4] + bf[co]);
          ob[out_off + (size_t)b*out_bstr + (size_t)co*HW4 + (size_t)(y*64 + x)] = v;
        }
      }
    }
  }
}

// ----------------------------------------------------------------------------------
extern "C" void kernel_launch(void* const* d_in, const int* in_sizes, int n_in,
                              void* d_out, int out_size, void* d_ws, size_t ws_size,
                              hipStream_t stream){
  const void* tenOne    = d_in[0];
  const void* tenTwo    = d_in[1];
  const void* prev_flow = d_in[2];
  const void* prev_feat = d_in[3];
  const void* quat      = d_in[4];
  const void* K         = d_in[5];
  const void* Kinv      = d_in[6];
  const void* upflow_w  = d_in[7];
  const void* upflow_b  = d_in[8];
  const void* upfeat_w  = d_in[9];
  const void* upfeat_b  = d_in[10];
  const void* w1 = d_in[11];  const void* b1 = d_in[12];
  const void* w2 = d_in[13];  const void* b2 = d_in[14];
  const void* w3 = d_in[15];  const void* b3 = d_in[16];
  const void* w4 = d_in[17];  const void* b4 = d_in[18];
  const void* w5 = d_in[19];  const void* b5 = d_in[20];
  const void* w6 = d_in[21];  const void* b6 = d_in[22];
  const void* probe = K;    // cam_intri[0]==500.0 discriminates dtype (runtime-only!)

  float* ws    = (float*)d_ws;
  float* Mws   = ws;                         // 160
  float* tmpA  = ws + 160;                   // 917504
  float* rfr   = ws + 917664;                // 57344
  float* tflow = ws + 975008;                // 57344
  float* wrp2  = ws + 1032352;               // 2752512 (end 3784864 floats = 15139456 B)
  u16*   wTb   = (u16*)(ws + 3784864);       // 4276224 u16 (8552448 B) split weights

  // host-side capacity check for the MFMA path's weight buffer
  const bool ws_ok = ws_size >= (size_t)23691904;   // 15139456 + 8552448

  k_M<<<1, 64, 0, stream>>>(quat, K, Kinv, Mws);
  k_rflow_col<<<1792, 256, 0, stream>>>(Mws, tmpA);
  k_rflow_row<<<112, 256, 0, stream>>>(tmpA, rfr, d_out, probe);
  k_dflow<<<224, 256, 0, stream>>>(prev_flow, upflow_w, upflow_b, tflow, d_out, probe);
  k_dfeat<<<448, 512, 0, stream>>>(prev_feat, upfeat_w, upfeat_b, d_out, probe);
  k_copy_one<<<10752, 256, 0, stream>>>(tenOne, d_out, probe);
  k_warp2<<<10752, 256, 0, stream>>>(tenTwo, rfr, tflow, wrp2, probe);
  k_corr<<<1008, 256, 0, stream>>>(tenOne, wrp2, d_out, probe);

  const size_t FB = (size_t)FCH * HW4;
  const size_t f0 = OUTOFF;

  struct LD { const void *w, *bi; int Cin, Cout, nCB, gy; size_t wOff, in_off, out_off, out_bstr; };
  const LD L[6] = {
    { w1, b1, 183, 128, 12, 2, 0,       f0+(size_t)448*HW4, f0+(size_t)320*HW4, FB },
    { w2, b2, 311, 128, 20, 2, 442368,  f0+(size_t)320*HW4, f0+(size_t)192*HW4, FB },
    { w3, b3, 439,  96, 28, 2, 1179648, f0+(size_t)192*HW4, f0+(size_t) 96*HW4, FB },
    { w4, b4, 535,  64, 34, 1, 2211840, f0+(size_t) 96*HW4, f0+(size_t) 32*HW4, FB },
    { w5, b5, 599,  32, 38, 1, 2838528, f0+(size_t) 32*HW4, f0,                 FB },
    { w6, b6, 631,   2, 40, 1, 3538944, f0,                 0,        (size_t)2*HW4 },
  };

  if (ws_ok){
    // f32 MFMA path (self-gated: early-out when probe says bf16)
    for (int i = 0; i < 6; i++){
      int total = L[i].gy * L[i].nCB * 18432;
      k_wprep<<<(total + 255)/256, 256, 0, stream>>>(
          L[i].w, wTb + L[i].wOff, L[i].Cin, L[i].Cout, L[i].nCB, total, probe);
    }
    for (int i = 0; i < 6; i++){
      k_conv_ms<<<dim3(224, L[i].gy), 256, 0, stream>>>(
          d_out, L[i].in_off, wTb + L[i].wOff, L[i].bi,
          L[i].Cin, L[i].nCB, L[i].Cout,
          L[i].out_off, L[i].out_bstr, probe);
    }
  }
  // VALU path: bf16 data always; f32 data only if ws too small for the MFMA path
  const int bf16_only = ws_ok ? 1 : 0;
  k_conv<<<dim3(448,4), 256, 0, stream>>>(d_out, f0 + (size_t)448*HW4, w1, b1, 183, 128,
                                          f0 + (size_t)320*HW4, FB, probe, bf16_only);
  k_conv<<<dim3(448,4), 256, 0, stream>>>(d_out, f0 + (size_t)320*HW4, w2, b2, 311, 128,
                                          f0 + (size_t)192*HW4, FB, probe, bf16_only);
  k_conv<<<dim3(448,3), 256, 0, stream>>>(d_out, f0 + (size_t)192*HW4, w3, b3, 439, 96,
                                          f0 + (size_t)96*HW4, FB, probe, bf16_only);
  k_conv<<<dim3(448,2), 256, 0, stream>>>(d_out, f0 + (size_t)96*HW4, w4, b4, 535, 64,
                                          f0 + (size_t)32*HW4, FB, probe, bf16_only);
  k_conv<<<dim3(448,1), 256, 0, stream>>>(d_out, f0 + (size_t)32*HW4, w5, b5, 599, 32,
                                          f0, FB, probe, bf16_only);
  k_conv<<<dim3(448,1), 256, 0, stream>>>(d_out, f0, w6, b6, 631, 2,
                                          0, (size_t)2*HW4, probe, bf16_only);
}

// Round 6
// 1030.316 us; speedup vs baseline: 5.8014x; 1.2866x over previous
//
#include <hip/hip_runtime.h>
#include <cstdint>
#include <cstddef>

typedef unsigned short u16;
typedef __attribute__((ext_vector_type(8))) short  short8;
typedef __attribute__((ext_vector_type(4))) float  f32x4;

#define HW4   1792      // 28*64
#define FCH   631       // final feat channels
#define OUTOFF ((size_t)57344)   // feat region element offset in d_out

__device__ __forceinline__ float b2f(u16 u){
  union { unsigned int i; float f; } v; v.i = ((unsigned int)u) << 16; return v.f;
}
__device__ __forceinline__ u16 f2b(float f){
  unsigned int x = __float_as_uint(f);
  return (u16)((x + 0x7fffu + ((x >> 16) & 1u)) >> 16);
}
__device__ __forceinline__ float lrelu(float v){ return v >= 0.f ? v : 0.1f * v; }
// dtype probe: cam_intri[0]=500.0. bf16 pair read as float -> 2.4e-41 ; fp32 -> 500.0
__device__ __forceinline__ bool is_f32(const void* probe){ return ((const float*)probe)[0] > 1.0f; }
__device__ __forceinline__ float ldg_(const void* p, size_t i, bool f){
  return f ? ((const float*)p)[i] : b2f(((const u16*)p)[i]);
}
__device__ __forceinline__ void stg_(void* p, size_t i, float v, bool f){
  if (f) ((float*)p)[i] = v; else ((u16*)p)[i] = f2b(v);
}
__device__ __forceinline__ short8 zero8(){
  union { long long l[2]; short8 s; } z; z.l[0] = 0; z.l[1] = 0; return z.s;
}
__device__ __forceinline__ f32x4 zero4(){
  union { long long l[2]; f32x4 s; } z; z.l[0] = 0; z.l[1] = 0; return z.s;
}
// swap 16b halves of each dword: K-slot j <-> j^1 (hi/lo plane exchange)
__device__ __forceinline__ short8 swap16(short8 v){
  union { short8 s; unsigned int u[4]; } a, r;
  a.s = v;
  #pragma unroll
  for (int i = 0; i < 4; i++) r.u[i] = (a.u[i] >> 16) | (a.u[i] << 16);
  return r.s;
}

// ---------------------------------------------------------------- M = K R(q) Kinv
__global__ void k_M(const void* __restrict__ quat, const void* __restrict__ K,
                    const void* __restrict__ Kinv, float* __restrict__ Mout){
  bool f = is_f32(K);
  int b = threadIdx.x;
  if (b >= 16) return;
  float q0 = ldg_(quat,b*4+0,f), q1 = ldg_(quat,b*4+1,f);
  float q2 = ldg_(quat,b*4+2,f), q3 = ldg_(quat,b*4+3,f);
  float n = sqrtf(q0*q0 + q1*q1 + q2*q2 + q3*q3);
  float w = q0/n, x = q1/n, y = q2/n, z = q3/n;
  float R[9];
  R[0] = 1.f - 2.f*(y*y + z*z); R[1] = 2.f*(x*y - w*z); R[2] = 2.f*(x*z + w*y);
  R[3] = 2.f*(x*y + w*z); R[4] = 1.f - 2.f*(x*x + z*z); R[5] = 2.f*(y*z - w*x);
  R[6] = 2.f*(x*z - w*y); R[7] = 2.f*(y*z + w*x); R[8] = 1.f - 2.f*(x*x + y*y);
  float Kf[9], Ki[9];
  for (int i = 0; i < 9; i++){ Kf[i] = ldg_(K,i,f); Ki[i] = ldg_(Kinv,i,f); }
  float T[9];
  for (int r = 0; r < 3; r++)
    for (int c = 0; c < 3; c++)
      T[r*3+c] = R[r*3+0]*Ki[0*3+c] + R[r*3+1]*Ki[1*3+c] + R[r*3+2]*Ki[2*3+c];
  for (int r = 0; r < 3; r++)
    for (int c = 0; c < 3; c++)
      Mout[b*9 + r*3 + c] = Kf[r*3+0]*T[0*3+c] + Kf[r*3+1]*T[1*3+c] + Kf[r*3+2]*T[2*3+c];
}

// ---------------------------------------- rotation-flow, column (W 1024->64) pass
__global__ void k_rflow_col(const float* __restrict__ Mws, float* __restrict__ tmpA){
  int t = blockIdx.x * 256 + threadIdx.x;      // 16*448*64 = 458752 exactly
  int xo = t & 63;
  int yf = (t >> 6) % 448;
  int b  = t / (448*64);
  const float* M = Mws + b*9;
  float m0=M[0],m1=M[1],m2=M[2],m3=M[3],m4=M[4],m5=M[5],m6=M[6],m7=M[7],m8=M[8];
  float cx = 16.f*xo + 7.5f;
  float yff = (float)yf;
  float su = 0.f, sv = 0.f, wsum = 0.f;
  for (int i = 0; i < 32; i++){
    int xi = 16*xo - 8 + i;
    if (xi < 0 || xi > 1023) continue;
    float xf = (float)xi;
    float wgt = 1.f - fabsf(xf - cx) * (1.f/16.f);
    float den = m6*xf + m7*yff + m8;
    float inv = 1.f / den;
    float u = (m0*xf + m1*yff + m2)*inv - xf;
    float v = (m3*xf + m4*yff + m5)*inv - yff;
    su += wgt*u; sv += wgt*v; wsum += wgt;
  }
  float rn = 1.f / wsum;
  tmpA[((size_t)(b*2+0)*64 + xo)*448 + yf] = su*rn;
  tmpA[((size_t)(b*2+1)*64 + xo)*448 + yf] = sv*rn;
}

// ---------------------------------------- rotation-flow, row (448->28) + /SCALE
__global__ void k_rflow_row(const float* __restrict__ tmpA, float* __restrict__ rfr,
                            void* __restrict__ outb, const void* probe){
  bool f = is_f32(probe);
  int t = blockIdx.x * 256 + threadIdx.x;      // 28672 exactly
  int xo = t & 63;
  int yo = (t >> 6) % 28;
  int b  = t / HW4;
  float cy = 16.f*yo + 7.5f;
  for (int c = 0; c < 2; c++){
    const float* col = tmpA + ((size_t)(b*2+c)*64 + xo)*448;
    float s = 0.f, wsum = 0.f;
    for (int i = 0; i < 32; i++){
      int yi = 16*yo - 8 + i;
      if (yi < 0 || yi > 447) continue;
      float wgt = 1.f - fabsf((float)yi - cy) * (1.f/16.f);
      s += wgt * col[yi]; wsum += wgt;
    }
    float val = s / (wsum * 16.0f);   // includes /SCALE
    rfr[(size_t)(b*2+c)*HW4 + yo*64 + xo] = val;
    stg_(outb, OUTOFF + ((size_t)b*FCH + 529 + c)*HW4 + yo*64 + xo, val, f);
  }
}

// ---------------------------------------------------- deconv4s2 of prev_flow (2ch)
__global__ void k_dflow(const void* __restrict__ pf, const void* __restrict__ w,
                        const void* __restrict__ bias, float* __restrict__ tflow,
                        void* __restrict__ outb, const void* probe){
  bool f = is_f32(probe);
  int t = blockIdx.x * 256 + threadIdx.x;      // 57344 exactly
  int x = t & 63;
  int y = (t >> 6) % 28;
  int co = (t / HW4) & 1;
  int b  = t / (2*HW4);
  float acc = ldg_(bias, co, f);
  for (int ky = 0; ky < 4; ky++){
    int dy = y + ky - 2;
    if (dy < 0 || dy > 26 || (dy & 1)) continue;
    int iy = dy >> 1;
    for (int kx = 0; kx < 4; kx++){
      int dx = x + kx - 2;
      if (dx < 0 || dx > 62 || (dx & 1)) continue;
      int ix = dx >> 1;
      for (int ci = 0; ci < 2; ci++){
        acc += ldg_(pf, ((size_t)(b*2+ci)*14 + iy)*32 + ix, f) *
               ldg_(w,  (size_t)ci*32 + co*16 + (3-ky)*4 + (3-kx), f);
      }
    }
  }
  tflow[(size_t)(b*2+co)*HW4 + y*64 + x] = acc;
  stg_(outb, OUTOFF + ((size_t)b*FCH + 627 + co)*HW4 + y*64 + x, acc, f);
}

// ---------------------------------------------------- deconv4s2 of prev_feat (663->2)
// ci-parallel: block = 512 thr (8 waves) per (b,y); lane = x; wave = ci-slice of 83.
// LDS tree-reduce the 8 partials per (co,x); bias + store by first 128 threads.
__global__ __launch_bounds__(512) void k_dfeat(
    const void* __restrict__ pfeat, const void* __restrict__ w,
    const void* __restrict__ bias, void* __restrict__ outb, const void* probe){
  bool f = is_f32(probe);
  __shared__ float red[8*128];
  int tid = threadIdx.x;
  int x = tid & 63;
  int s = tid >> 6;                 // ci-slice 0..7
  int b = blockIdx.x / 28;
  int y = blockIdx.x % 28;

  // valid (ky,iy) pairs: ky parity == y parity; dy = y+ky-2 in [0,26] even
  int iy0 = -1, iy1 = -1, wy0 = 0, wy1 = 0;
  {
    int n = 0;
    for (int ky = (y & 1); ky < 4; ky += 2){
      int dy = y + ky - 2;
      if (dy >= 0 && dy <= 26){
        if (n == 0){ iy0 = dy >> 1; wy0 = (3-ky)*4; }
        else       { iy1 = dy >> 1; wy1 = (3-ky)*4; }
        n++;
      }
    }
  }
  int ix0 = -1, ix1 = -1, wx0 = 0, wx1 = 0;
  {
    int n = 0;
    for (int kx = (x & 1); kx < 4; kx += 2){
      int dx = x + kx - 2;
      if (dx >= 0 && dx <= 62){
        if (n == 0){ ix0 = dx >> 1; wx0 = 3-kx; }
        else       { ix1 = dx >> 1; wx1 = 3-kx; }
        n++;
      }
    }
  }
  const bool v00 = (iy0 >= 0) && (ix0 >= 0);
  const bool v01 = (iy0 >= 0) && (ix1 >= 0);
  const bool v10 = (iy1 >= 0) && (ix0 >= 0);
  const bool v11 = (iy1 >= 0) && (ix1 >= 0);
  const int wo00 = wy0 + wx0, wo01 = wy0 + wx1, wo10 = wy1 + wx0, wo11 = wy1 + wx1;

  float acc0 = 0.f, acc1 = 0.f;
  const size_t pbase = (size_t)b * 663 * 448;
  const int ci_end = min(663, (s + 1) * 83);
  #pragma unroll 2
  for (int ci = s * 83; ci < ci_end; ci++){
    const size_t cbase = pbase + (size_t)ci * 448;
    const int wb = ci * 32;
    if (v00){ float iv = ldg_(pfeat, cbase + iy0*32 + ix0, f);
      acc0 += iv * ldg_(w, wb + wo00, f); acc1 += iv * ldg_(w, wb + 16 + wo00, f); }
    if (v01){ float iv = ldg_(pfeat, cbase + iy0*32 + ix1, f);
      acc0 += iv * ldg_(w, wb + wo01, f); acc1 += iv * ldg_(w, wb + 16 + wo01, f); }
    if (v10){ float iv = ldg_(pfeat, cbase + iy1*32 + ix0, f);
      acc0 += iv * ldg_(w, wb + wo10, f); acc1 += iv * ldg_(w, wb + 16 + wo10, f); }
    if (v11){ float iv = ldg_(pfeat, cbase + iy1*32 + ix1, f);
      acc0 += iv * ldg_(w, wb + wo11, f); acc1 += iv * ldg_(w, wb + 16 + wo11, f); }
  }
  red[s*128 + x]      = acc0;
  red[s*128 + 64 + x] = acc1;
  __syncthreads();
  if (tid < 128){
    int co = tid >> 6, xx = tid & 63;
    float t = ldg_(bias, co, f);
    #pragma unroll
    for (int q = 0; q < 8; q++) t += red[q*128 + co*64 + xx];
    stg_(outb, OUTOFF + ((size_t)b*FCH + 629 + co)*HW4 + y*64 + xx, t, f);
  }
}

// ---------------------------------------------------------------- copy tenOne into feat
__global__ void k_copy_one(const void* __restrict__ one, void* __restrict__ outb,
                           const void* probe){
  bool f = is_f32(probe);
  int t = blockIdx.x * 256 + threadIdx.x;      // 2752512 exactly
  int p = t % HW4;
  int c = (t / HW4) % 96;
  int b = t / (96*HW4);
  stg_(outb, OUTOFF + ((size_t)b*FCH + 531 + c)*HW4 + p,
       ldg_(one, (size_t)(b*96+c)*HW4 + p, f), f);
}

// ------------------------------------------- fused double-warp of tenTwo (16-pt gather)
__global__ void k_warp2(const void* __restrict__ two, const float* __restrict__ rfr,
                        const float* __restrict__ tflow, float* __restrict__ wrp2,
                        const void* probe){
  bool f = is_f32(probe);
  int t = blockIdx.x * 256 + threadIdx.x;      // 2752512 exactly
  int x = t & 63;
  int y = (t >> 6) % 28;
  int c = (t / HW4) % 96;
  int b = t / (96*HW4);
  float qu = tflow[(size_t)(b*2+0)*HW4 + y*64 + x] * 1.25f;
  float qv = tflow[(size_t)(b*2+1)*HW4 + y*64 + x] * 1.25f;
  float qx = (float)x + qu, qy = (float)y + qv;
  float qx0 = floorf(qx), qy0 = floorf(qy);
  float wx = qx - qx0, wy = qy - qy0;
  const size_t cb = (size_t)(b*96+c)*HW4;
  float acc = 0.f;
  #pragma unroll
  for (int a = 0; a < 2; a++){
    #pragma unroll
    for (int bb = 0; bb < 2; bb++){
      float ry = qy0 + (float)a, rx = qx0 + (float)bb;
      if (ry < 0.f || ry > 27.f || rx < 0.f || rx > 63.f) continue;
      float W = (a ? wy : 1.f-wy) * (bb ? wx : 1.f-wx);
      int iry = (int)ry, irx = (int)rx;
      float su = rfr[(size_t)(b*2+0)*HW4 + iry*64 + irx];
      float sv = rfr[(size_t)(b*2+1)*HW4 + iry*64 + irx];
      float sx = rx + su, sy = ry + sv;
      float sx0 = floorf(sx), sy0 = floorf(sy);
      float swx = sx - sx0, swy = sy - sy0;
      float inner = 0.f;
      #pragma unroll
      for (int aa = 0; aa < 2; aa++){
        #pragma unroll
        for (int cc2 = 0; cc2 < 2; cc2++){
          float gy2 = sy0 + (float)aa, gx2 = sx0 + (float)cc2;
          if (gy2 < 0.f || gy2 > 27.f || gx2 < 0.f || gx2 > 63.f) continue;
          float wv = (aa ? swy : 1.f-swy) * (cc2 ? swx : 1.f-swx);
          inner += wv * ldg_(two, cb + (size_t)((int)gy2*64 + (int)gx2), f);
        }
      }
      acc += W * inner;
    }
  }
  wrp2[t] = acc;
}

// ---------------------------------------------------------------- correlation (81 ch)
__global__ void k_corr(const void* __restrict__ one, const float* __restrict__ two,
                       void* __restrict__ outb, const void* probe){
  bool f = is_f32(probe);
  int t = blockIdx.x * 256 + threadIdx.x;      // 16*9*1792 = 258048 exactly
  int x  = t & 63;
  int y  = (t >> 6) % 28;
  int dy = (t / HW4) % 9;
  int b  = t / (9*HW4);
  float acc[9];
  #pragma unroll
  for (int i = 0; i < 9; i++) acc[i] = 0.f;
  int row = y + dy - 4;
  if (row >= 0 && row < 28){
    for (int c = 0; c < 96; c++){
      float f1 = ldg_(one, (size_t)(b*96+c)*HW4 + y*64 + x, f);
      const float* rp = two + (size_t)(b*96+c)*HW4 + row*64;
      #pragma unroll
      for (int dx = 0; dx < 9; dx++){
        int xx = x + dx - 4;
        if (xx >= 0 && xx < 64) acc[dx] += f1 * rp[xx];
      }
    }
  }
  #pragma unroll
  for (int dx = 0; dx < 9; dx++){
    float v = lrelu(acc[dx] * (1.f/96.f));
    stg_(outb, OUTOFF + ((size_t)b*FCH + 448 + dy*9 + dx)*HW4 + y*64 + x, v, f);
  }
}

// ---------------------------------------------------------------- 3x3 conv + lrelu
// Dual-dtype VALU path. bf16_only=1: run only when data is bf16 (f32 -> MFMA path).
__global__ __launch_bounds__(256) void k_conv(
    void* __restrict__ base, size_t in_off,
    const void* __restrict__ w, const void* __restrict__ bias,
    int Cin, int Cout, size_t out_off, size_t out_bstr, const void* probe,
    int bf16_only){
  bool f = is_f32(probe);
  if (bf16_only && f) return;
  __shared__ float s_in[32*3*66];    // 25344 B
  __shared__ float s_w[32*9*32];     // 36864 B
  int tid = threadIdx.x;
  int x = tid & 63;
  int g = tid >> 6;
  int by = blockIdx.x;
  int b = by / 28, y = by % 28;
  int co_base = blockIdx.y * 32;
  const size_t FB = (size_t)FCH * HW4;
  float acc[8];
  #pragma unroll
  for (int j = 0; j < 8; j++) acc[j] = 0.f;

  for (int ci0 = 0; ci0 < Cin; ci0 += 32){
    int cc = min(32, Cin - ci0);
    if (f){
      const float* inb = (const float*)base + in_off + (size_t)b*FB;
      for (int e = tid; e < cc*198; e += 256){
        int ci = e / 198; int rem = e - ci*198;
        int r = rem / 66; int xx = rem - r*66;
        int iy = y + r - 1; int ix = xx - 1;
        float v = 0.f;
        if (iy >= 0 && iy < 28 && ix >= 0 && ix < 64)
          v = inb[(size_t)(ci0+ci)*HW4 + iy*64 + ix];
        s_in[(ci*3 + r)*66 + xx] = v;
      }
      const float* wf = (const float*)w;
      for (int e = tid; e < cc*288; e += 256){
        int co_i = e & 31; int k = (e >> 5) % 9; int ci = e / 288;
        int co = co_base + co_i;
        float v = 0.f;
        if (co < Cout) v = wf[((size_t)co*Cin + ci0 + ci)*9 + k];
        s_w[(ci*9 + k)*32 + co_i] = v;
      }
    } else {
      const u16* inb = (const u16*)base + in_off + (size_t)b*FB;
      for (int e = tid; e < cc*198; e += 256){
        int ci = e / 198; int rem = e - ci*198;
        int r = rem / 66; int xx = rem - r*66;
        int iy = y + r - 1; int ix = xx - 1;
        float v = 0.f;
        if (iy >= 0 && iy < 28 && ix >= 0 && ix < 64)
          v = b2f(inb[(size_t)(ci0+ci)*HW4 + iy*64 + ix]);
        s_in[(ci*3 + r)*66 + xx] = v;
      }
      const u16* wf = (const u16*)w;
      for (int e = tid; e < cc*288; e += 256){
        int co_i = e & 31; int k = (e >> 5) % 9; int ci = e / 288;
        int co = co_base + co_i;
        float v = 0.f;
        if (co < Cout) v = b2f(wf[((size_t)co*Cin + ci0 + ci)*9 + k]);
        s_w[(ci*9 + k)*32 + co_i] = v;
      }
    }
    __syncthreads();
    for (int ci = 0; ci < cc; ci++){
      const float* si = &s_in[ci*198 + x];
      const float* sw = &s_w[ci*288 + 8*g];
      #pragma unroll
      for (int ky = 0; ky < 3; ky++){
        #pragma unroll
        for (int kx = 0; kx < 3; kx++){
          float v = si[ky*66 + kx];
          const float* wp = sw + (ky*3 + kx)*32;
          float4 wa = *(const float4*)(wp);
          float4 wb = *(const float4*)(wp + 4);
          acc[0] += wa.x*v; acc[1] += wa.y*v; acc[2] += wa.z*v; acc[3] += wa.w*v;
          acc[4] += wb.x*v; acc[5] += wb.y*v; acc[6] += wb.z*v; acc[7] += wb.w*v;
        }
      }
    }
    __syncthreads();
  }
  #pragma unroll
  for (int j = 0; j < 8; j++){
    int co = co_base + 8*g + j;
    if (co < Cout){
      float v = lrelu(acc[j] + ldg_(bias, co, f));
      stg_(base, out_off + (size_t)b*out_bstr + (size_t)co*HW4 + y*64 + x, v, f);
    }
  }
}

// --------------------------------------------------------- weight hi/lo split + frag-linearize
// t = ((((gyb*nCB + cb)*9 + tap)*4 + tI)*64 + lane)*8 + j
// kk = (lane>>4)*8 + j ; ci = cb*16 + (kk>>1) ; plane = kk&1 ; co = gyb*64 + tI*16 + (lane&15)
__global__ void k_wprep(const void* __restrict__ w, u16* __restrict__ wT,
                        int Cin, int Cout, int nCB, int total, const void* probe){
  if (!is_f32(probe)) return;          // f32 path only
  int t = blockIdx.x * 256 + threadIdx.x;
  if (t >= total) return;
  int j     = t & 7;
  int lane  = (t >> 3) & 63;
  int rest  = t >> 9;
  int tI    = rest & 3;
  int rest2 = rest >> 2;
  int tap   = rest2 % 9;
  int gc    = rest2 / 9;
  int cb    = gc % nCB;
  int gyb   = gc / nCB;
  int kk = ((lane >> 4) << 3) + j;
  int ci = cb*16 + (kk >> 1);
  int co = gyb*64 + tI*16 + (lane & 15);
  float x = 0.f;
  if (co < Cout && ci < Cin) x = ((const float*)w)[((size_t)co*Cin + ci)*9 + tap];
  u16 hi = f2b(x);
  wT[t] = (kk & 1) ? f2b(x - b2f(hi)) : hi;
}

// --------------------------------------------------------- 3x3 conv via split-bf16 MFMA (f32 I/O)
// w = w_hi + w_lo, in = in_hi + in_lo ; K interleaved kk = 2*ci_local + plane (K=32 = 16 ci).
// acc += MFMA(A,B) + MFMA(A, swap16(B))  == full 4-term product, f32-accumulated.
// Block: 256 thr = 4 waves; wave wv: row = y0+(wv&1), x-half = (wv>>1)*32; 64 co.
// Grid: (224 = 16 b * 14 row-pairs, ceil(Cout/64)).
// LDS 53248 B:
//   input  u16 [0,8192):     slot-swizzled B-frag layout: data (n = r*64+x, lg) at
//                            slot' = n*4 + (lg ^ ((x>>2)&3)), 8 u16/slot (kills the
//                            16-way staging-write and 4x B-read bank conflicts)
//   weight u16 [8192,26624): [tap:9][tI:4][lane:64][j:8]  (conflict-free b128 A-frags)
// cb-loop is register double-buffered (ping-pong A/B sets; nCB always even):
// global loads for cb+1 issue before the barrier and fly under cb's MFMA phase.
__global__ __launch_bounds__(256, 2) void k_conv_ms(
    void* __restrict__ base, size_t in_off, const u16* __restrict__ wT,
    const void* __restrict__ bias, int Cin, int nCB, int Cout,
    size_t out_off, size_t out_bstr, const void* __restrict__ probe){
  if (!is_f32(probe)) return;          // f32 path only
  __shared__ __align__(16) u16 lds[26624];   // 53248 B
  const int tid  = threadIdx.x;
  const int lane = tid & 63, wv = tid >> 6;
  const int lx = lane & 15, lg = lane >> 4;
  const int wr  = wv & 1;              // wave row within pair
  const int wxh = wv >> 1;             // wave x-half
  const int b  = blockIdx.x & 15;
  const int y0 = (blockIdx.x >> 4) * 2;
  const int coB = (int)blockIdx.y * 64;
  const float* inb = (const float*)base + in_off + (size_t)b * ((size_t)FCH * HW4);
  const u16* wTg = wT + (size_t)blockIdx.y * (size_t)nCB * 18432;

  f32x4 acc[4][2];
  #pragma unroll
  for (int tI = 0; tI < 4; tI++){ acc[tI][0] = zero4(); acc[tI][1] = zero4(); }

  // B-frag read offsets (u16), slot-swizzled: xo = lx+kx-1 in [-1,16]
  // addr = n*32 + (lg ^ ((x_eff>>2)&3))*8 ; (x_eff>>2)&3 == (xo>>2)&3 (wxh*16 = 0 mod 4-blocks)
  int offb[3];
  #pragma unroll
  for (int kx = 0; kx < 3; kx++){
    int xo = lx + kx - 1;
    offb[kx] = (xo >> 4)*512 + (xo & 15)*32 + ((lg ^ ((xo >> 2) & 3)) << 3);
  }
  const bool maskB0 = (lx == 0  && wxh == 0);   // x = -1
  const bool maskB1 = (lx == 15 && wxh == 1);   // x = 64

  // staging thread constants: thread -> (x4, r), cil = wv + 4*i
  const int sx4 = tid & 15;
  const int sr  = (tid >> 4) & 3;
  const int srow = y0 - 1 + sr;
  const bool rok = (srow >= 0 && srow < 28);
  const int swz = sx4 & 3;            // write-side slot XOR = (x>>2)&3 (x = 4*sx4+u)
  const int nb0 = sr*64 + sx4*4;      // n for u=0

  float4 paA[4], paB[4];
  short8 pwA[9], pwB[9];

  auto LOADA = [&](int cb){
    const u16* wsrc = wTg + (size_t)cb * 18432;
    #pragma unroll
    for (int i = 0; i < 9; i++)
      pwA[i] = *(const short8*)(wsrc + (size_t)(wv*9 + i)*512 + lane*8);
    #pragma unroll
    for (int i = 0; i < 4; i++){
      int ci = cb*16 + wv + 4*i;
      float4 v = {0.f, 0.f, 0.f, 0.f};
      if (rok && ci < Cin) v = *(const float4*)(inb + (size_t)ci*HW4 + srow*64 + sx4*4);
      paA[i] = v;
    }
  };
  auto LOADB = [&](int cb){
    const u16* wsrc = wTg + (size_t)cb * 18432;
    #pragma unroll
    for (int i = 0; i < 9; i++)
      pwB[i] = *(const short8*)(wsrc + (size_t)(wv*9 + i)*512 + lane*8);
    #pragma unroll
    for (int i = 0; i < 4; i++){
      int ci = cb*16 + wv + 4*i;
      float4 v = {0.f, 0.f, 0.f, 0.f};
      if (rok && ci < Cin) v = *(const float4*)(inb + (size_t)ci*HW4 + srow*64 + sx4*4);
      paB[i] = v;
    }
  };
  auto WRITEA = [&](){
    #pragma unroll
    for (int i = 0; i < 9; i++)
      *(short8*)&lds[8192 + (wv*9 + i)*512 + lane*8] = pwA[i];
    #pragma unroll
    for (int i = 0; i < 4; i++){
      int cil = wv + 4*i;
      int jo = (((cil >> 2) ^ swz) << 3) + 2*(cil & 3);
      #pragma unroll
      for (int u = 0; u < 4; u++){
        float xv = (&paA[i].x)[u];
        u16 hi = f2b(xv);
        u16 lo = f2b(xv - b2f(hi));
        *(unsigned int*)&lds[(nb0 + u)*32 + jo] = (unsigned int)hi | ((unsigned int)lo << 16);
      }
    }
  };
  auto WRITEB = [&](){
    #pragma unroll
    for (int i = 0; i < 9; i++)
      *(short8*)&lds[8192 + (wv*9 + i)*512 + lane*8] = pwB[i];
    #pragma unroll
    for (int i = 0; i < 4; i++){
      int cil = wv + 4*i;
      int jo = (((cil >> 2) ^ swz) << 3) + 2*(cil & 3);
      #pragma unroll
      for (int u = 0; u < 4; u++){
        float xv = (&paB[i].x)[u];
        u16 hi = f2b(xv);
        u16 lo = f2b(xv - b2f(hi));
        *(unsigned int*)&lds[(nb0 + u)*32 + jo] = (unsigned int)hi | ((unsigned int)lo << 16);
      }
    }
  };
  auto COMPUTE = [&](){
    #pragma unroll
    for (int ky = 0; ky < 3; ky++){
      const int rb = (wr + ky)*2048 + wxh*1024;   // u16 base: input row, wave x-half
      #pragma unroll
      for (int kx = 0; kx < 3; kx++){
        const int k = ky*3 + kx;
        const int bA = rb + offb[kx];
        short8 B0 = *(const short8*)&lds[bA];          // xg=0 frag
        short8 B1 = *(const short8*)&lds[bA + 512];    // xg=1 frag (+16 x = +4 slots*4)
        if (kx == 0 && maskB0) B0 = zero8();
        if (kx == 2 && maskB1) B1 = zero8();
        short8 S0 = swap16(B0), S1 = swap16(B1);
        #pragma unroll
        for (int tI = 0; tI < 4; tI++){
          short8 Af = *(const short8*)&lds[8192 + ((k*4 + tI)*64 + lane)*8];
          acc[tI][0] = __builtin_amdgcn_mfma_f32_16x16x32_bf16(Af, B0, acc[tI][0], 0,0,0);
          acc[tI][0] = __builtin_amdgcn_mfma_f32_16x16x32_bf16(Af, S0, acc[tI][0], 0,0,0);
          acc[tI][1] = __builtin_amdgcn_mfma_f32_16x16x32_bf16(Af, B1, acc[tI][1], 0,0,0);
          acc[tI][1] = __builtin_amdgcn_mfma_f32_16x16x32_bf16(Af, S1, acc[tI][1], 0,0,0);
        }
      }
    }
  };

  LOADA(0);
  for (int cb = 0; cb < nCB; cb += 2){         // nCB is always even
    WRITEA();
    LOADB(cb + 1);
    __syncthreads();
    COMPUTE();
    __syncthreads();
    WRITEB();
    if (cb + 2 < nCB) LOADA(cb + 2);
    __syncthreads();
    COMPUTE();
    __syncthreads();
  }
  // epilogue: bias + lrelu + f32 store. D: col=lane&15 -> x, row=(lane>>4)*4+reg -> co
  float* ob = (float*)base;
  const float* bf = (const float*)bias;
  const int y = y0 + wr;
  #pragma unroll
  for (int tI = 0; tI < 4; tI++){
    #pragma unroll
    for (int xg = 0; xg < 2; xg++){
      const int x = wxh*32 + xg*16 + lx;
      #pragma unroll
      for (int r4 = 0; r4 < 4; r4++){
        int co = coB + tI*16 + lg*4 + r4;
        if (co < Cout){
          float v = lrelu(acc[tI][xg][r4] + bf[co]);
          ob[out_off + (size_t)b*out_bstr + (size_t)co*HW4 + (size_t)(y*64 + x)] = v;
        }
      }
    }
  }
}

// ----------------------------------------------------------------------------------
extern "C" void kernel_launch(void* const* d_in, const int* in_sizes, int n_in,
                              void* d_out, int out_size, void* d_ws, size_t ws_size,
                              hipStream_t stream){
  const void* tenOne    = d_in[0];
  const void* tenTwo    = d_in[1];
  const void* prev_flow = d_in[2];
  const void* prev_feat = d_in[3];
  const void* quat      = d_in[4];
  const void* K         = d_in[5];
  const void* Kinv      = d_in[6];
  const void* upflow_w  = d_in[7];
  const void* upflow_b  = d_in[8];
  const void* upfeat_w  = d_in[9];
  const void* upfeat_b  = d_in[10];
  const void* w1 = d_in[11];  const void* b1 = d_in[12];
  const void* w2 = d_in[13];  const void* b2 = d_in[14];
  const void* w3 = d_in[15];  const void* b3 = d_in[16];
  const void* w4 = d_in[17];  const void* b4 = d_in[18];
  const void* w5 = d_in[19];  const void* b5 = d_in[20];
  const void* w6 = d_in[21];  const void* b6 = d_in[22];
  const void* probe = K;    // cam_intri[0]==500.0 discriminates dtype (runtime-only!)

  float* ws    = (float*)d_ws;
  float* Mws   = ws;                         // 160
  float* tmpA  = ws + 160;                   // 917504
  float* rfr   = ws + 917664;                // 57344
  float* tflow = ws + 975008;                // 57344
  float* wrp2  = ws + 1032352;               // 2752512 (end 3784864 floats = 15139456 B)
  u16*   wTb   = (u16*)(ws + 3784864);       // 4276224 u16 (8552448 B) split weights

  // host-side capacity check for the MFMA path's weight buffer
  const bool ws_ok = ws_size >= (size_t)23691904;   // 15139456 + 8552448

  k_M<<<1, 64, 0, stream>>>(quat, K, Kinv, Mws);
  k_rflow_col<<<1792, 256, 0, stream>>>(Mws, tmpA);
  k_rflow_row<<<112, 256, 0, stream>>>(tmpA, rfr, d_out, probe);
  k_dflow<<<224, 256, 0, stream>>>(prev_flow, upflow_w, upflow_b, tflow, d_out, probe);
  k_dfeat<<<448, 512, 0, stream>>>(prev_feat, upfeat_w, upfeat_b, d_out, probe);
  k_copy_one<<<10752, 256, 0, stream>>>(tenOne, d_out, probe);
  k_warp2<<<10752, 256, 0, stream>>>(tenTwo, rfr, tflow, wrp2, probe);
  k_corr<<<1008, 256, 0, stream>>>(tenOne, wrp2, d_out, probe);

  const size_t FB = (size_t)FCH * HW4;
  const size_t f0 = OUTOFF;

  struct LD { const void *w, *bi; int Cin, Cout, nCB, gy; size_t wOff, in_off, out_off, out_bstr; };
  const LD L[6] = {
    { w1, b1, 183, 128, 12, 2, 0,       f0+(size_t)448*HW4, f0+(size_t)320*HW4, FB },
    { w2, b2, 311, 128, 20, 2, 442368,  f0+(size_t)320*HW4, f0+(size_t)192*HW4, FB },
    { w3, b3, 439,  96, 28, 2, 1179648, f0+(size_t)192*HW4, f0+(size_t) 96*HW4, FB },
    { w4, b4, 535,  64, 34, 1, 2211840, f0+(size_t) 96*HW4, f0+(size_t) 32*HW4, FB },
    { w5, b5, 599,  32, 38, 1, 2838528, f0+(size_t) 32*HW4, f0,                 FB },
    { w6, b6, 631,   2, 40, 1, 3538944, f0,                 0,        (size_t)2*HW4 },
  };

  if (ws_ok){
    // f32 MFMA path (self-gated: early-out when probe says bf16)
    for (int i = 0; i < 6; i++){
      int total = L[i].gy * L[i].nCB * 18432;
      k_wprep<<<(total + 255)/256, 256, 0, stream>>>(
          L[i].w, wTb + L[i].wOff, L[i].Cin, L[i].Cout, L[i].nCB, total, probe);
    }
    for (int i = 0; i < 6; i++){
      k_conv_ms<<<dim3(224, L[i].gy), 256, 0, stream>>>(
          d_out, L[i].in_off, wTb + L[i].wOff, L[i].bi,
          L[i].Cin, L[i].nCB, L[i].Cout,
          L[i].out_off, L[i].out_bstr, probe);
    }
  }
  // VALU path: bf16 data always; f32 data only if ws too small for the MFMA path
  const int bf16_only = ws_ok ? 1 : 0;
  k_conv<<<dim3(448,4), 256, 0, stream>>>(d_out, f0 + (size_t)448*HW4, w1, b1, 183, 128,
                                          f0 + (size_t)320*HW4, FB, probe, bf16_only);
  k_conv<<<dim3(448,4), 256, 0, stream>>>(d_out, f0 + (size_t)320*HW4, w2, b2, 311, 128,
                                          f0 + (size_t)192*HW4, FB, probe, bf16_only);
  k_conv<<<dim3(448,3), 256, 0, stream>>>(d_out, f0 + (size_t)192*HW4, w3, b3, 439, 96,
                                          f0 + (size_t)96*HW4, FB, probe, bf16_only);
  k_conv<<<dim3(448,2), 256, 0, stream>>>(d_out, f0 + (size_t)96*HW4, w4, b4, 535, 64,
                                          f0 + (size_t)32*HW4, FB, probe, bf16_only);
  k_conv<<<dim3(448,1), 256, 0, stream>>>(d_out, f0 + (size_t)32*HW4, w5, b5, 599, 32,
                                          f0, FB, probe, bf16_only);
  k_conv<<<dim3(448,1), 256, 0, stream>>>(d_out, f0, w6, b6, 631, 2,
                                          0, (size_t)2*HW4, probe, bf16_only);
}

// Round 7
// 927.089 us; speedup vs baseline: 6.4473x; 1.1113x over previous
//
#include <hip/hip_runtime.h>
#include <cstdint>
#include <cstddef>

typedef unsigned short u16;
typedef __attribute__((ext_vector_type(8))) short  short8;
typedef __attribute__((ext_vector_type(4))) float  f32x4;

#define HW4   1792      // 28*64
#define FCH   631       // final feat channels
#define OUTOFF ((size_t)57344)   // feat region element offset in d_out

__device__ __forceinline__ float b2f(u16 u){
  union { unsigned int i; float f; } v; v.i = ((unsigned int)u) << 16; return v.f;
}
__device__ __forceinline__ u16 f2b(float f){
  unsigned int x = __float_as_uint(f);
  return (u16)((x + 0x7fffu + ((x >> 16) & 1u)) >> 16);
}
__device__ __forceinline__ float lrelu(float v){ return v >= 0.f ? v : 0.1f * v; }
// dtype probe: cam_intri[0]=500.0. bf16 pair read as float -> 2.4e-41 ; fp32 -> 500.0
__device__ __forceinline__ bool is_f32(const void* probe){ return ((const float*)probe)[0] > 1.0f; }
__device__ __forceinline__ float ldg_(const void* p, size_t i, bool f){
  return f ? ((const float*)p)[i] : b2f(((const u16*)p)[i]);
}
__device__ __forceinline__ void stg_(void* p, size_t i, float v, bool f){
  if (f) ((float*)p)[i] = v; else ((u16*)p)[i] = f2b(v);
}
__device__ __forceinline__ short8 zero8(){
  union { long long l[2]; short8 s; } z; z.l[0] = 0; z.l[1] = 0; return z.s;
}
__device__ __forceinline__ f32x4 zero4(){
  union { long long l[2]; f32x4 s; } z; z.l[0] = 0; z.l[1] = 0; return z.s;
}
// swap 16b halves of each dword: K-slot j <-> j^1 (hi/lo plane exchange)
__device__ __forceinline__ short8 swap16(short8 v){
  union { short8 s; unsigned int u[4]; } a, r;
  a.s = v;
  #pragma unroll
  for (int i = 0; i < 4; i++) r.u[i] = (a.u[i] >> 16) | (a.u[i] << 16);
  return r.s;
}

// ---------------------------------------------------------------- M = K R(q) Kinv
__global__ void k_M(const void* __restrict__ quat, const void* __restrict__ K,
                    const void* __restrict__ Kinv, float* __restrict__ Mout){
  bool f = is_f32(K);
  int b = threadIdx.x;
  if (b >= 16) return;
  float q0 = ldg_(quat,b*4+0,f), q1 = ldg_(quat,b*4+1,f);
  float q2 = ldg_(quat,b*4+2,f), q3 = ldg_(quat,b*4+3,f);
  float n = sqrtf(q0*q0 + q1*q1 + q2*q2 + q3*q3);
  float w = q0/n, x = q1/n, y = q2/n, z = q3/n;
  float R[9];
  R[0] = 1.f - 2.f*(y*y + z*z); R[1] = 2.f*(x*y - w*z); R[2] = 2.f*(x*z + w*y);
  R[3] = 2.f*(x*y + w*z); R[4] = 1.f - 2.f*(x*x + z*z); R[5] = 2.f*(y*z - w*x);
  R[6] = 2.f*(x*z - w*y); R[7] = 2.f*(y*z + w*x); R[8] = 1.f - 2.f*(x*x + y*y);
  float Kf[9], Ki[9];
  for (int i = 0; i < 9; i++){ Kf[i] = ldg_(K,i,f); Ki[i] = ldg_(Kinv,i,f); }
  float T[9];
  for (int r = 0; r < 3; r++)
    for (int c = 0; c < 3; c++)
      T[r*3+c] = R[r*3+0]*Ki[0*3+c] + R[r*3+1]*Ki[1*3+c] + R[r*3+2]*Ki[2*3+c];
  for (int r = 0; r < 3; r++)
    for (int c = 0; c < 3; c++)
      Mout[b*9 + r*3 + c] = Kf[r*3+0]*T[0*3+c] + Kf[r*3+1]*T[1*3+c] + Kf[r*3+2]*T[2*3+c];
}

// ---------------------------------------- rotation-flow, column (W 1024->64) pass
__global__ void k_rflow_col(const float* __restrict__ Mws, float* __restrict__ tmpA){
  int t = blockIdx.x * 256 + threadIdx.x;      // 16*448*64 = 458752 exactly
  int xo = t & 63;
  int yf = (t >> 6) % 448;
  int b  = t / (448*64);
  const float* M = Mws + b*9;
  float m0=M[0],m1=M[1],m2=M[2],m3=M[3],m4=M[4],m5=M[5],m6=M[6],m7=M[7],m8=M[8];
  float cx = 16.f*xo + 7.5f;
  float yff = (float)yf;
  float su = 0.f, sv = 0.f, wsum = 0.f;
  for (int i = 0; i < 32; i++){
    int xi = 16*xo - 8 + i;
    if (xi < 0 || xi > 1023) continue;
    float xf = (float)xi;
    float wgt = 1.f - fabsf(xf - cx) * (1.f/16.f);
    float den = m6*xf + m7*yff + m8;
    float inv = 1.f / den;
    float u = (m0*xf + m1*yff + m2)*inv - xf;
    float v = (m3*xf + m4*yff + m5)*inv - yff;
    su += wgt*u; sv += wgt*v; wsum += wgt;
  }
  float rn = 1.f / wsum;
  tmpA[((size_t)(b*2+0)*64 + xo)*448 + yf] = su*rn;
  tmpA[((size_t)(b*2+1)*64 + xo)*448 + yf] = sv*rn;
}

// ---------------------------------------- rotation-flow, row (448->28) + /SCALE
__global__ void k_rflow_row(const float* __restrict__ tmpA, float* __restrict__ rfr,
                            void* __restrict__ outb, const void* probe){
  bool f = is_f32(probe);
  int t = blockIdx.x * 256 + threadIdx.x;      // 28672 exactly
  int xo = t & 63;
  int yo = (t >> 6) % 28;
  int b  = t / HW4;
  float cy = 16.f*yo + 7.5f;
  for (int c = 0; c < 2; c++){
    const float* col = tmpA + ((size_t)(b*2+c)*64 + xo)*448;
    float s = 0.f, wsum = 0.f;
    for (int i = 0; i < 32; i++){
      int yi = 16*yo - 8 + i;
      if (yi < 0 || yi > 447) continue;
      float wgt = 1.f - fabsf((float)yi - cy) * (1.f/16.f);
      s += wgt * col[yi]; wsum += wgt;
    }
    float val = s / (wsum * 16.0f);   // includes /SCALE
    rfr[(size_t)(b*2+c)*HW4 + yo*64 + xo] = val;
    stg_(outb, OUTOFF + ((size_t)b*FCH + 529 + c)*HW4 + yo*64 + xo, val, f);
  }
}

// ---------------------------------------------------- deconv4s2 of prev_flow (2ch)
__global__ void k_dflow(const void* __restrict__ pf, const void* __restrict__ w,
                        const void* __restrict__ bias, float* __restrict__ tflow,
                        void* __restrict__ outb, const void* probe){
  bool f = is_f32(probe);
  int t = blockIdx.x * 256 + threadIdx.x;      // 57344 exactly
  int x = t & 63;
  int y = (t >> 6) % 28;
  int co = (t / HW4) & 1;
  int b  = t / (2*HW4);
  float acc = ldg_(bias, co, f);
  for (int ky = 0; ky < 4; ky++){
    int dy = y + ky - 2;
    if (dy < 0 || dy > 26 || (dy & 1)) continue;
    int iy = dy >> 1;
    for (int kx = 0; kx < 4; kx++){
      int dx = x + kx - 2;
      if (dx < 0 || dx > 62 || (dx & 1)) continue;
      int ix = dx >> 1;
      for (int ci = 0; ci < 2; ci++){
        acc += ldg_(pf, ((size_t)(b*2+ci)*14 + iy)*32 + ix, f) *
               ldg_(w,  (size_t)ci*32 + co*16 + (3-ky)*4 + (3-kx), f);
      }
    }
  }
  tflow[(size_t)(b*2+co)*HW4 + y*64 + x] = acc;
  stg_(outb, OUTOFF + ((size_t)b*FCH + 627 + co)*HW4 + y*64 + x, acc, f);
}

// ------------------------------- deconv4s2 of prev_feat (663->2), two-stage LDS version
// Stage 1: block (ch, b) loads 16-ci chunk [16][448] into LDS (coalesced float4) + 16x32
// weights; computes partial sums for all 2x28x64 outputs from LDS; writes partials.
// Stage 2: per output, sum 42 chunk-partials (coalesced, stride 14336B) + bias, store.
#define DF_NCH 42
__global__ __launch_bounds__(256) void k_dfeat_s1(
    const void* __restrict__ pfeat, const void* __restrict__ w,
    float* __restrict__ part, const void* probe){
  bool f = is_f32(probe);
  __shared__ float s_in[16*448];    // 28672 B
  __shared__ float s_w[16*32];      // 2048 B
  const int tid = threadIdx.x;
  const int ch = blockIdx.x;        // 0..41
  const int b  = blockIdx.y;        // 0..15
  // ---- stage input chunk (1792 float4-groups)
  if (f){
    const float* src = (const float*)pfeat + ((size_t)b*663 + (size_t)ch*16)*448;
    #pragma unroll
    for (int i = 0; i < 7; i++){
      int e = tid + 256*i;
      int ci = ch*16 + e/112;
      float4 v = {0.f,0.f,0.f,0.f};
      if (ci < 663) v = *(const float4*)(src + e*4);
      *(float4*)&s_in[e*4] = v;
    }
  } else {
    const u16* src = (const u16*)pfeat + ((size_t)b*663 + (size_t)ch*16)*448;
    #pragma unroll
    for (int i = 0; i < 7; i++){
      int e = tid + 256*i;
      int ci = ch*16 + e/112;
      float4 v = {0.f,0.f,0.f,0.f};
      if (ci < 663){
        ushort4 u = *(const ushort4*)(src + e*4);
        v.x = b2f(u.x); v.y = b2f(u.y); v.z = b2f(u.z); v.w = b2f(u.w);
      }
      *(float4*)&s_in[e*4] = v;
    }
  }
  // ---- stage weights (16 ci x 32)
  #pragma unroll
  for (int i = 0; i < 2; i++){
    int e = tid + 256*i;            // 0..511
    int ci = ch*16 + (e >> 5);
    s_w[e] = (ci < 663) ? ldg_(w, (size_t)ci*32 + (e & 31), f) : 0.f;
  }
  __syncthreads();
  // ---- x geometry (fixed per thread: x = tid&63 for all its positions)
  const int x = tid & 63;
  int ix0=-1, ix1=-1, wx0=0, wx1=0;
  { int n = 0;
    for (int kx = (x & 1); kx < 4; kx += 2){
      int dx = x + kx - 2;
      if (dx >= 0 && dx <= 62){
        if (n == 0){ ix0 = dx >> 1; wx0 = 3-kx; } else { ix1 = dx >> 1; wx1 = 3-kx; }
        n++;
      }
    } }
  float* pout = part + (size_t)(b*DF_NCH + ch)*2*1792;
  #pragma unroll
  for (int i = 0; i < 7; i++){
    int p = tid + 256*i;            // covers 0..1791, x = p&63 = tid&63
    int y = p >> 6;
    int iy0=-1, iy1=-1, wy0=0, wy1=0;
    { int n = 0;
      for (int ky = (y & 1); ky < 4; ky += 2){
        int dy = y + ky - 2;
        if (dy >= 0 && dy <= 26){
          if (n == 0){ iy0 = dy >> 1; wy0 = (3-ky)*4; } else { iy1 = dy >> 1; wy1 = (3-ky)*4; }
          n++;
        }
      } }
    const bool v00 = (iy0 >= 0) && (ix0 >= 0);
    const bool v01 = (iy0 >= 0) && (ix1 >= 0);
    const bool v10 = (iy1 >= 0) && (ix0 >= 0);
    const bool v11 = (iy1 >= 0) && (ix1 >= 0);
    const int o00 = iy0*32+ix0, o01 = iy0*32+ix1, o10 = iy1*32+ix0, o11 = iy1*32+ix1;
    const int w00 = wy0+wx0, w01 = wy0+wx1, w10 = wy1+wx0, w11 = wy1+wx1;
    float a0 = 0.f, a1 = 0.f;
    #pragma unroll 4
    for (int ci = 0; ci < 16; ci++){
      const float* si = s_in + ci*448;
      const float* sw = s_w + ci*32;
      if (v00){ float iv = si[o00]; a0 += iv*sw[w00]; a1 += iv*sw[16+w00]; }
      if (v01){ float iv = si[o01]; a0 += iv*sw[w01]; a1 += iv*sw[16+w01]; }
      if (v10){ float iv = si[o10]; a0 += iv*sw[w10]; a1 += iv*sw[16+w10]; }
      if (v11){ float iv = si[o11]; a0 += iv*sw[w11]; a1 += iv*sw[16+w11]; }
    }
    pout[p]        = a0;
    pout[1792 + p] = a1;
  }
}

__global__ void k_dfeat_s2(const float* __restrict__ part, const void* __restrict__ bias,
                           void* __restrict__ outb, const void* probe){
  bool f = is_f32(probe);
  int t = blockIdx.x * 256 + threadIdx.x;      // 57344 exactly
  int x = t & 63;
  int y = (t >> 6) % 28;
  int co = (t / HW4) & 1;
  int b  = t / (2*HW4);
  float s = ldg_(bias, co, f);
  const float* pp = part + ((size_t)b*(2*DF_NCH) + co)*1792 + (size_t)(y*64 + x);
  #pragma unroll
  for (int ch = 0; ch < DF_NCH; ch++) s += pp[(size_t)ch*3584];
  stg_(outb, OUTOFF + ((size_t)b*FCH + 629 + co)*HW4 + y*64 + x, s, f);
}

// ---------------------------------------------------------------- copy tenOne into feat
__global__ void k_copy_one(const void* __restrict__ one, void* __restrict__ outb,
                           const void* probe){
  bool f = is_f32(probe);
  int t = blockIdx.x * 256 + threadIdx.x;      // 2752512 exactly
  int p = t % HW4;
  int c = (t / HW4) % 96;
  int b = t / (96*HW4);
  stg_(outb, OUTOFF + ((size_t)b*FCH + 531 + c)*HW4 + p,
       ldg_(one, (size_t)(b*96+c)*HW4 + p, f), f);
}

// ------------------------------------------- fused double-warp of tenTwo (16-pt gather)
__global__ void k_warp2(const void* __restrict__ two, const float* __restrict__ rfr,
                        const float* __restrict__ tflow, float* __restrict__ wrp2,
                        const void* probe){
  bool f = is_f32(probe);
  int t = blockIdx.x * 256 + threadIdx.x;      // 2752512 exactly
  int x = t & 63;
  int y = (t >> 6) % 28;
  int c = (t / HW4) % 96;
  int b = t / (96*HW4);
  float qu = tflow[(size_t)(b*2+0)*HW4 + y*64 + x] * 1.25f;
  float qv = tflow[(size_t)(b*2+1)*HW4 + y*64 + x] * 1.25f;
  float qx = (float)x + qu, qy = (float)y + qv;
  float qx0 = floorf(qx), qy0 = floorf(qy);
  float wx = qx - qx0, wy = qy - qy0;
  const size_t cb = (size_t)(b*96+c)*HW4;
  float acc = 0.f;
  #pragma unroll
  for (int a = 0; a < 2; a++){
    #pragma unroll
    for (int bb = 0; bb < 2; bb++){
      float ry = qy0 + (float)a, rx = qx0 + (float)bb;
      if (ry < 0.f || ry > 27.f || rx < 0.f || rx > 63.f) continue;
      float W = (a ? wy : 1.f-wy) * (bb ? wx : 1.f-wx);
      int iry = (int)ry, irx = (int)rx;
      float su = rfr[(size_t)(b*2+0)*HW4 + iry*64 + irx];
      float sv = rfr[(size_t)(b*2+1)*HW4 + iry*64 + irx];
      float sx = rx + su, sy = ry + sv;
      float sx0 = floorf(sx), sy0 = floorf(sy);
      float swx = sx - sx0, swy = sy - sy0;
      float inner = 0.f;
      #pragma unroll
      for (int aa = 0; aa < 2; aa++){
        #pragma unroll
        for (int cc2 = 0; cc2 < 2; cc2++){
          float gy2 = sy0 + (float)aa, gx2 = sx0 + (float)cc2;
          if (gy2 < 0.f || gy2 > 27.f || gx2 < 0.f || gx2 > 63.f) continue;
          float wv = (aa ? swy : 1.f-swy) * (cc2 ? swx : 1.f-swx);
          inner += wv * ldg_(two, cb + (size_t)((int)gy2*64 + (int)gx2), f);
        }
      }
      acc += W * inner;
    }
  }
  wrp2[t] = acc;
}

// ---------------------------------------------------------------- correlation (81 ch)
__global__ void k_corr(const void* __restrict__ one, const float* __restrict__ two,
                       void* __restrict__ outb, const void* probe){
  bool f = is_f32(probe);
  int t = blockIdx.x * 256 + threadIdx.x;      // 16*9*1792 = 258048 exactly
  int x  = t & 63;
  int y  = (t >> 6) % 28;
  int dy = (t / HW4) % 9;
  int b  = t / (9*HW4);
  float acc[9];
  #pragma unroll
  for (int i = 0; i < 9; i++) acc[i] = 0.f;
  int row = y + dy - 4;
  if (row >= 0 && row < 28){
    for (int c = 0; c < 96; c++){
      float f1 = ldg_(one, (size_t)(b*96+c)*HW4 + y*64 + x, f);
      const float* rp = two + (size_t)(b*96+c)*HW4 + row*64;
      #pragma unroll
      for (int dx = 0; dx < 9; dx++){
        int xx = x + dx - 4;
        if (xx >= 0 && xx < 64) acc[dx] += f1 * rp[xx];
      }
    }
  }
  #pragma unroll
  for (int dx = 0; dx < 9; dx++){
    float v = lrelu(acc[dx] * (1.f/96.f));
    stg_(outb, OUTOFF + ((size_t)b*FCH + 448 + dy*9 + dx)*HW4 + y*64 + x, v, f);
  }
}

// ---------------------------------------------------------------- 3x3 conv + lrelu
// Dual-dtype VALU path. bf16_only=1: run only when data is bf16 (f32 -> MFMA path).
__global__ __launch_bounds__(256) void k_conv(
    void* __restrict__ base, size_t in_off,
    const void* __restrict__ w, const void* __restrict__ bias,
    int Cin, int Cout, size_t out_off, size_t out_bstr, const void* probe,
    int bf16_only){
  bool f = is_f32(probe);
  if (bf16_only && f) return;
  __shared__ float s_in[32*3*66];    // 25344 B
  __shared__ float s_w[32*9*32];     // 36864 B
  int tid = threadIdx.x;
  int x = tid & 63;
  int g = tid >> 6;
  int by = blockIdx.x;
  int b = by / 28, y = by % 28;
  int co_base = blockIdx.y * 32;
  const size_t FB = (size_t)FCH * HW4;
  float acc[8];
  #pragma unroll
  for (int j = 0; j < 8; j++) acc[j] = 0.f;

  for (int ci0 = 0; ci0 < Cin; ci0 += 32){
    int cc = min(32, Cin - ci0);
    if (f){
      const float* inb = (const float*)base + in_off + (size_t)b*FB;
      for (int e = tid; e < cc*198; e += 256){
        int ci = e / 198; int rem = e - ci*198;
        int r = rem / 66; int xx = rem - r*66;
        int iy = y + r - 1; int ix = xx - 1;
        float v = 0.f;
        if (iy >= 0 && iy < 28 && ix >= 0 && ix < 64)
          v = inb[(size_t)(ci0+ci)*HW4 + iy*64 + ix];
        s_in[(ci*3 + r)*66 + xx] = v;
      }
      const float* wf = (const float*)w;
      for (int e = tid; e < cc*288; e += 256){
        int co_i = e & 31; int k = (e >> 5) % 9; int ci = e / 288;
        int co = co_base + co_i;
        float v = 0.f;
        if (co < Cout) v = wf[((size_t)co*Cin + ci0 + ci)*9 + k];
        s_w[(ci*9 + k)*32 + co_i] = v;
      }
    } else {
      const u16* inb = (const u16*)base + in_off + (size_t)b*FB;
      for (int e = tid; e < cc*198; e += 256){
        int ci = e / 198; int rem = e - ci*198;
        int r = rem / 66; int xx = rem - r*66;
        int iy = y + r - 1; int ix = xx - 1;
        float v = 0.f;
        if (iy >= 0 && iy < 28 && ix >= 0 && ix < 64)
          v = b2f(inb[(size_t)(ci0+ci)*HW4 + iy*64 + ix]);
        s_in[(ci*3 + r)*66 + xx] = v;
      }
      const u16* wf = (const u16*)w;
      for (int e = tid; e < cc*288; e += 256){
        int co_i = e & 31; int k = (e >> 5) % 9; int ci = e / 288;
        int co = co_base + co_i;
        float v = 0.f;
        if (co < Cout) v = b2f(wf[((size_t)co*Cin + ci0 + ci)*9 + k]);
        s_w[(ci*9 + k)*32 + co_i] = v;
      }
    }
    __syncthreads();
    for (int ci = 0; ci < cc; ci++){
      const float* si = &s_in[ci*198 + x];
      const float* sw = &s_w[ci*288 + 8*g];
      #pragma unroll
      for (int ky = 0; ky < 3; ky++){
        #pragma unroll
        for (int kx = 0; kx < 3; kx++){
          float v = si[ky*66 + kx];
          const float* wp = sw + (ky*3 + kx)*32;
          float4 wa = *(const float4*)(wp);
          float4 wb = *(const float4*)(wp + 4);
          acc[0] += wa.x*v; acc[1] += wa.y*v; acc[2] += wa.z*v; acc[3] += wa.w*v;
          acc[4] += wb.x*v; acc[5] += wb.y*v; acc[6] += wb.z*v; acc[7] += wb.w*v;
        }
      }
    }
    __syncthreads();
  }
  #pragma unroll
  for (int j = 0; j < 8; j++){
    int co = co_base + 8*g + j;
    if (co < Cout){
      float v = lrelu(acc[j] + ldg_(bias, co, f));
      stg_(base, out_off + (size_t)b*out_bstr + (size_t)co*HW4 + y*64 + x, v, f);
    }
  }
}

// --------------------------------------------------------- weight hi/lo split + frag-linearize
// t = ((((gyb*nCB + cb)*9 + tap)*4 + tI)*64 + lane)*8 + j
// kk = (lane>>4)*8 + j ; ci = cb*16 + (kk>>1) ; plane = kk&1 ; co = gyb*64 + tI*16 + (lane&15)
__global__ void k_wprep(const void* __restrict__ w, u16* __restrict__ wT,
                        int Cin, int Cout, int nCB, int total, const void* probe){
  if (!is_f32(probe)) return;          // f32 path only
  int t = blockIdx.x * 256 + threadIdx.x;
  if (t >= total) return;
  int j     = t & 7;
  int lane  = (t >> 3) & 63;
  int rest  = t >> 9;
  int tI    = rest & 3;
  int rest2 = rest >> 2;
  int tap   = rest2 % 9;
  int gc    = rest2 / 9;
  int cb    = gc % nCB;
  int gyb   = gc / nCB;
  int kk = ((lane >> 4) << 3) + j;
  int ci = cb*16 + (kk >> 1);
  int co = gyb*64 + tI*16 + (lane & 15);
  float x = 0.f;
  if (co < Cout && ci < Cin) x = ((const float*)w)[((size_t)co*Cin + ci)*9 + tap];
  u16 hi = f2b(x);
  wT[t] = (kk & 1) ? f2b(x - b2f(hi)) : hi;
}

// --------------------------------------------------------- 3x3 conv via split-bf16 MFMA (f32 I/O)
// w = w_hi + w_lo, in = in_hi + in_lo ; K interleaved kk = 2*ci_local + plane (K=32 = 16 ci).
// acc += MFMA(A,B) + MFMA(A, swap16(B))  == full 4-term product, f32-accumulated.
// Block: 256 thr = 4 waves; wave wv: row = y0+(wv&1), x-half = (wv>>1)*32; 64 co.
// Grid: (224 = 16 b * 14 row-pairs, ceil(Cout/64)).
// LDS 53248 B:
//   input  u16 [0,8192):     slot-swizzled B-frag layout: data (n = r*64+x, lg) at
//                            slot' = n*4 + (lg ^ ((x>>2)&3)), 8 u16/slot (kills the
//                            16-way staging-write and 4x B-read bank conflicts)
//   weight u16 [8192,26624): [tap:9][tI:4][lane:64][j:8]  (conflict-free b128 A-frags)
// cb-loop is register double-buffered (ping-pong A/B sets; nCB always even):
// global loads for cb+1 issue before the barrier and fly under cb's MFMA phase.
__global__ __launch_bounds__(256, 2) void k_conv_ms(
    void* __restrict__ base, size_t in_off, const u16* __restrict__ wT,
    const void* __restrict__ bias, int Cin, int nCB, int Cout,
    size_t out_off, size_t out_bstr, const void* __restrict__ probe){
  if (!is_f32(probe)) return;          // f32 path only
  __shared__ __align__(16) u16 lds[26624];   // 53248 B
  const int tid  = threadIdx.x;
  const int lane = tid & 63, wv = tid >> 6;
  const int lx = lane & 15, lg = lane >> 4;
  const int wr  = wv & 1;              // wave row within pair
  const int wxh = wv >> 1;             // wave x-half
  const int b  = blockIdx.x & 15;
  const int y0 = (blockIdx.x >> 4) * 2;
  const int coB = (int)blockIdx.y * 64;
  const float* inb = (const float*)base + in_off + (size_t)b * ((size_t)FCH * HW4);
  const u16* wTg = wT + (size_t)blockIdx.y * (size_t)nCB * 18432;

  f32x4 acc[4][2];
  #pragma unroll
  for (int tI = 0; tI < 4; tI++){ acc[tI][0] = zero4(); acc[tI][1] = zero4(); }

  // B-frag read offsets (u16), slot-swizzled: xo = lx+kx-1 in [-1,16]
  // addr = n*32 + (lg ^ ((x_eff>>2)&3))*8 ; (x_eff>>2)&3 == (xo>>2)&3 (wxh*16 = 0 mod 4-blocks)
  int offb[3];
  #pragma unroll
  for (int kx = 0; kx < 3; kx++){
    int xo = lx + kx - 1;
    offb[kx] = (xo >> 4)*512 + (xo & 15)*32 + ((lg ^ ((xo >> 2) & 3)) << 3);
  }
  const bool maskB0 = (lx == 0  && wxh == 0);   // x = -1
  const bool maskB1 = (lx == 15 && wxh == 1);   // x = 64

  // staging thread constants: thread -> (x4, r), cil = wv + 4*i
  const int sx4 = tid & 15;
  const int sr  = (tid >> 4) & 3;
  const int srow = y0 - 1 + sr;
  const bool rok = (srow >= 0 && srow < 28);
  const int swz = sx4 & 3;            // write-side slot XOR = (x>>2)&3 (x = 4*sx4+u)
  const int nb0 = sr*64 + sx4*4;      // n for u=0

  float4 paA[4], paB[4];
  short8 pwA[9], pwB[9];

  auto LOADA = [&](int cb){
    const u16* wsrc = wTg + (size_t)cb * 18432;
    #pragma unroll
    for (int i = 0; i < 9; i++)
      pwA[i] = *(const short8*)(wsrc + (size_t)(wv*9 + i)*512 + lane*8);
    #pragma unroll
    for (int i = 0; i < 4; i++){
      int ci = cb*16 + wv + 4*i;
      float4 v = {0.f, 0.f, 0.f, 0.f};
      if (rok && ci < Cin) v = *(const float4*)(inb + (size_t)ci*HW4 + srow*64 + sx4*4);
      paA[i] = v;
    }
  };
  auto LOADB = [&](int cb){
    const u16* wsrc = wTg + (size_t)cb * 18432;
    #pragma unroll
    for (int i = 0; i < 9; i++)
      pwB[i] = *(const short8*)(wsrc + (size_t)(wv*9 + i)*512 + lane*8);
    #pragma unroll
    for (int i = 0; i < 4; i++){
      int ci = cb*16 + wv + 4*i;
      float4 v = {0.f, 0.f, 0.f, 0.f};
      if (rok && ci < Cin) v = *(const float4*)(inb + (size_t)ci*HW4 + srow*64 + sx4*4);
      paB[i] = v;
    }
  };
  auto WRITEA = [&](){
    #pragma unroll
    for (int i = 0; i < 9; i++)
      *(short8*)&lds[8192 + (wv*9 + i)*512 + lane*8] = pwA[i];
    #pragma unroll
    for (int i = 0; i < 4; i++){
      int cil = wv + 4*i;
      int jo = (((cil >> 2) ^ swz) << 3) + 2*(cil & 3);
      #pragma unroll
      for (int u = 0; u < 4; u++){
        float xv = (&paA[i].x)[u];
        u16 hi = f2b(xv);
        u16 lo = f2b(xv - b2f(hi));
        *(unsigned int*)&lds[(nb0 + u)*32 + jo] = (unsigned int)hi | ((unsigned int)lo << 16);
      }
    }
  };
  auto WRITEB = [&](){
    #pragma unroll
    for (int i = 0; i < 9; i++)
      *(short8*)&lds[8192 + (wv*9 + i)*512 + lane*8] = pwB[i];
    #pragma unroll
    for (int i = 0; i < 4; i++){
      int cil = wv + 4*i;
      int jo = (((cil >> 2) ^ swz) << 3) + 2*(cil & 3);
      #pragma unroll
      for (int u = 0; u < 4; u++){
        float xv = (&paB[i].x)[u];
        u16 hi = f2b(xv);
        u16 lo = f2b(xv - b2f(hi));
        *(unsigned int*)&lds[(nb0 + u)*32 + jo] = (unsigned int)hi | ((unsigned int)lo << 16);
      }
    }
  };
  auto COMPUTE = [&](){
    #pragma unroll
    for (int ky = 0; ky < 3; ky++){
      const int rb = (wr + ky)*2048 + wxh*1024;   // u16 base: input row, wave x-half
      #pragma unroll
      for (int kx = 0; kx < 3; kx++){
        const int k = ky*3 + kx;
        const int bA = rb + offb[kx];
        short8 B0 = *(const short8*)&lds[bA];          // xg=0 frag
        short8 B1 = *(const short8*)&lds[bA + 512];    // xg=1 frag (+16 x = +4 slots*4)
        if (kx == 0 && maskB0) B0 = zero8();
        if (kx == 2 && maskB1) B1 = zero8();
        short8 S0 = swap16(B0), S1 = swap16(B1);
        #pragma unroll
        for (int tI = 0; tI < 4; tI++){
          short8 Af = *(const short8*)&lds[8192 + ((k*4 + tI)*64 + lane)*8];
          acc[tI][0] = __builtin_amdgcn_mfma_f32_16x16x32_bf16(Af, B0, acc[tI][0], 0,0,0);
          acc[tI][0] = __builtin_amdgcn_mfma_f32_16x16x32_bf16(Af, S0, acc[tI][0], 0,0,0);
          acc[tI][1] = __builtin_amdgcn_mfma_f32_16x16x32_bf16(Af, B1, acc[tI][1], 0,0,0);
          acc[tI][1] = __builtin_amdgcn_mfma_f32_16x16x32_bf16(Af, S1, acc[tI][1], 0,0,0);
        }
      }
    }
  };

  LOADA(0);
  for (int cb = 0; cb < nCB; cb += 2){         // nCB is always even
    WRITEA();
    LOADB(cb + 1);
    __syncthreads();
    COMPUTE();
    __syncthreads();
    WRITEB();
    if (cb + 2 < nCB) LOADA(cb + 2);
    __syncthreads();
    COMPUTE();
    __syncthreads();
  }
  // epilogue: bias + lrelu + f32 store. D: col=lane&15 -> x, row=(lane>>4)*4+reg -> co
  float* ob = (float*)base;
  const float* bf = (const float*)bias;
  const int y = y0 + wr;
  #pragma unroll
  for (int tI = 0; tI < 4; tI++){
    #pragma unroll
    for (int xg = 0; xg < 2; xg++){
      const int x = wxh*32 + xg*16 + lx;
      #pragma unroll
      for (int r4 = 0; r4 < 4; r4++){
        int co = coB + tI*16 + lg*4 + r4;
        if (co < Cout){
          float v = lrelu(acc[tI][xg][r4] + bf[co]);
          ob[out_off + (size_t)b*out_bstr + (size_t)co*HW4 + (size_t)(y*64 + x)] = v;
        }
      }
    }
  }
}

// ----------------------------------------------------------------------------------
extern "C" void kernel_launch(void* const* d_in, const int* in_sizes, int n_in,
                              void* d_out, int out_size, void* d_ws, size_t ws_size,
                              hipStream_t stream){
  const void* tenOne    = d_in[0];
  const void* tenTwo    = d_in[1];
  const void* prev_flow = d_in[2];
  const void* prev_feat = d_in[3];
  const void* quat      = d_in[4];
  const void* K         = d_in[5];
  const void* Kinv      = d_in[6];
  const void* upflow_w  = d_in[7];
  const void* upflow_b  = d_in[8];
  const void* upfeat_w  = d_in[9];
  const void* upfeat_b  = d_in[10];
  const void* w1 = d_in[11];  const void* b1 = d_in[12];
  const void* w2 = d_in[13];  const void* b2 = d_in[14];
  const void* w3 = d_in[15];  const void* b3 = d_in[16];
  const void* w4 = d_in[17];  const void* b4 = d_in[18];
  const void* w5 = d_in[19];  const void* b5 = d_in[20];
  const void* w6 = d_in[21];  const void* b6 = d_in[22];
  const void* probe = K;    // cam_intri[0]==500.0 discriminates dtype (runtime-only!)

  float* ws    = (float*)d_ws;
  float* Mws   = ws;                         // 160
  float* tmpA  = ws + 160;                   // 917504
  float* rfr   = ws + 917664;                // 57344
  float* tflow = ws + 975008;                // 57344
  float* wrp2  = ws + 1032352;               // 2752512 (end 3784864 floats = 15139456 B)
  u16*   wTb   = (u16*)(ws + 3784864);       // 4276224 u16 (8552448 B) split weights
  // dfeat partials (2408448 floats) alias the wrp2 region: k_dfeat_s1/s2 complete
  // before k_warp2 writes wrp2 (same-stream ordering).
  float* dpart = wrp2;

  // host-side capacity check for the MFMA path's weight buffer
  const bool ws_ok = ws_size >= (size_t)23691904;   // 15139456 + 8552448

  k_M<<<1, 64, 0, stream>>>(quat, K, Kinv, Mws);
  k_rflow_col<<<1792, 256, 0, stream>>>(Mws, tmpA);
  k_rflow_row<<<112, 256, 0, stream>>>(tmpA, rfr, d_out, probe);
  k_dflow<<<224, 256, 0, stream>>>(prev_flow, upflow_w, upflow_b, tflow, d_out, probe);
  k_dfeat_s1<<<dim3(DF_NCH, 16), 256, 0, stream>>>(prev_feat, upfeat_w, dpart, probe);
  k_dfeat_s2<<<224, 256, 0, stream>>>(dpart, upfeat_b, d_out, probe);
  k_copy_one<<<10752, 256, 0, stream>>>(tenOne, d_out, probe);
  k_warp2<<<10752, 256, 0, stream>>>(tenTwo, rfr, tflow, wrp2, probe);
  k_corr<<<1008, 256, 0, stream>>>(tenOne, wrp2, d_out, probe);

  const size_t FB = (size_t)FCH * HW4;
  const size_t f0 = OUTOFF;

  struct LD { const void *w, *bi; int Cin, Cout, nCB, gy; size_t wOff, in_off, out_off, out_bstr; };
  const LD L[6] = {
    { w1, b1, 183, 128, 12, 2, 0,       f0+(size_t)448*HW4, f0+(size_t)320*HW4, FB },
    { w2, b2, 311, 128, 20, 2, 442368,  f0+(size_t)320*HW4, f0+(size_t)192*HW4, FB },
    { w3, b3, 439,  96, 28, 2, 1179648, f0+(size_t)192*HW4, f0+(size_t) 96*HW4, FB },
    { w4, b4, 535,  64, 34, 1, 2211840, f0+(size_t) 96*HW4, f0+(size_t) 32*HW4, FB },
    { w5, b5, 599,  32, 38, 1, 2838528, f0+(size_t) 32*HW4, f0,                 FB },
    { w6, b6, 631,   2, 40, 1, 3538944, f0,                 0,        (size_t)2*HW4 },
  };

  if (ws_ok){
    // f32 MFMA path (self-gated: early-out when probe says bf16)
    for (int i = 0; i < 6; i++){
      int total = L[i].gy * L[i].nCB * 18432;
      k_wprep<<<(total + 255)/256, 256, 0, stream>>>(
          L[i].w, wTb + L[i].wOff, L[i].Cin, L[i].Cout, L[i].nCB, total, probe);
    }
    for (int i = 0; i < 6; i++){
      k_conv_ms<<<dim3(224, L[i].gy), 256, 0, stream>>>(
          d_out, L[i].in_off, wTb + L[i].wOff, L[i].bi,
          L[i].Cin, L[i].nCB, L[i].Cout,
          L[i].out_off, L[i].out_bstr, probe);
    }
  }
  // VALU path: bf16 data always; f32 data only if ws too small for the MFMA path
  const int bf16_only = ws_ok ? 1 : 0;
  k_conv<<<dim3(448,4), 256, 0, stream>>>(d_out, f0 + (size_t)448*HW4, w1, b1, 183, 128,
                                          f0 + (size_t)320*HW4, FB, probe, bf16_only);
  k_conv<<<dim3(448,4), 256, 0, stream>>>(d_out, f0 + (size_t)320*HW4, w2, b2, 311, 128,
                                          f0 + (size_t)192*HW4, FB, probe, bf16_only);
  k_conv<<<dim3(448,3), 256, 0, stream>>>(d_out, f0 + (size_t)192*HW4, w3, b3, 439, 96,
                                          f0 + (size_t)96*HW4, FB, probe, bf16_only);
  k_conv<<<dim3(448,2), 256, 0, stream>>>(d_out, f0 + (size_t)96*HW4, w4, b4, 535, 64,
                                          f0 + (size_t)32*HW4, FB, probe, bf16_only);
  k_conv<<<dim3(448,1), 256, 0, stream>>>(d_out, f0 + (size_t)32*HW4, w5, b5, 599, 32,
                                          f0, FB, probe, bf16_only);
  k_conv<<<dim3(448,1), 256, 0, stream>>>(d_out, f0, w6, b6, 631, 2,
                                          0, (size_t)2*HW4, probe, bf16_only);
}

// Round 8
// 857.310 us; speedup vs baseline: 6.9721x; 1.0814x over previous
//
#include <hip/hip_runtime.h>
#include <cstdint>
#include <cstddef>

typedef unsigned short u16;
typedef __attribute__((ext_vector_type(8))) short  short8;
typedef __attribute__((ext_vector_type(4))) float  f32x4;

#define HW4   1792      // 28*64
#define FCH   631       // final feat channels
#define OUTOFF ((size_t)57344)   // feat region element offset in d_out

__device__ __forceinline__ float b2f(u16 u){
  union { unsigned int i; float f; } v; v.i = ((unsigned int)u) << 16; return v.f;
}
__device__ __forceinline__ u16 f2b(float f){
  unsigned int x = __float_as_uint(f);
  return (u16)((x + 0x7fffu + ((x >> 16) & 1u)) >> 16);
}
__device__ __forceinline__ float lrelu(float v){ return v >= 0.f ? v : 0.1f * v; }
// dtype probe: cam_intri[0]=500.0. bf16 pair read as float -> 2.4e-41 ; fp32 -> 500.0
__device__ __forceinline__ bool is_f32(const void* probe){ return ((const float*)probe)[0] > 1.0f; }
__device__ __forceinline__ float ldg_(const void* p, size_t i, bool f){
  return f ? ((const float*)p)[i] : b2f(((const u16*)p)[i]);
}
__device__ __forceinline__ void stg_(void* p, size_t i, float v, bool f){
  if (f) ((float*)p)[i] = v; else ((u16*)p)[i] = f2b(v);
}
__device__ __forceinline__ short8 zero8(){
  union { long long l[2]; short8 s; } z; z.l[0] = 0; z.l[1] = 0; return z.s;
}
__device__ __forceinline__ f32x4 zero4(){
  union { long long l[2]; f32x4 s; } z; z.l[0] = 0; z.l[1] = 0; return z.s;
}
// swap 16b halves of each dword: K-slot j <-> j^1 (hi/lo plane exchange)
__device__ __forceinline__ short8 swap16(short8 v){
  union { short8 s; unsigned int u[4]; } a, r;
  a.s = v;
  #pragma unroll
  for (int i = 0; i < 4; i++) r.u[i] = (a.u[i] >> 16) | (a.u[i] << 16);
  return r.s;
}
__device__ __forceinline__ void split2(float x, u16& h, u16& l){
  h = f2b(x);
  l = f2b(x - b2f(h));
}

// ---------------------------------------------------------------- M = K R(q) Kinv
__global__ void k_M(const void* __restrict__ quat, const void* __restrict__ K,
                    const void* __restrict__ Kinv, float* __restrict__ Mout){
  bool f = is_f32(K);
  int b = threadIdx.x;
  if (b >= 16) return;
  float q0 = ldg_(quat,b*4+0,f), q1 = ldg_(quat,b*4+1,f);
  float q2 = ldg_(quat,b*4+2,f), q3 = ldg_(quat,b*4+3,f);
  float n = sqrtf(q0*q0 + q1*q1 + q2*q2 + q3*q3);
  float w = q0/n, x = q1/n, y = q2/n, z = q3/n;
  float R[9];
  R[0] = 1.f - 2.f*(y*y + z*z); R[1] = 2.f*(x*y - w*z); R[2] = 2.f*(x*z + w*y);
  R[3] = 2.f*(x*y + w*z); R[4] = 1.f - 2.f*(x*x + z*z); R[5] = 2.f*(y*z - w*x);
  R[6] = 2.f*(x*z - w*y); R[7] = 2.f*(y*z + w*x); R[8] = 1.f - 2.f*(x*x + y*y);
  float Kf[9], Ki[9];
  for (int i = 0; i < 9; i++){ Kf[i] = ldg_(K,i,f); Ki[i] = ldg_(Kinv,i,f); }
  float T[9];
  for (int r = 0; r < 3; r++)
    for (int c = 0; c < 3; c++)
      T[r*3+c] = R[r*3+0]*Ki[0*3+c] + R[r*3+1]*Ki[1*3+c] + R[r*3+2]*Ki[2*3+c];
  for (int r = 0; r < 3; r++)
    for (int c = 0; c < 3; c++)
      Mout[b*9 + r*3 + c] = Kf[r*3+0]*T[0*3+c] + Kf[r*3+1]*T[1*3+c] + Kf[r*3+2]*T[2*3+c];
}

// ---------------------------------------- rotation-flow, column (W 1024->64) pass
__global__ void k_rflow_col(const float* __restrict__ Mws, float* __restrict__ tmpA){
  int t = blockIdx.x * 256 + threadIdx.x;      // 16*448*64 = 458752 exactly
  int xo = t & 63;
  int yf = (t >> 6) % 448;
  int b  = t / (448*64);
  const float* M = Mws + b*9;
  float m0=M[0],m1=M[1],m2=M[2],m3=M[3],m4=M[4],m5=M[5],m6=M[6],m7=M[7],m8=M[8];
  float cx = 16.f*xo + 7.5f;
  float yff = (float)yf;
  float su = 0.f, sv = 0.f, wsum = 0.f;
  for (int i = 0; i < 32; i++){
    int xi = 16*xo - 8 + i;
    if (xi < 0 || xi > 1023) continue;
    float xf = (float)xi;
    float wgt = 1.f - fabsf(xf - cx) * (1.f/16.f);
    float den = m6*xf + m7*yff + m8;
    float inv = 1.f / den;
    float u = (m0*xf + m1*yff + m2)*inv - xf;
    float v = (m3*xf + m4*yff + m5)*inv - yff;
    su += wgt*u; sv += wgt*v; wsum += wgt;
  }
  float rn = 1.f / wsum;
  tmpA[((size_t)(b*2+0)*64 + xo)*448 + yf] = su*rn;
  tmpA[((size_t)(b*2+1)*64 + xo)*448 + yf] = sv*rn;
}

// ---------------------------------------- rotation-flow, row (448->28) + /SCALE
__global__ void k_rflow_row(const float* __restrict__ tmpA, float* __restrict__ rfr,
                            void* __restrict__ outb, const void* probe){
  bool f = is_f32(probe);
  int t = blockIdx.x * 256 + threadIdx.x;      // 28672 exactly
  int xo = t & 63;
  int yo = (t >> 6) % 28;
  int b  = t / HW4;
  float cy = 16.f*yo + 7.5f;
  for (int c = 0; c < 2; c++){
    const float* col = tmpA + ((size_t)(b*2+c)*64 + xo)*448;
    float s = 0.f, wsum = 0.f;
    for (int i = 0; i < 32; i++){
      int yi = 16*yo - 8 + i;
      if (yi < 0 || yi > 447) continue;
      float wgt = 1.f - fabsf((float)yi - cy) * (1.f/16.f);
      s += wgt * col[yi]; wsum += wgt;
    }
    float val = s / (wsum * 16.0f);   // includes /SCALE
    rfr[(size_t)(b*2+c)*HW4 + yo*64 + xo] = val;
    stg_(outb, OUTOFF + ((size_t)b*FCH + 529 + c)*HW4 + yo*64 + xo, val, f);
  }
}

// ---------------------------------------------------- deconv4s2 of prev_flow (2ch)
__global__ void k_dflow(const void* __restrict__ pf, const void* __restrict__ w,
                        const void* __restrict__ bias, float* __restrict__ tflow,
                        void* __restrict__ outb, const void* probe){
  bool f = is_f32(probe);
  int t = blockIdx.x * 256 + threadIdx.x;      // 57344 exactly
  int x = t & 63;
  int y = (t >> 6) % 28;
  int co = (t / HW4) & 1;
  int b  = t / (2*HW4);
  float acc = ldg_(bias, co, f);
  for (int ky = 0; ky < 4; ky++){
    int dy = y + ky - 2;
    if (dy < 0 || dy > 26 || (dy & 1)) continue;
    int iy = dy >> 1;
    for (int kx = 0; kx < 4; kx++){
      int dx = x + kx - 2;
      if (dx < 0 || dx > 62 || (dx & 1)) continue;
      int ix = dx >> 1;
      for (int ci = 0; ci < 2; ci++){
        acc += ldg_(pf, ((size_t)(b*2+ci)*14 + iy)*32 + ix, f) *
               ldg_(w,  (size_t)ci*32 + co*16 + (3-ky)*4 + (3-kx), f);
      }
    }
  }
  tflow[(size_t)(b*2+co)*HW4 + y*64 + x] = acc;
  stg_(outb, OUTOFF + ((size_t)b*FCH + 627 + co)*HW4 + y*64 + x, acc, f);
}

// ------------------------------- deconv4s2 of prev_feat (663->2), two-stage LDS version
#define DF_NCH 42
__global__ __launch_bounds__(256) void k_dfeat_s1(
    const void* __restrict__ pfeat, const void* __restrict__ w,
    float* __restrict__ part, const void* probe){
  bool f = is_f32(probe);
  __shared__ float s_in[16*448];    // 28672 B
  __shared__ float s_w[16*32];      // 2048 B
  const int tid = threadIdx.x;
  const int ch = blockIdx.x;        // 0..41
  const int b  = blockIdx.y;        // 0..15
  if (f){
    const float* src = (const float*)pfeat + ((size_t)b*663 + (size_t)ch*16)*448;
    #pragma unroll
    for (int i = 0; i < 7; i++){
      int e = tid + 256*i;
      int ci = ch*16 + e/112;
      float4 v = {0.f,0.f,0.f,0.f};
      if (ci < 663) v = *(const float4*)(src + e*4);
      *(float4*)&s_in[e*4] = v;
    }
  } else {
    const u16* src = (const u16*)pfeat + ((size_t)b*663 + (size_t)ch*16)*448;
    #pragma unroll
    for (int i = 0; i < 7; i++){
      int e = tid + 256*i;
      int ci = ch*16 + e/112;
      float4 v = {0.f,0.f,0.f,0.f};
      if (ci < 663){
        ushort4 u = *(const ushort4*)(src + e*4);
        v.x = b2f(u.x); v.y = b2f(u.y); v.z = b2f(u.z); v.w = b2f(u.w);
      }
      *(float4*)&s_in[e*4] = v;
    }
  }
  #pragma unroll
  for (int i = 0; i < 2; i++){
    int e = tid + 256*i;            // 0..511
    int ci = ch*16 + (e >> 5);
    s_w[e] = (ci < 663) ? ldg_(w, (size_t)ci*32 + (e & 31), f) : 0.f;
  }
  __syncthreads();
  const int x = tid & 63;
  int ix0=-1, ix1=-1, wx0=0, wx1=0;
  { int n = 0;
    for (int kx = (x & 1); kx < 4; kx += 2){
      int dx = x + kx - 2;
      if (dx >= 0 && dx <= 62){
        if (n == 0){ ix0 = dx >> 1; wx0 = 3-kx; } else { ix1 = dx >> 1; wx1 = 3-kx; }
        n++;
      }
    } }
  float* pout = part + (size_t)(b*DF_NCH + ch)*2*1792;
  #pragma unroll
  for (int i = 0; i < 7; i++){
    int p = tid + 256*i;            // covers 0..1791, x = p&63 = tid&63
    int y = p >> 6;
    int iy0=-1, iy1=-1, wy0=0, wy1=0;
    { int n = 0;
      for (int ky = (y & 1); ky < 4; ky += 2){
        int dy = y + ky - 2;
        if (dy >= 0 && dy <= 26){
          if (n == 0){ iy0 = dy >> 1; wy0 = (3-ky)*4; } else { iy1 = dy >> 1; wy1 = (3-ky)*4; }
          n++;
        }
      } }
    const bool v00 = (iy0 >= 0) && (ix0 >= 0);
    const bool v01 = (iy0 >= 0) && (ix1 >= 0);
    const bool v10 = (iy1 >= 0) && (ix0 >= 0);
    const bool v11 = (iy1 >= 0) && (ix1 >= 0);
    const int o00 = iy0*32+ix0, o01 = iy0*32+ix1, o10 = iy1*32+ix0, o11 = iy1*32+ix1;
    const int w00 = wy0+wx0, w01 = wy0+wx1, w10 = wy1+wx0, w11 = wy1+wx1;
    float a0 = 0.f, a1 = 0.f;
    #pragma unroll 4
    for (int ci = 0; ci < 16; ci++){
      const float* si = s_in + ci*448;
      const float* sw = s_w + ci*32;
      if (v00){ float iv = si[o00]; a0 += iv*sw[w00]; a1 += iv*sw[16+w00]; }
      if (v01){ float iv = si[o01]; a0 += iv*sw[w01]; a1 += iv*sw[16+w01]; }
      if (v10){ float iv = si[o10]; a0 += iv*sw[w10]; a1 += iv*sw[16+w10]; }
      if (v11){ float iv = si[o11]; a0 += iv*sw[w11]; a1 += iv*sw[16+w11]; }
    }
    pout[p]        = a0;
    pout[1792 + p] = a1;
  }
}

__global__ void k_dfeat_s2(const float* __restrict__ part, const void* __restrict__ bias,
                           void* __restrict__ outb, const void* probe){
  bool f = is_f32(probe);
  int t = blockIdx.x * 256 + threadIdx.x;      // 57344 exactly
  int x = t & 63;
  int y = (t >> 6) % 28;
  int co = (t / HW4) & 1;
  int b  = t / (2*HW4);
  float s = ldg_(bias, co, f);
  const float* pp = part + ((size_t)b*(2*DF_NCH) + co)*1792 + (size_t)(y*64 + x);
  #pragma unroll
  for (int ch = 0; ch < DF_NCH; ch++) s += pp[(size_t)ch*3584];
  stg_(outb, OUTOFF + ((size_t)b*FCH + 629 + co)*HW4 + y*64 + x, s, f);
}

// ---------------------------------------------------------------- copy tenOne into feat
__global__ void k_copy_one(const void* __restrict__ one, void* __restrict__ outb,
                           const void* probe){
  bool f = is_f32(probe);
  int t = blockIdx.x * 256 + threadIdx.x;      // 2752512 exactly
  int p = t % HW4;
  int c = (t / HW4) % 96;
  int b = t / (96*HW4);
  stg_(outb, OUTOFF + ((size_t)b*FCH + 531 + c)*HW4 + p,
       ldg_(one, (size_t)(b*96+c)*HW4 + p, f), f);
}

// ------------------------------------------- fused double-warp of tenTwo (16-pt gather)
__global__ void k_warp2(const void* __restrict__ two, const float* __restrict__ rfr,
                        const float* __restrict__ tflow, float* __restrict__ wrp2,
                        const void* probe){
  bool f = is_f32(probe);
  int t = blockIdx.x * 256 + threadIdx.x;      // 2752512 exactly
  int x = t & 63;
  int y = (t >> 6) % 28;
  int c = (t / HW4) % 96;
  int b = t / (96*HW4);
  float qu = tflow[(size_t)(b*2+0)*HW4 + y*64 + x] * 1.25f;
  float qv = tflow[(size_t)(b*2+1)*HW4 + y*64 + x] * 1.25f;
  float qx = (float)x + qu, qy = (float)y + qv;
  float qx0 = floorf(qx), qy0 = floorf(qy);
  float wx = qx - qx0, wy = qy - qy0;
  const size_t cb = (size_t)(b*96+c)*HW4;
  float acc = 0.f;
  #pragma unroll
  for (int a = 0; a < 2; a++){
    #pragma unroll
    for (int bb = 0; bb < 2; bb++){
      float ry = qy0 + (float)a, rx = qx0 + (float)bb;
      if (ry < 0.f || ry > 27.f || rx < 0.f || rx > 63.f) continue;
      float W = (a ? wy : 1.f-wy) * (bb ? wx : 1.f-wx);
      int iry = (int)ry, irx = (int)rx;
      float su = rfr[(size_t)(b*2+0)*HW4 + iry*64 + irx];
      float sv = rfr[(size_t)(b*2+1)*HW4 + iry*64 + irx];
      float sx = rx + su, sy = ry + sv;
      float sx0 = floorf(sx), sy0 = floorf(sy);
      float swx = sx - sx0, swy = sy - sy0;
      float inner = 0.f;
      #pragma unroll
      for (int aa = 0; aa < 2; aa++){
        #pragma unroll
        for (int cc2 = 0; cc2 < 2; cc2++){
          float gy2 = sy0 + (float)aa, gx2 = sx0 + (float)cc2;
          if (gy2 < 0.f || gy2 > 27.f || gx2 < 0.f || gx2 > 63.f) continue;
          float wv = (aa ? swy : 1.f-swy) * (cc2 ? swx : 1.f-swx);
          inner += wv * ldg_(two, cb + (size_t)((int)gy2*64 + (int)gx2), f);
        }
      }
      acc += W * inner;
    }
  }
  wrp2[t] = acc;
}

// ---------------------------------------------------------------- correlation (81 ch)
__global__ void k_corr(const void* __restrict__ one, const float* __restrict__ two,
                       void* __restrict__ outb, const void* probe){
  bool f = is_f32(probe);
  int t = blockIdx.x * 256 + threadIdx.x;      // 16*9*1792 = 258048 exactly
  int x  = t & 63;
  int y  = (t >> 6) % 28;
  int dy = (t / HW4) % 9;
  int b  = t / (9*HW4);
  float acc[9];
  #pragma unroll
  for (int i = 0; i < 9; i++) acc[i] = 0.f;
  int row = y + dy - 4;
  if (row >= 0 && row < 28){
    for (int c = 0; c < 96; c++){
      float f1 = ldg_(one, (size_t)(b*96+c)*HW4 + y*64 + x, f);
      const float* rp = two + (size_t)(b*96+c)*HW4 + row*64;
      #pragma unroll
      for (int dx = 0; dx < 9; dx++){
        int xx = x + dx - 4;
        if (xx >= 0 && xx < 64) acc[dx] += f1 * rp[xx];
      }
    }
  }
  #pragma unroll
  for (int dx = 0; dx < 9; dx++){
    float v = lrelu(acc[dx] * (1.f/96.f));
    stg_(outb, OUTOFF + ((size_t)b*FCH + 448 + dy*9 + dx)*HW4 + y*64 + x, v, f);
  }
}

// ---------------------------------------------------------------- 3x3 conv + lrelu
// Dual-dtype VALU path. bf16_only=1: run only when data is bf16 (f32 -> MFMA path).
__global__ __launch_bounds__(256) void k_conv(
    void* __restrict__ base, size_t in_off,
    const void* __restrict__ w, const void* __restrict__ bias,
    int Cin, int Cout, size_t out_off, size_t out_bstr, const void* probe,
    int bf16_only){
  bool f = is_f32(probe);
  if (bf16_only && f) return;
  __shared__ float s_in[32*3*66];    // 25344 B
  __shared__ float s_w[32*9*32];     // 36864 B
  int tid = threadIdx.x;
  int x = tid & 63;
  int g = tid >> 6;
  int by = blockIdx.x;
  int b = by / 28, y = by % 28;
  int co_base = blockIdx.y * 32;
  const size_t FB = (size_t)FCH * HW4;
  float acc[8];
  #pragma unroll
  for (int j = 0; j < 8; j++) acc[j] = 0.f;

  for (int ci0 = 0; ci0 < Cin; ci0 += 32){
    int cc = min(32, Cin - ci0);
    if (f){
      const float* inb = (const float*)base + in_off + (size_t)b*FB;
      for (int e = tid; e < cc*198; e += 256){
        int ci = e / 198; int rem = e - ci*198;
        int r = rem / 66; int xx = rem - r*66;
        int iy = y + r - 1; int ix = xx - 1;
        float v = 0.f;
        if (iy >= 0 && iy < 28 && ix >= 0 && ix < 64)
          v = inb[(size_t)(ci0+ci)*HW4 + iy*64 + ix];
        s_in[(ci*3 + r)*66 + xx] = v;
      }
      const float* wf = (const float*)w;
      for (int e = tid; e < cc*288; e += 256){
        int co_i = e & 31; int k = (e >> 5) % 9; int ci = e / 288;
        int co = co_base + co_i;
        float v = 0.f;
        if (co < Cout) v = wf[((size_t)co*Cin + ci0 + ci)*9 + k];
        s_w[(ci*9 + k)*32 + co_i] = v;
      }
    } else {
      const u16* inb = (const u16*)base + in_off + (size_t)b*FB;
      for (int e = tid; e < cc*198; e += 256){
        int ci = e / 198; int rem = e - ci*198;
        int r = rem / 66; int xx = rem - r*66;
        int iy = y + r - 1; int ix = xx - 1;
        float v = 0.f;
        if (iy >= 0 && iy < 28 && ix >= 0 && ix < 64)
          v = b2f(inb[(size_t)(ci0+ci)*HW4 + iy*64 + ix]);
        s_in[(ci*3 + r)*66 + xx] = v;
      }
      const u16* wf = (const u16*)w;
      for (int e = tid; e < cc*288; e += 256){
        int co_i = e & 31; int k = (e >> 5) % 9; int ci = e / 288;
        int co = co_base + co_i;
        float v = 0.f;
        if (co < Cout) v = b2f(wf[((size_t)co*Cin + ci0 + ci)*9 + k]);
        s_w[(ci*9 + k)*32 + co_i] = v;
      }
    }
    __syncthreads();
    for (int ci = 0; ci < cc; ci++){
      const float* si = &s_in[ci*198 + x];
      const float* sw = &s_w[ci*288 + 8*g];
      #pragma unroll
      for (int ky = 0; ky < 3; ky++){
        #pragma unroll
        for (int kx = 0; kx < 3; kx++){
          float v = si[ky*66 + kx];
          const float* wp = sw + (ky*3 + kx)*32;
          float4 wa = *(const float4*)(wp);
          float4 wb = *(const float4*)(wp + 4);
          acc[0] += wa.x*v; acc[1] += wa.y*v; acc[2] += wa.z*v; acc[3] += wa.w*v;
          acc[4] += wb.x*v; acc[5] += wb.y*v; acc[6] += wb.z*v; acc[7] += wb.w*v;
        }
      }
    }
    __syncthreads();
  }
  #pragma unroll
  for (int j = 0; j < 8; j++){
    int co = co_base + 8*g + j;
    if (co < Cout){
      float v = lrelu(acc[j] + ldg_(bias, co, f));
      stg_(base, out_off + (size_t)b*out_bstr + (size_t)co*HW4 + y*64 + x, v, f);
    }
  }
}

// --------------------------------------------------------- weight hi/lo split + frag-linearize
// t = ((((gyb*nCB + cb)*9 + tap)*nTI + tI)*64 + lane)*8 + j
// kk = (lane>>4)*8 + j ; ci = cb*16 + (kk>>1) ; plane = kk&1 ; co = gyb*nTI*16 + tI*16 + (lane&15)
__global__ void k_wprep(const void* __restrict__ w, u16* __restrict__ wT,
                        int Cin, int Cout, int nCB, int nTI, int total, const void* probe){
  if (!is_f32(probe)) return;          // f32 path only
  int t = blockIdx.x * 256 + threadIdx.x;
  if (t >= total) return;
  int j     = t & 7;
  int lane  = (t >> 3) & 63;
  int rest  = t >> 9;
  int tI    = rest % nTI;
  int r2    = rest / nTI;
  int tap   = r2 % 9;
  int gc    = r2 / 9;
  int cb    = gc % nCB;
  int gyb   = gc / nCB;
  int kk = ((lane >> 4) << 3) + j;
  int ci = cb*16 + (kk >> 1);
  int co = gyb*nTI*16 + tI*16 + (lane & 15);
  float x = 0.f;
  if (co < Cout && ci < Cin) x = ((const float*)w)[((size_t)co*Cin + ci)*9 + tap];
  u16 hi = f2b(x);
  wT[t] = (kk & 1) ? f2b(x - b2f(hi)) : hi;
}

// --------------------------------------------------------- 3x3 conv via split-bf16 MFMA (f32 I/O)
// Template NTI = co-tiles per block (coP_block = NTI*16). Block: 4 waves;
// wave wv: row = y0+(wv&1), x-half = (wv>>1)*32; NTI*16 co.
// Grid: (224 = 16 b * 14 row-pairs, gy).
// LDS: input u16 [0,8192): slot (n = r*64+x, lg) at n*32 + ((lg ^ ((x>>2)&3))*8,
//      8 u16 (K-octet); staged as per-thread ds_write_b128 (conflict-free);
//      weight u16 [8192, 8192+9*NTI*512): [tap][tI][lane][j] (conflict-free b128).
// Register double-buffered cb-loop (ping-pong named sets; nCB always even).
template<int NTI>
__global__ __launch_bounds__(256, 3) void k_conv_ms(
    void* __restrict__ base, size_t in_off, const u16* __restrict__ wT,
    const void* __restrict__ bias, int Cin, int nCB, int Cout,
    size_t out_off, size_t out_bstr, const void* __restrict__ probe){
  if (!is_f32(probe)) return;          // f32 path only
  constexpr int WU16 = 9*NTI*512;      // weight region u16 per cb
  constexpr int WCH  = WU16/8;         // 16B chunks per cb (576*NTI)
  constexpr int NW   = (WCH + 255)/256;
  __shared__ __align__(16) u16 lds[8192 + WU16];
  const int tid  = threadIdx.x;
  const int lane = tid & 63, wv = tid >> 6;
  const int lx = lane & 15, lg = lane >> 4;
  const int wr  = wv & 1;              // wave row within pair
  const int wxh = wv >> 1;             // wave x-half
  const int b  = blockIdx.x & 15;
  const int y0 = (blockIdx.x >> 4) * 2;
  const int coB = (int)blockIdx.y * (NTI*16);
  const float* inb = (const float*)base + in_off + (size_t)b * ((size_t)FCH * HW4);
  const u16* wTg = wT + (size_t)blockIdx.y * (size_t)nCB * WU16;

  f32x4 acc[NTI][2];
  #pragma unroll
  for (int tI = 0; tI < NTI; tI++){ acc[tI][0] = zero4(); acc[tI][1] = zero4(); }

  // B-frag read offsets (u16), slot-swizzled: xo = lx+kx-1 in [-1,16]
  int offb[3];
  #pragma unroll
  for (int kx = 0; kx < 3; kx++){
    int xo = lx + kx - 1;
    offb[kx] = (xo >> 4)*512 + (xo & 15)*32 + ((lg ^ ((xo >> 2) & 3)) << 3);
  }
  const bool maskB0 = (lx == 0  && wxh == 0);   // x = -1
  const bool maskB1 = (lx == 15 && wxh == 1);   // x = 64

  // staging thread constants: slot n = tid (r = tid>>6, x = tid&63), octet lg_w = i
  const int sx   = tid & 63;
  const int srow = y0 - 1 + (tid >> 6);
  const bool rok = (srow >= 0 && srow < 28);
  const int sw4  = (tid >> 2) & 3;     // (x>>2)&3

  float paA[16], paB[16];
  short8 pwA[NW], pwB[NW];

  auto LOADA = [&](int cb){
    const u16* wsrc = wTg + (size_t)cb * WU16;
    #pragma unroll
    for (int i = 0; i < NW; i++){
      int e = tid + 256*i;
      if (e < WCH) pwA[i] = *(const short8*)(wsrc + (size_t)e*8);
    }
    #pragma unroll
    for (int i = 0; i < 4; i++)
      #pragma unroll
      for (int c = 0; c < 4; c++){
        int ci = cb*16 + i*4 + c;
        float v = 0.f;
        if (rok && ci < Cin) v = inb[(size_t)ci*HW4 + srow*64 + sx];
        paA[i*4+c] = v;
      }
  };
  auto LOADB = [&](int cb){
    const u16* wsrc = wTg + (size_t)cb * WU16;
    #pragma unroll
    for (int i = 0; i < NW; i++){
      int e = tid + 256*i;
      if (e < WCH) pwB[i] = *(const short8*)(wsrc + (size_t)e*8);
    }
    #pragma unroll
    for (int i = 0; i < 4; i++)
      #pragma unroll
      for (int c = 0; c < 4; c++){
        int ci = cb*16 + i*4 + c;
        float v = 0.f;
        if (rok && ci < Cin) v = inb[(size_t)ci*HW4 + srow*64 + sx];
        paB[i*4+c] = v;
      }
  };
  auto WRITEA = [&](){
    #pragma unroll
    for (int i = 0; i < NW; i++){
      int e = tid + 256*i;
      if (e < WCH) *(short8*)&lds[8192 + e*8] = pwA[i];
    }
    #pragma unroll
    for (int i = 0; i < 4; i++){
      short8 s;
      #pragma unroll
      for (int c = 0; c < 4; c++){
        u16 h, l; split2(paA[i*4+c], h, l);
        s[2*c] = (short)h; s[2*c+1] = (short)l;
      }
      *(short8*)&lds[tid*32 + ((i ^ sw4) << 3)] = s;
    }
  };
  auto WRITEB = [&](){
    #pragma unroll
    for (int i = 0; i < NW; i++){
      int e = tid + 256*i;
      if (e < WCH) *(short8*)&lds[8192 + e*8] = pwB[i];
    }
    #pragma unroll
    for (int i = 0; i < 4; i++){
      short8 s;
      #pragma unroll
      for (int c = 0; c < 4; c++){
        u16 h, l; split2(paB[i*4+c], h, l);
        s[2*c] = (short)h; s[2*c+1] = (short)l;
      }
      *(short8*)&lds[tid*32 + ((i ^ sw4) << 3)] = s;
    }
  };
  auto COMPUTE = [&](){
    #pragma unroll
    for (int ky = 0; ky < 3; ky++){
      const int rb = (wr + ky)*2048 + wxh*1024;   // u16 base: input row, wave x-half
      #pragma unroll
      for (int kx = 0; kx < 3; kx++){
        const int k = ky*3 + kx;
        const int bA = rb + offb[kx];
        short8 B0 = *(const short8*)&lds[bA];          // xg=0 frag
        short8 B1 = *(const short8*)&lds[bA + 512];    // xg=1 frag (+16 x)
        if (kx == 0 && maskB0) B0 = zero8();
        if (kx == 2 && maskB1) B1 = zero8();
        short8 S0 = swap16(B0), S1 = swap16(B1);
        #pragma unroll
        for (int tI = 0; tI < NTI; tI++){
          short8 Af = *(const short8*)&lds[8192 + ((k*NTI + tI)*64 + lane)*8];
          acc[tI][0] = __builtin_amdgcn_mfma_f32_16x16x32_bf16(Af, B0, acc[tI][0], 0,0,0);
          acc[tI][0] = __builtin_amdgcn_mfma_f32_16x16x32_bf16(Af, S0, acc[tI][0], 0,0,0);
          acc[tI][1] = __builtin_amdgcn_mfma_f32_16x16x32_bf16(Af, B1, acc[tI][1], 0,0,0);
          acc[tI][1] = __builtin_amdgcn_mfma_f32_16x16x32_bf16(Af, S1, acc[tI][1], 0,0,0);
        }
      }
    }
  };

  LOADA(0);
  for (int cb = 0; cb < nCB; cb += 2){         // nCB is always even
    WRITEA();
    LOADB(cb + 1);
    __syncthreads();
    COMPUTE();
    __syncthreads();
    WRITEB();
    if (cb + 2 < nCB) LOADA(cb + 2);
    __syncthreads();
    COMPUTE();
    __syncthreads();
  }
  // epilogue: bias + lrelu + f32 store. D: col=lane&15 -> x, row=(lane>>4)*4+reg -> co
  float* ob = (float*)base;
  const float* bf = (const float*)bias;
  const int y = y0 + wr;
  #pragma unroll
  for (int tI = 0; tI < NTI; tI++){
    #pragma unroll
    for (int xg = 0; xg < 2; xg++){
      const int x = wxh*32 + xg*16 + lx;
      #pragma unroll
      for (int r4 = 0; r4 < 4; r4++){
        int co = coB + tI*16 + lg*4 + r4;
        if (co < Cout){
          float v = lrelu(acc[tI][xg][r4] + bf[co]);
          ob[out_off + (size_t)b*out_bstr + (size_t)co*HW4 + (size_t)(y*64 + x)] = v;
        }
      }
    }
  }
}

// ----------------------------------------------------------------------------------
extern "C" void kernel_launch(void* const* d_in, const int* in_sizes, int n_in,
                              void* d_out, int out_size, void* d_ws, size_t ws_size,
                              hipStream_t stream){
  const void* tenOne    = d_in[0];
  const void* tenTwo    = d_in[1];
  const void* prev_flow = d_in[2];
  const void* prev_feat = d_in[3];
  const void* quat      = d_in[4];
  const void* K         = d_in[5];
  const void* Kinv      = d_in[6];
  const void* upflow_w  = d_in[7];
  const void* upflow_b  = d_in[8];
  const void* upfeat_w  = d_in[9];
  const void* upfeat_b  = d_in[10];
  const void* w1 = d_in[11];  const void* b1 = d_in[12];
  const void* w2 = d_in[13];  const void* b2 = d_in[14];
  const void* w3 = d_in[15];  const void* b3 = d_in[16];
  const void* w4 = d_in[17];  const void* b4 = d_in[18];
  const void* w5 = d_in[19];  const void* b5 = d_in[20];
  const void* w6 = d_in[21];  const void* b6 = d_in[22];
  const void* probe = K;    // cam_intri[0]==500.0 discriminates dtype (runtime-only!)

  float* ws    = (float*)d_ws;
  float* Mws   = ws;                         // 160
  float* tmpA  = ws + 160;                   // 917504
  float* rfr   = ws + 917664;                // 57344
  float* tflow = ws + 975008;                // 57344
  float* wrp2  = ws + 1032352;               // 2752512 (end 3784864 floats = 15139456 B)
  u16*   wTb   = (u16*)(ws + 3784864);       // 3115008 u16 (6230016 B) split weights
  // dfeat partials (2408448 floats) alias the wrp2 region: k_dfeat_s1/s2 complete
  // before k_warp2 writes wrp2 (same-stream ordering).
  float* dpart = wrp2;

  // host-side capacity check for the MFMA path's weight buffer
  const bool ws_ok = ws_size >= (size_t)21369472;   // 15139456 + 6230016

  k_M<<<1, 64, 0, stream>>>(quat, K, Kinv, Mws);
  k_rflow_col<<<1792, 256, 0, stream>>>(Mws, tmpA);
  k_rflow_row<<<112, 256, 0, stream>>>(tmpA, rfr, d_out, probe);
  k_dflow<<<224, 256, 0, stream>>>(prev_flow, upflow_w, upflow_b, tflow, d_out, probe);
  k_dfeat_s1<<<dim3(DF_NCH, 16), 256, 0, stream>>>(prev_feat, upfeat_w, dpart, probe);
  k_dfeat_s2<<<224, 256, 0, stream>>>(dpart, upfeat_b, d_out, probe);
  k_copy_one<<<10752, 256, 0, stream>>>(tenOne, d_out, probe);
  k_warp2<<<10752, 256, 0, stream>>>(tenTwo, rfr, tflow, wrp2, probe);
  k_corr<<<1008, 256, 0, stream>>>(tenOne, wrp2, d_out, probe);

  const size_t FB = (size_t)FCH * HW4;
  const size_t f0 = OUTOFF;

  struct LD { const void *w, *bi; int Cin, Cout, nCB, gy, nTI;
              size_t wOff, in_off, out_off, out_bstr; };
  const LD L[6] = {
    { w1, b1, 183, 128, 12, 4, 2, 0,       f0+(size_t)448*HW4, f0+(size_t)320*HW4, FB },
    { w2, b2, 311, 128, 20, 4, 2, 442368,  f0+(size_t)320*HW4, f0+(size_t)192*HW4, FB },
    { w3, b3, 439,  96, 28, 3, 2, 1179648, f0+(size_t)192*HW4, f0+(size_t) 96*HW4, FB },
    { w4, b4, 535,  64, 34, 2, 2, 1953792, f0+(size_t) 96*HW4, f0+(size_t) 32*HW4, FB },
    { w5, b5, 599,  32, 38, 2, 1, 2580480, f0+(size_t) 32*HW4, f0,                 FB },
    { w6, b6, 631,   2, 40, 1, 1, 2930688, f0,                 0,        (size_t)2*HW4 },
  };

  if (ws_ok){
    // f32 MFMA path (self-gated: early-out when probe says bf16)
    for (int i = 0; i < 6; i++){
      int total = L[i].gy * L[i].nCB * 9 * L[i].nTI * 512;
      k_wprep<<<(total + 255)/256, 256, 0, stream>>>(
          L[i].w, wTb + L[i].wOff, L[i].Cin, L[i].Cout, L[i].nCB, L[i].nTI, total, probe);
    }
    for (int i = 0; i < 6; i++){
      if (L[i].nTI == 2)
        k_conv_ms<2><<<dim3(224, L[i].gy), 256, 0, stream>>>(
            d_out, L[i].in_off, wTb + L[i].wOff, L[i].bi,
            L[i].Cin, L[i].nCB, L[i].Cout, L[i].out_off, L[i].out_bstr, probe);
      else
        k_conv_ms<1><<<dim3(224, L[i].gy), 256, 0, stream>>>(
            d_out, L[i].in_off, wTb + L[i].wOff, L[i].bi,
            L[i].Cin, L[i].nCB, L[i].Cout, L[i].out_off, L[i].out_bstr, probe);
    }
  }
  // VALU path: bf16 data always; f32 data only if ws too small for the MFMA path
  const int bf16_only = ws_ok ? 1 : 0;
  k_conv<<<dim3(448,4), 256, 0, stream>>>(d_out, f0 + (size_t)448*HW4, w1, b1, 183, 128,
                                          f0 + (size_t)320*HW4, FB, probe, bf16_only);
  k_conv<<<dim3(448,4), 256, 0, stream>>>(d_out, f0 + (size_t)320*HW4, w2, b2, 311, 128,
                                          f0 + (size_t)192*HW4, FB, probe, bf16_only);
  k_conv<<<dim3(448,3), 256, 0, stream>>>(d_out, f0 + (size_t)192*HW4, w3, b3, 439, 96,
                                          f0 + (size_t)96*HW4, FB, probe, bf16_only);
  k_conv<<<dim3(448,2), 256, 0, stream>>>(d_out, f0 + (size_t)96*HW4, w4, b4, 535, 64,
                                          f0 + (size_t)32*HW4, FB, probe, bf16_only);
  k_conv<<<dim3(448,1), 256, 0, stream>>>(d_out, f0 + (size_t)32*HW4, w5, b5, 599, 32,
                                          f0, FB, probe, bf16_only);
  k_conv<<<dim3(448,1), 256, 0, stream>>>(d_out, f0, w6, b6, 631, 2,
                                          0, (size_t)2*HW4, probe, bf16_only);
}